// Round 9
// baseline (540.471 us; speedup 1.0000x reference)
//
#include <hip/hip_runtime.h>
#include <hip/hip_bf16.h>

// B=4, N=4096, C=128, K=16. float32 in/out. R8: ~450us profiled, VALUBusy 48%
// -> memory-latency/L2-bound on per-wave weight streams (~3.8GB L2).
// R9: (1) block-level LDS staging of ALL MLP weights through a 32KB window
//     (geo 19KB; diff_w1 32KB; diff_w2+ep_w1 32KB; ref_w1 4x32KB chunks)
//     => 4x less weight traffic, LDS-latency matvecs, conflict-free reads.
// (2) SoA xyz tile (xs/ys/zs) kills the 6.3e6 float4-repack write conflicts.
// (3) ballot-guarded phase-1 insertion (skips ~80% of candidates' selects).
// KNN formula, eig, all accumulation orders unchanged (numpy-f32-faithful).
#define N_ 4096
#define C_ 128
#define K_ 16
#define NPT 16384

__device__ __forceinline__ float wave_sum64(float v) {
#pragma unroll
  for (int off = 32; off >= 1; off >>= 1) v += __shfl_xor(v, off, 64);
  return v;
}

// ---------------- LAPACK f32 helpers (gfortran SIGN == copysignf) ----------------

__device__ __forceinline__ float sign_f(float a, float b) {
  return copysignf(fabsf(a), b);
}

__device__ float lapy2_f(float x, float y) {
#pragma clang fp contract(off)
  float xa = fabsf(x), ya = fabsf(y);
  float w = fmaxf(xa, ya), z = fminf(xa, ya);
  if (z == 0.0f) return w;
  float t = z / w;
  return w * sqrtf(1.0f + t * t);
}

// LAPACK >= 3.10 slartg
__device__ void lartg_f(float f, float g, float& c, float& s, float& r) {
#pragma clang fp contract(off)
  if (g == 0.0f) {
    c = 1.0f; s = 0.0f; r = f;
  } else if (f == 0.0f) {
    c = 0.0f; s = copysignf(1.0f, g); r = fabsf(g);
  } else {
    float d = sqrtf(f * f + g * g);
    c = fabsf(f) / d;
    r = sign_f(d, f);
    s = g / r;
  }
}

__device__ void laev2_f(float a, float b, float cc, float& rt1, float& rt2,
                        float& cs1, float& sn1) {
#pragma clang fp contract(off)
  float sm = a + cc;
  float df = a - cc;
  float adf = fabsf(df);
  float tb = b + b;
  float ab = fabsf(tb);
  float acmx, acmn;
  if (fabsf(a) > fabsf(cc)) { acmx = a; acmn = cc; } else { acmx = cc; acmn = a; }
  float rt;
  if (adf > ab) {
    float t = ab / adf; rt = adf * sqrtf(1.0f + t * t);
  } else if (adf < ab) {
    float t = adf / ab; rt = ab * sqrtf(1.0f + t * t);
  } else {
    rt = ab * sqrtf(2.0f);
  }
  int sgn1;
  if (sm < 0.0f) {
    rt1 = 0.5f * (sm - rt); sgn1 = -1;
    rt2 = (acmx / rt1) * acmn - (b / rt1) * b;
  } else if (sm > 0.0f) {
    rt1 = 0.5f * (sm + rt); sgn1 = 1;
    rt2 = (acmx / rt1) * acmn - (b / rt1) * b;
  } else {
    rt1 = 0.5f * rt; rt2 = -0.5f * rt; sgn1 = 1;
  }
  float cs; int sgn2;
  if (df >= 0.0f) { cs = df + rt; sgn2 = 1; } else { cs = df - rt; sgn2 = -1; }
  float acs = fabsf(cs);
  if (acs > ab) {
    float ct = -tb / cs;
    sn1 = 1.0f / sqrtf(1.0f + ct * ct);
    cs1 = ct * sn1;
  } else {
    if (ab == 0.0f) { cs1 = 1.0f; sn1 = 0.0f; }
    else {
      float tn = -cs / tb;
      cs1 = 1.0f / sqrtf(1.0f + tn * tn);
      sn1 = tn * cs1;
    }
  }
  if (sgn1 == sgn2) { float tn = cs1; cs1 = -sn1; sn1 = tn; }
}

// ssteqr('I') specialized to n=3, f32 constants.
__device__ void steqr3_f(float d[3], float e[2], float Z[3][3]) {
#pragma clang fp contract(off)
  const int n = 3;
  const float eps = 5.9604644775390625e-08f;   // 2^-24
  const float eps2 = eps * eps;
  const float safmin = 1.17549435e-38f;
  const int nmaxit = n * 30;
  int jtot = 0;
  int l1 = 1;

  for (int og = 0; og < 16; ++og) {
    if (l1 > n) break;
    if (l1 > 1) e[l1 - 2] = 0.0f;
    int m, l, lend;
    if (l1 <= n - 1) {
      bool found = false;
      for (m = l1; m <= n - 1; ++m) {
        float tst = fabsf(e[m - 1]);
        if (tst == 0.0f) { found = true; break; }
        if (tst <= (sqrtf(fabsf(d[m - 1])) * sqrtf(fabsf(d[m]))) * eps) {
          e[m - 1] = 0.0f; found = true; break;
        }
      }
      if (!found) m = n;
    } else {
      m = n;
    }
    l = l1; lend = m; l1 = m + 1;
    if (lend == l) continue;
    if (fabsf(d[lend - 1]) < fabsf(d[l - 1])) { int t = l; l = lend; lend = t; }

    if (lend > l) {
      // ---- QL ----
      for (int it = 0; it < 128; ++it) {
        int mm;
        if (l != lend) {
          bool f2 = false;
          for (mm = l; mm <= lend - 1; ++mm) {
            float tst = e[mm - 1] * e[mm - 1];
            if (tst <= (eps2 * fabsf(d[mm - 1])) * fabsf(d[mm]) + safmin) { f2 = true; break; }
          }
          if (!f2) mm = lend;
        } else mm = lend;
        if (mm < lend) e[mm - 1] = 0.0f;
        float p = d[l - 1];
        if (mm == l) {
          d[l - 1] = p; ++l;
          if (l <= lend) continue;
          break;
        }
        if (mm == l + 1) {
          float rt1, rt2, cc, ss;
          laev2_f(d[l - 1], e[l - 1], d[l], rt1, rt2, cc, ss);
          for (int r = 0; r < n; ++r) {
            float temp = Z[r][l];
            Z[r][l] = cc * temp - ss * Z[r][l - 1];
            Z[r][l - 1] = ss * temp + cc * Z[r][l - 1];
          }
          d[l - 1] = rt1; d[l] = rt2; e[l - 1] = 0.0f;
          l += 2;
          if (l <= lend) continue;
          break;
        }
        if (jtot == nmaxit) break;
        ++jtot;
        float g = (d[l] - p) / (2.0f * e[l - 1]);
        float r = lapy2_f(g, 1.0f);
        g = d[mm - 1] - p + e[l - 1] / (g + sign_f(r, g));
        float s = 1.0f, c = 1.0f;
        p = 0.0f;
        float csv[2], snv[2];
        for (int i = mm - 1; i >= l; --i) {
          float f = s * e[i - 1];
          float bb = c * e[i - 1];
          lartg_f(g, f, c, s, r);
          if (i != mm - 1) e[i] = r;
          g = d[i] - p;
          r = (d[i - 1] - g) * s + 2.0f * c * bb;
          p = s * r;
          d[i] = g + p;
          g = c * r - bb;
          csv[i - l] = c;
          snv[i - l] = -s;
        }
        int mml = mm - l;
        for (int j = mml; j >= 1; --j) {
          float cc = csv[j - 1], ss = snv[j - 1];
          for (int r2 = 0; r2 < n; ++r2) {
            float temp = Z[r2][l + j - 1];
            Z[r2][l + j - 1] = cc * temp - ss * Z[r2][l + j - 2];
            Z[r2][l + j - 2] = ss * temp + cc * Z[r2][l + j - 2];
          }
        }
        d[l - 1] -= p;
        e[l - 1] = g;
      }
    } else {
      // ---- QR ----
      for (int it = 0; it < 128; ++it) {
        int mm;
        if (l != lend) {
          bool f2 = false;
          for (mm = l; mm >= lend + 1; --mm) {
            float tst = e[mm - 2] * e[mm - 2];
            if (tst <= (eps2 * fabsf(d[mm - 1])) * fabsf(d[mm - 2]) + safmin) { f2 = true; break; }
          }
          if (!f2) mm = lend;
        } else mm = lend;
        if (mm > lend) e[mm - 2] = 0.0f;
        float p = d[l - 1];
        if (mm == l) {
          d[l - 1] = p; --l;
          if (l >= lend) continue;
          break;
        }
        if (mm == l - 1) {
          float rt1, rt2, cc, ss;
          laev2_f(d[l - 2], e[l - 2], d[l - 1], rt1, rt2, cc, ss);
          for (int r = 0; r < n; ++r) {
            float temp = Z[r][l - 1];
            Z[r][l - 1] = cc * temp - ss * Z[r][l - 2];
            Z[r][l - 2] = ss * temp + cc * Z[r][l - 2];
          }
          d[l - 2] = rt1; d[l - 1] = rt2; e[l - 2] = 0.0f;
          l -= 2;
          if (l >= lend) continue;
          break;
        }
        if (jtot == nmaxit) break;
        ++jtot;
        float g = (d[l - 2] - p) / (2.0f * e[l - 2]);
        float r = lapy2_f(g, 1.0f);
        g = d[mm - 1] - p + e[l - 2] / (g + sign_f(r, g));
        float s = 1.0f, c = 1.0f;
        p = 0.0f;
        float csv[2], snv[2];
        for (int i = mm; i <= l - 1; ++i) {
          float f = s * e[i - 1];
          float bb = c * e[i - 1];
          lartg_f(g, f, c, s, r);
          if (i != mm) e[i - 2] = r;
          g = d[i - 1] - p;
          r = (d[i] - g) * s + 2.0f * c * bb;
          p = s * r;
          d[i - 1] = g + p;
          g = c * r - bb;
          csv[i - mm] = c;
          snv[i - mm] = s;
        }
        int lm = l - mm;
        for (int j = 1; j <= lm; ++j) {
          float cc = csv[j - 1], ss = snv[j - 1];
          for (int r2 = 0; r2 < n; ++r2) {
            float temp = Z[r2][mm + j - 1];
            Z[r2][mm + j - 1] = cc * temp - ss * Z[r2][mm + j - 2];
            Z[r2][mm + j - 2] = ss * temp + cc * Z[r2][mm + j - 2];
          }
        }
        d[l - 1] -= p;
        e[l - 2] = g;
      }
    }
  }
  // ascending selection sort with column swaps
  for (int ii = 2; ii <= n; ++ii) {
    int i = ii - 1, k = i;
    float p = d[i - 1];
    for (int j = ii; j <= n; ++j) {
      if (d[j - 1] < p) { k = j; p = d[j - 1]; }
    }
    if (k != i) {
      d[k - 1] = d[i - 1]; d[i - 1] = p;
      for (int r = 0; r < n; ++r) {
        float t = Z[r][i - 1]; Z[r][i - 1] = Z[r][k - 1]; Z[r][k - 1] = t;
      }
    }
  }
}

// ssyevd(jobz='V', uplo='L') for 3x3
__device__ void eig3_f(float A00, float A10, float A20,
                       float A11, float A21, float A22, float Z[3][3]) {
#pragma clang fp contract(off)
  float d[3], e[2];
  float tau = 0.0f, v2 = 0.0f;
  d[0] = A00;
  float xnorm = fabsf(A20);
  if (xnorm == 0.0f) {
    tau = 0.0f; v2 = 0.0f;
    e[0] = A10; d[1] = A11; e[1] = A21; d[2] = A22;
  } else {
    float beta = -sign_f(lapy2_f(A10, xnorm), A10);
    tau = (beta - A10) / beta;
    float inv = 1.0f / (A10 - beta);
    v2 = A20 * inv;
    e[0] = beta;
    float x0 = tau * A11;
    float x1 = tau * A21;
    float tmp2 = A21 * v2;
    x0 = x0 + tau * tmp2;
    x1 = x1 + (tau * v2) * A22;
    float dotv = x0 + x1 * v2;
    float aw = (-0.5f * tau) * dotv;
    float w0 = x0 + aw;
    float w1 = x1 + aw * v2;
    d[1] = (A11 - w0) - w0;
    float pq = v2 * w0;
    e[1] = (A21 - pq) - w1;
    float pr = v2 * w1;
    d[2] = (A22 - pr) - pr;
  }
  Z[0][0] = 1.0f; Z[0][1] = 0.0f; Z[0][2] = 0.0f;
  Z[1][0] = 0.0f; Z[1][1] = 1.0f; Z[1][2] = 0.0f;
  Z[2][0] = 0.0f; Z[2][1] = 0.0f; Z[2][2] = 1.0f;
  steqr3_f(d, e, Z);
  if (tau != 0.0f) {
    for (int j = 0; j < 3; ++j) {
      float sum = Z[1][j] + v2 * Z[2][j];
      float tw = tau * sum;
      Z[1][j] = Z[1][j] - tw;
      Z[2][j] = Z[2][j] - v2 * tw;
    }
  }
}

// ---------------- Fused kernel ----------------
__global__ __launch_bounds__(256) void fused_kernel(
    const float* __restrict__ xyz, const float* __restrict__ feats,
    const float* __restrict__ geo_w1, const float* __restrict__ geo_b1,
    const float* __restrict__ geo_g1, const float* __restrict__ geo_be1,
    const float* __restrict__ geo_w2, const float* __restrict__ geo_b2,
    const float* __restrict__ diff_w1, const float* __restrict__ diff_b1,
    const float* __restrict__ diff_g1, const float* __restrict__ diff_be1,
    const float* __restrict__ diff_w2, const float* __restrict__ diff_b2,
    const float* __restrict__ ep_w1, const float* __restrict__ ep_b1,
    const float* __restrict__ ep_w2, const float* __restrict__ ep_b2,
    const float* __restrict__ ref_w1, const float* __restrict__ ref_b1,
    const float* __restrict__ ref_g1, const float* __restrict__ ref_be1,
    float* __restrict__ out, float* __restrict__ out_prob) {

  // 32 KB union: SoA xyz tile (phase 1) / weight window (phases 4-6).
  __shared__ union SMem {
    struct { float xs[1024]; float ys[1024]; float zs[1024]; } soa;  // 12 KB
    float w[8192];                                                   // 32 KB
    float4 w4[2048];
  } sm;

  const int wave = threadIdx.x >> 6;
  const int lane = threadIdx.x & 63;
  const int tid = threadIdx.x;
  const int p = blockIdx.x * 4 + wave;   // 4 points/block, same batch b
  const int b = p >> 12;
  const int i = p & 4095;
  const float* xb = xyz + (size_t)b * (N_ * 3);

  const float qx = xb[3 * i];
  const float qy = xb[3 * i + 1];
  const float qz = xb[3 * i + 2];
  const float qxx =
      __fadd_rn(__fadd_rn(__fmul_rn(qx, qx), __fmul_rn(qy, qy)), __fmul_rn(qz, qz));
  const float nqxx = -qxx;

  // ---- Phase 1: per-lane top-4 packed u64 keys, 4 x 12KB SoA sub-tiles ----
  unsigned long long pk[4] = {0ull, 0ull, 0ull, 0ull};

  for (int tile = 0; tile < 4; ++tile) {
    {
      const float4* gsrc = (const float4*)(xb + tile * 3072);
      float4 r0 = gsrc[tid * 3];
      float4 r1 = gsrc[tid * 3 + 1];
      float4 r2 = gsrc[tid * 3 + 2];
      const int q = tid * 4;
      sm.soa.xs[q] = r0.x; sm.soa.xs[q + 1] = r0.w;
      sm.soa.xs[q + 2] = r1.z; sm.soa.xs[q + 3] = r2.y;
      sm.soa.ys[q] = r0.y; sm.soa.ys[q + 1] = r1.x;
      sm.soa.ys[q + 2] = r1.w; sm.soa.ys[q + 3] = r2.z;
      sm.soa.zs[q] = r0.z; sm.soa.zs[q + 1] = r1.y;
      sm.soa.zs[q + 2] = r2.x; sm.soa.zs[q + 3] = r2.w;
    }
    __syncthreads();

#pragma unroll 4
    for (int tloc = 0; tloc < 16; ++tloc) {
      const int idx = tloc * 64 + lane;
      const int j = tile * 1024 + idx;
      const float x = sm.soa.xs[idx];
      const float y = sm.soa.ys[idx];
      const float z = sm.soa.zs[idx];
      const float dot = __fmaf_rn(qz, z, __fmaf_rn(qy, y, __fmul_rn(qx, x)));
      const float xxj =
          __fadd_rn(__fadd_rn(__fmul_rn(x, x), __fmul_rn(y, y)), __fmul_rn(z, z));
      const float inner = __fmul_rn(-2.0f, dot);
      const float pval = __fsub_rn(__fsub_rn(nqxx, inner), xxj);
      const unsigned bits = __float_as_uint(pval);
      const unsigned ordv = bits ^ (unsigned)(((int)bits >> 31) | 0x80000000);
      const unsigned long long key =
          ((unsigned long long)ordv << 32) | (unsigned)(4095 - j);
      // wave-uniform skip: inserting when key<=pk[3] is a no-op
      if (__ballot(key > pk[3]) != 0ull) {
        const bool c0 = key > pk[0], c1 = key > pk[1], c2 = key > pk[2],
                   c3 = key > pk[3];
        pk[3] = c3 ? (c2 ? pk[2] : key) : pk[3];
        pk[2] = c2 ? (c1 ? pk[1] : key) : pk[2];
        pk[1] = c1 ? (c0 ? pk[0] : key) : pk[1];
        pk[0] = c0 ? key : pk[0];
      }
    }
    __syncthreads();   // tile reuse boundary
  }

  // ---- Phase 2: 16-pop tournament merge over per-lane top-4 lists ----
  int nidx[K_];
  int h = 0;
#pragma unroll
  for (int k = 0; k < K_; ++k) {
    unsigned long long v = pk[0];
    int ln = lane;
#pragma unroll
    for (int off = 32; off >= 1; off >>= 1) {
      unsigned long long ov = __shfl_xor(v, off, 64);
      int ol = __shfl_xor(ln, off, 64);
      if (ov > v) { v = ov; ln = ol; }   // keys distinct => no ties
    }
    nidx[k] = (4095 - (int)(unsigned)(v & 0xFFFFFFFFull)) & (N_ - 1);
    if (lane == ln) {
      pk[0] = pk[1]; pk[1] = pk[2]; pk[2] = pk[3]; pk[3] = 0ull;
      ++h;
    }
  }
  // Exact fallback (rare, wave-uniform, global reads, no barriers inside).
  if (__ballot(h >= 4) != 0ull) {
    unsigned long long q[K_];
#pragma unroll
    for (int k = 0; k < K_; ++k) q[k] = 0ull;
    for (int t = 0; t < 64; ++t) {
      const int j = t * 64 + lane;
      const float x = xb[3 * j];
      const float y = xb[3 * j + 1];
      const float z = xb[3 * j + 2];
      const float dot = __fmaf_rn(qz, z, __fmaf_rn(qy, y, __fmul_rn(qx, x)));
      const float xxj =
          __fadd_rn(__fadd_rn(__fmul_rn(x, x), __fmul_rn(y, y)), __fmul_rn(z, z));
      const float inner = __fmul_rn(-2.0f, dot);
      const float pval = __fsub_rn(__fsub_rn(nqxx, inner), xxj);
      const unsigned bits = __float_as_uint(pval);
      const unsigned ordv = bits ^ (unsigned)(((int)bits >> 31) | 0x80000000);
      const unsigned long long key =
          ((unsigned long long)ordv << 32) | (unsigned)(4095 - j);
      bool c[K_];
#pragma unroll
      for (int s = 0; s < K_; ++s) c[s] = key > q[s];
#pragma unroll
      for (int s = K_ - 1; s >= 1; --s)
        q[s] = c[s] ? (c[s - 1] ? q[s - 1] : key) : q[s];
      q[0] = c[0] ? key : q[0];
    }
#pragma unroll
    for (int k = 0; k < K_; ++k) {
      unsigned long long v = q[0];
      int ln = lane;
#pragma unroll
      for (int off = 32; off >= 1; off >>= 1) {
        unsigned long long ov = __shfl_xor(v, off, 64);
        int ol = __shfl_xor(ln, off, 64);
        if (ov > v) { v = ov; ln = ol; }
      }
      nidx[k] = (4095 - (int)(unsigned)(v & 0xFFFFFFFFull)) & (N_ - 1);
      if (lane == ln) {
#pragma unroll
        for (int s = 0; s < K_ - 1; ++s) q[s] = q[s + 1];
        q[K_ - 1] = 0ull;
      }
    }
  }

  // ---- Phase 3: rel_pos/cov/eig/gfeat (global reads, byte-identical math) ----
  float c00 = 0, c01 = 0, c02 = 0, c11 = 0, c12 = 0, c22 = 0;
  float mrx = 0, mry = 0, mrz = 0, md = 0;
#pragma unroll
  for (int k = 0; k < K_; ++k) {
    const int j = nidx[k];
    const float rx = __fsub_rn(xb[3 * j], qx);
    const float ry = __fsub_rn(xb[3 * j + 1], qy);
    const float rz = __fsub_rn(xb[3 * j + 2], qz);
    c00 = __fadd_rn(c00, __fmul_rn(rx, rx));
    c01 = __fadd_rn(c01, __fmul_rn(rx, ry));
    c02 = __fadd_rn(c02, __fmul_rn(rx, rz));
    c11 = __fadd_rn(c11, __fmul_rn(ry, ry));
    c12 = __fadd_rn(c12, __fmul_rn(ry, rz));
    c22 = __fadd_rn(c22, __fmul_rn(rz, rz));
    mrx = __fadd_rn(mrx, rx);
    mry = __fadd_rn(mry, ry);
    mrz = __fadd_rn(mrz, rz);
    const float nn = __fadd_rn(__fadd_rn(__fmul_rn(rx, rx), __fmul_rn(ry, ry)),
                               __fmul_rn(rz, rz));
    md = __fadd_rn(md, sqrtf(nn));
  }
  const float s16 = 0.0625f;
  float Z[3][3];
  eig3_f(__fmul_rn(c00, s16), __fmul_rn(c01, s16), __fmul_rn(c02, s16),
         __fmul_rn(c11, s16), __fmul_rn(c12, s16), __fmul_rn(c22, s16), Z);
  float gf[10];
  gf[0] = Z[0][0]; gf[1] = Z[1][0]; gf[2] = Z[2][0];
  gf[3] = Z[0][2]; gf[4] = Z[1][2]; gf[5] = Z[2][2];
  gf[6] = __fmul_rn(mrx, s16); gf[7] = __fmul_rn(mry, s16);
  gf[8] = __fmul_rn(mrz, s16);
  gf[9] = __fmul_rn(md, s16);

  // ---- Phase 4: geo MLP, weights staged in LDS (gw1@0, gw2@640 dwords) ----
  {
    if (tid < 160) sm.w4[tid] = ((const float4*)geo_w1)[tid];
#pragma unroll
    for (int m = 0; m < 4; ++m)
      sm.w4[160 + m * 256 + tid] = ((const float4*)geo_w2)[m * 256 + tid];
  }
  __syncthreads();
  float acc = 0.0f;
#pragma unroll
  for (int ii = 0; ii < 10; ++ii) acc += gf[ii] * sm.w[ii * 64 + lane];
  acc += geo_b1[lane];
  float yr;
  {
    float m = wave_sum64(acc) * (1.0f / 64.0f);
    float xm = acc - m;
    float var = wave_sum64(xm * xm) * (1.0f / 64.0f);
    float yv = xm * (1.0f / sqrtf(var + 1e-5f)) * geo_g1[lane] + geo_be1[lane];
    yr = fmaxf(yv, 0.0f);
  }
  float ge = 0.0f;
#pragma unroll 8
  for (int jj = 0; jj < 64; ++jj)
    ge += __shfl(yr, jj, 64) * sm.w[640 + jj * 64 + lane];
  ge += geo_b2[lane];
  __syncthreads();   // done reading geo weights

  // ---- Phase 5: feat_diff + diff MLP (diff_w1 staged: 8192 dwords) ----
  const float* fb = feats + (size_t)b * N_ * C_;
  const float* fi = fb + (size_t)i * C_;
  const float f0 = fi[lane];
  const float f1 = fi[64 + lane];
  float s0 = 0.0f, s1 = 0.0f;
#pragma unroll
  for (int k = 0; k < K_; ++k) {
    const float* fj = fb + (size_t)nidx[k] * C_;
    s0 += fabsf(f0 - fj[lane]);
    s1 += fabsf(f1 - fj[64 + lane]);
  }
  s0 *= (1.0f / 16.0f);
  s1 *= (1.0f / 16.0f);
  {
#pragma unroll
    for (int m = 0; m < 8; ++m)
      sm.w4[m * 256 + tid] = ((const float4*)diff_w1)[m * 256 + tid];
  }
  __syncthreads();
  float acc2 = 0.0f;
#pragma unroll 8
  for (int c = 0; c < 64; ++c) acc2 += __shfl(s0, c, 64) * sm.w[c * 64 + lane];
#pragma unroll 8
  for (int c = 64; c < 128; ++c) acc2 += __shfl(s1, c - 64, 64) * sm.w[c * 64 + lane];
  acc2 += diff_b1[lane];
  float yr2;
  {
    float m = wave_sum64(acc2) * (1.0f / 64.0f);
    float xm = acc2 - m;
    float var = wave_sum64(xm * xm) * (1.0f / 64.0f);
    float yv = xm * (1.0f / sqrtf(var + 1e-5f)) * diff_g1[lane] + diff_be1[lane];
    yr2 = fmaxf(yv, 0.0f);
  }
  __syncthreads();   // done reading diff_w1
  // stage diff_w2 (@0, 4096 dw) + ep_w1 (@4096 dw)
  {
#pragma unroll
    for (int m = 0; m < 4; ++m)
      sm.w4[m * 256 + tid] = ((const float4*)diff_w2)[m * 256 + tid];
#pragma unroll
    for (int m = 0; m < 4; ++m)
      sm.w4[1024 + m * 256 + tid] = ((const float4*)ep_w1)[m * 256 + tid];
  }
  __syncthreads();
  float de = 0.0f;
#pragma unroll 8
  for (int jj = 0; jj < 64; ++jj)
    de += __shfl(yr2, jj, 64) * sm.w[jj * 64 + lane];
  de += diff_b2[lane];

  // ---- Phase 6: edge prob (ep_w1 from LDS), then ref matvec in 4 chunks ----
  const int u = lane & 31;
  float a = 0.0f;
#pragma unroll 8
  for (int c = 0; c < 64; ++c) a += __shfl(ge, c, 64) * sm.w[4096 + c * 32 + u];
#pragma unroll 8
  for (int c = 64; c < 128; ++c)
    a += __shfl(de, c - 64, 64) * sm.w[4096 + c * 32 + u];
  a += ep_b1[u];
  float hh = (lane < 32) ? fmaxf(a, 0.0f) * ep_w2[u] : 0.0f;
  float tsum = wave_sum64(hh) + ep_b2[0];
  float prob = 1.0f / (1.0f + expf(-tsum));

  const float gep = ge * prob;
  const float dep = de * prob;
  float a0 = 0.0f, a1 = 0.0f;
  for (int ch = 0; ch < 4; ++ch) {
    __syncthreads();   // prior readers (ep / previous chunk) done
    {
      const float4* g = (const float4*)(ref_w1 + ch * 8192);
#pragma unroll
      for (int m = 0; m < 8; ++m) sm.w4[m * 256 + tid] = g[m * 256 + tid];
    }
    __syncthreads();
    const float ev = (ch == 0) ? f0 : (ch == 1) ? f1 : (ch == 2) ? gep : dep;
#pragma unroll 4
    for (int cl = 0; cl < 64; ++cl) {
      float ec = __shfl(ev, cl, 64);
      a0 += ec * sm.w[cl * 128 + lane];
      a1 += ec * sm.w[cl * 128 + 64 + lane];
    }
  }
  a0 += ref_b1[lane];
  a1 += ref_b1[64 + lane];
  float mm2 = wave_sum64(a0 + a1) * (1.0f / 128.0f);
  float d0 = a0 - mm2, d1 = a1 - mm2;
  float var2 = wave_sum64(d0 * d0 + d1 * d1) * (1.0f / 128.0f);
  float rs = 1.0f / sqrtf(var2 + 1e-5f);
  float y0 = d0 * rs * ref_g1[lane] + ref_be1[lane];
  float y1 = d1 * rs * ref_g1[64 + lane] + ref_be1[64 + lane];
  y0 = fmaxf(y0, 0.0f) + f0;
  y1 = fmaxf(y1, 0.0f) + f1;
  out[(size_t)p * 128 + lane] = y0;
  out[(size_t)p * 128 + 64 + lane] = y1;
  if (lane == 0) out_prob[p] = prob;
}

extern "C" void kernel_launch(void* const* d_in, const int* in_sizes, int n_in,
                              void* d_out, int out_size, void* d_ws, size_t ws_size,
                              hipStream_t stream) {
  const float* xyz = (const float*)d_in[0];
  const float* features = (const float*)d_in[1];
  const float* geo_w1 = (const float*)d_in[2];
  const float* geo_b1 = (const float*)d_in[3];
  const float* geo_g1 = (const float*)d_in[4];
  const float* geo_be1 = (const float*)d_in[5];
  const float* geo_w2 = (const float*)d_in[6];
  const float* geo_b2 = (const float*)d_in[7];
  const float* diff_w1 = (const float*)d_in[8];
  const float* diff_b1 = (const float*)d_in[9];
  const float* diff_g1 = (const float*)d_in[10];
  const float* diff_be1 = (const float*)d_in[11];
  const float* diff_w2 = (const float*)d_in[12];
  const float* diff_b2 = (const float*)d_in[13];
  const float* ep_w1 = (const float*)d_in[14];
  const float* ep_b1 = (const float*)d_in[15];
  const float* ep_w2 = (const float*)d_in[16];
  const float* ep_b2 = (const float*)d_in[17];
  const float* ref_w1 = (const float*)d_in[18];
  const float* ref_b1 = (const float*)d_in[19];
  const float* ref_g1 = (const float*)d_in[20];
  const float* ref_be1 = (const float*)d_in[21];

  float* out = (float*)d_out;
  float* out_prob = out + (size_t)NPT * C_;

  fused_kernel<<<dim3(NPT / 4), dim3(256), 0, stream>>>(
      xyz, features, geo_w1, geo_b1, geo_g1, geo_be1, geo_w2, geo_b2, diff_w1,
      diff_b1, diff_g1, diff_be1, diff_w2, diff_b2, ep_w1, ep_b1, ep_w2, ep_b2,
      ref_w1, ref_b1, ref_g1, ref_be1, out, out_prob);
}

// Round 10
// 443.702 us; speedup vs baseline: 1.2181x; 1.2181x over previous
//
#include <hip/hip_runtime.h>
#include <hip/hip_bf16.h>

// B=4, N=4096, C=128, K=16. float32 in/out. R8 fused: 450us, VALUBusy 48%.
// R9 (weight LDS staging) NEUTRAL => not weight-BW-bound; bottleneck is the
// per-wave shuffle/LDS instruction storm + serial chains, unattributable in
// one dispatch. R10: SPLIT.
//   Kernel A: KNN scan + tournament merge + cov/eig -> nidx,gf to d_ws.
//             (merge owner via pk[0]==v: no ln shuffles; no ballot guard.)
//   Kernel B: all MLPs, block-cooperative: 16 pts/block, weights staged once
//             per block in a 32KB LDS window, inputs via uniform-address LDS
//             broadcasts (zero ds_bpermute), LN per wave-owned point.
// MLP sums reassociate (tolerance-covered); KNN/eig math byte-identical.
// Fallback: if ws_size < 2MB, launch the proven R8 fused kernel.
#define N_ 4096
#define C_ 128
#define K_ 16
#define NPT 16384

__device__ __forceinline__ float wave_sum64(float v) {
#pragma unroll
  for (int off = 32; off >= 1; off >>= 1) v += __shfl_xor(v, off, 64);
  return v;
}

// ---------------- LAPACK f32 helpers ----------------

__device__ __forceinline__ float sign_f(float a, float b) {
  return copysignf(fabsf(a), b);
}

__device__ float lapy2_f(float x, float y) {
#pragma clang fp contract(off)
  float xa = fabsf(x), ya = fabsf(y);
  float w = fmaxf(xa, ya), z = fminf(xa, ya);
  if (z == 0.0f) return w;
  float t = z / w;
  return w * sqrtf(1.0f + t * t);
}

__device__ void lartg_f(float f, float g, float& c, float& s, float& r) {
#pragma clang fp contract(off)
  if (g == 0.0f) {
    c = 1.0f; s = 0.0f; r = f;
  } else if (f == 0.0f) {
    c = 0.0f; s = copysignf(1.0f, g); r = fabsf(g);
  } else {
    float d = sqrtf(f * f + g * g);
    c = fabsf(f) / d;
    r = sign_f(d, f);
    s = g / r;
  }
}

__device__ void laev2_f(float a, float b, float cc, float& rt1, float& rt2,
                        float& cs1, float& sn1) {
#pragma clang fp contract(off)
  float sm = a + cc;
  float df = a - cc;
  float adf = fabsf(df);
  float tb = b + b;
  float ab = fabsf(tb);
  float acmx, acmn;
  if (fabsf(a) > fabsf(cc)) { acmx = a; acmn = cc; } else { acmx = cc; acmn = a; }
  float rt;
  if (adf > ab) {
    float t = ab / adf; rt = adf * sqrtf(1.0f + t * t);
  } else if (adf < ab) {
    float t = adf / ab; rt = ab * sqrtf(1.0f + t * t);
  } else {
    rt = ab * sqrtf(2.0f);
  }
  int sgn1;
  if (sm < 0.0f) {
    rt1 = 0.5f * (sm - rt); sgn1 = -1;
    rt2 = (acmx / rt1) * acmn - (b / rt1) * b;
  } else if (sm > 0.0f) {
    rt1 = 0.5f * (sm + rt); sgn1 = 1;
    rt2 = (acmx / rt1) * acmn - (b / rt1) * b;
  } else {
    rt1 = 0.5f * rt; rt2 = -0.5f * rt; sgn1 = 1;
  }
  float cs; int sgn2;
  if (df >= 0.0f) { cs = df + rt; sgn2 = 1; } else { cs = df - rt; sgn2 = -1; }
  float acs = fabsf(cs);
  if (acs > ab) {
    float ct = -tb / cs;
    sn1 = 1.0f / sqrtf(1.0f + ct * ct);
    cs1 = ct * sn1;
  } else {
    if (ab == 0.0f) { cs1 = 1.0f; sn1 = 0.0f; }
    else {
      float tn = -cs / tb;
      cs1 = 1.0f / sqrtf(1.0f + tn * tn);
      sn1 = tn * cs1;
    }
  }
  if (sgn1 == sgn2) { float tn = cs1; cs1 = -sn1; sn1 = tn; }
}

__device__ void steqr3_f(float d[3], float e[2], float Z[3][3]) {
#pragma clang fp contract(off)
  const int n = 3;
  const float eps = 5.9604644775390625e-08f;
  const float eps2 = eps * eps;
  const float safmin = 1.17549435e-38f;
  const int nmaxit = n * 30;
  int jtot = 0;
  int l1 = 1;

  for (int og = 0; og < 16; ++og) {
    if (l1 > n) break;
    if (l1 > 1) e[l1 - 2] = 0.0f;
    int m, l, lend;
    if (l1 <= n - 1) {
      bool found = false;
      for (m = l1; m <= n - 1; ++m) {
        float tst = fabsf(e[m - 1]);
        if (tst == 0.0f) { found = true; break; }
        if (tst <= (sqrtf(fabsf(d[m - 1])) * sqrtf(fabsf(d[m]))) * eps) {
          e[m - 1] = 0.0f; found = true; break;
        }
      }
      if (!found) m = n;
    } else {
      m = n;
    }
    l = l1; lend = m; l1 = m + 1;
    if (lend == l) continue;
    if (fabsf(d[lend - 1]) < fabsf(d[l - 1])) { int t = l; l = lend; lend = t; }

    if (lend > l) {
      for (int it = 0; it < 128; ++it) {
        int mm;
        if (l != lend) {
          bool f2 = false;
          for (mm = l; mm <= lend - 1; ++mm) {
            float tst = e[mm - 1] * e[mm - 1];
            if (tst <= (eps2 * fabsf(d[mm - 1])) * fabsf(d[mm]) + safmin) { f2 = true; break; }
          }
          if (!f2) mm = lend;
        } else mm = lend;
        if (mm < lend) e[mm - 1] = 0.0f;
        float p = d[l - 1];
        if (mm == l) {
          d[l - 1] = p; ++l;
          if (l <= lend) continue;
          break;
        }
        if (mm == l + 1) {
          float rt1, rt2, cc, ss;
          laev2_f(d[l - 1], e[l - 1], d[l], rt1, rt2, cc, ss);
          for (int r = 0; r < n; ++r) {
            float temp = Z[r][l];
            Z[r][l] = cc * temp - ss * Z[r][l - 1];
            Z[r][l - 1] = ss * temp + cc * Z[r][l - 1];
          }
          d[l - 1] = rt1; d[l] = rt2; e[l - 1] = 0.0f;
          l += 2;
          if (l <= lend) continue;
          break;
        }
        if (jtot == nmaxit) break;
        ++jtot;
        float g = (d[l] - p) / (2.0f * e[l - 1]);
        float r = lapy2_f(g, 1.0f);
        g = d[mm - 1] - p + e[l - 1] / (g + sign_f(r, g));
        float s = 1.0f, c = 1.0f;
        p = 0.0f;
        float csv[2], snv[2];
        for (int i = mm - 1; i >= l; --i) {
          float f = s * e[i - 1];
          float bb = c * e[i - 1];
          lartg_f(g, f, c, s, r);
          if (i != mm - 1) e[i] = r;
          g = d[i] - p;
          r = (d[i - 1] - g) * s + 2.0f * c * bb;
          p = s * r;
          d[i] = g + p;
          g = c * r - bb;
          csv[i - l] = c;
          snv[i - l] = -s;
        }
        int mml = mm - l;
        for (int j = mml; j >= 1; --j) {
          float cc = csv[j - 1], ss = snv[j - 1];
          for (int r2 = 0; r2 < n; ++r2) {
            float temp = Z[r2][l + j - 1];
            Z[r2][l + j - 1] = cc * temp - ss * Z[r2][l + j - 2];
            Z[r2][l + j - 2] = ss * temp + cc * Z[r2][l + j - 2];
          }
        }
        d[l - 1] -= p;
        e[l - 1] = g;
      }
    } else {
      for (int it = 0; it < 128; ++it) {
        int mm;
        if (l != lend) {
          bool f2 = false;
          for (mm = l; mm >= lend + 1; --mm) {
            float tst = e[mm - 2] * e[mm - 2];
            if (tst <= (eps2 * fabsf(d[mm - 1])) * fabsf(d[mm - 2]) + safmin) { f2 = true; break; }
          }
          if (!f2) mm = lend;
        } else mm = lend;
        if (mm > lend) e[mm - 2] = 0.0f;
        float p = d[l - 1];
        if (mm == l) {
          d[l - 1] = p; --l;
          if (l >= lend) continue;
          break;
        }
        if (mm == l - 1) {
          float rt1, rt2, cc, ss;
          laev2_f(d[l - 2], e[l - 2], d[l - 1], rt1, rt2, cc, ss);
          for (int r = 0; r < n; ++r) {
            float temp = Z[r][l - 1];
            Z[r][l - 1] = cc * temp - ss * Z[r][l - 2];
            Z[r][l - 2] = ss * temp + cc * Z[r][l - 2];
          }
          d[l - 2] = rt1; d[l - 1] = rt2; e[l - 2] = 0.0f;
          l -= 2;
          if (l >= lend) continue;
          break;
        }
        if (jtot == nmaxit) break;
        ++jtot;
        float g = (d[l - 2] - p) / (2.0f * e[l - 2]);
        float r = lapy2_f(g, 1.0f);
        g = d[mm - 1] - p + e[l - 2] / (g + sign_f(r, g));
        float s = 1.0f, c = 1.0f;
        p = 0.0f;
        float csv[2], snv[2];
        for (int i = mm; i <= l - 1; ++i) {
          float f = s * e[i - 1];
          float bb = c * e[i - 1];
          lartg_f(g, f, c, s, r);
          if (i != mm) e[i - 2] = r;
          g = d[i - 1] - p;
          r = (d[i] - g) * s + 2.0f * c * bb;
          p = s * r;
          d[i - 1] = g + p;
          g = c * r - bb;
          csv[i - mm] = c;
          snv[i - mm] = s;
        }
        int lm = l - mm;
        for (int j = 1; j <= lm; ++j) {
          float cc = csv[j - 1], ss = snv[j - 1];
          for (int r2 = 0; r2 < n; ++r2) {
            float temp = Z[r2][mm + j - 1];
            Z[r2][mm + j - 1] = cc * temp - ss * Z[r2][mm + j - 2];
            Z[r2][mm + j - 2] = ss * temp + cc * Z[r2][mm + j - 2];
          }
        }
        d[l - 1] -= p;
        e[l - 2] = g;
      }
    }
  }
  for (int ii = 2; ii <= n; ++ii) {
    int i = ii - 1, k = i;
    float p = d[i - 1];
    for (int j = ii; j <= n; ++j) {
      if (d[j - 1] < p) { k = j; p = d[j - 1]; }
    }
    if (k != i) {
      d[k - 1] = d[i - 1]; d[i - 1] = p;
      for (int r = 0; r < n; ++r) {
        float t = Z[r][i - 1]; Z[r][i - 1] = Z[r][k - 1]; Z[r][k - 1] = t;
      }
    }
  }
}

__device__ void eig3_f(float A00, float A10, float A20,
                       float A11, float A21, float A22, float Z[3][3]) {
#pragma clang fp contract(off)
  float d[3], e[2];
  float tau = 0.0f, v2 = 0.0f;
  d[0] = A00;
  float xnorm = fabsf(A20);
  if (xnorm == 0.0f) {
    tau = 0.0f; v2 = 0.0f;
    e[0] = A10; d[1] = A11; e[1] = A21; d[2] = A22;
  } else {
    float beta = -sign_f(lapy2_f(A10, xnorm), A10);
    tau = (beta - A10) / beta;
    float inv = 1.0f / (A10 - beta);
    v2 = A20 * inv;
    e[0] = beta;
    float x0 = tau * A11;
    float x1 = tau * A21;
    float tmp2 = A21 * v2;
    x0 = x0 + tau * tmp2;
    x1 = x1 + (tau * v2) * A22;
    float dotv = x0 + x1 * v2;
    float aw = (-0.5f * tau) * dotv;
    float w0 = x0 + aw;
    float w1 = x1 + aw * v2;
    d[1] = (A11 - w0) - w0;
    float pq = v2 * w0;
    e[1] = (A21 - pq) - w1;
    float pr = v2 * w1;
    d[2] = (A22 - pr) - pr;
  }
  Z[0][0] = 1.0f; Z[0][1] = 0.0f; Z[0][2] = 0.0f;
  Z[1][0] = 0.0f; Z[1][1] = 1.0f; Z[1][2] = 0.0f;
  Z[2][0] = 0.0f; Z[2][1] = 0.0f; Z[2][2] = 1.0f;
  steqr3_f(d, e, Z);
  if (tau != 0.0f) {
    for (int j = 0; j < 3; ++j) {
      float sum = Z[1][j] + v2 * Z[2][j];
      float tw = tau * sum;
      Z[1][j] = Z[1][j] - tw;
      Z[2][j] = Z[2][j] - v2 * tw;
    }
  }
}

// ---------------- KNN distance helper (numpy-f32-faithful) ----------------
__device__ __forceinline__ unsigned long long knn_key(float qx, float qy, float qz,
                                                      float nqxx, float x, float y,
                                                      float z, int j) {
  const float dot = __fmaf_rn(qz, z, __fmaf_rn(qy, y, __fmul_rn(qx, x)));
  const float xxj =
      __fadd_rn(__fadd_rn(__fmul_rn(x, x), __fmul_rn(y, y)), __fmul_rn(z, z));
  const float inner = __fmul_rn(-2.0f, dot);
  const float pval = __fsub_rn(__fsub_rn(nqxx, inner), xxj);
  const unsigned bits = __float_as_uint(pval);
  const unsigned ordv = bits ^ (unsigned)(((int)bits >> 31) | 0x80000000);
  return ((unsigned long long)ordv << 32) | (unsigned)(4095 - j);
}

// ---------------- Kernel A: KNN + merge + cov/eig -> d_ws ----------------
__global__ __launch_bounds__(256) void knn_geo_kernel(
    const float* __restrict__ xyz, int* __restrict__ nidx_ws,
    float* __restrict__ gf_ws) {
  __shared__ float4 tile4[1024];   // 16 KB

  const int wave = threadIdx.x >> 6;
  const int lane = threadIdx.x & 63;
  const int tid = threadIdx.x;
  const int p = blockIdx.x * 4 + wave;
  const int b = p >> 12;
  const int i = p & 4095;
  const float* xb = xyz + (size_t)b * (N_ * 3);

  const float qx = xb[3 * i];
  const float qy = xb[3 * i + 1];
  const float qz = xb[3 * i + 2];
  const float qxx =
      __fadd_rn(__fadd_rn(__fmul_rn(qx, qx), __fmul_rn(qy, qy)), __fmul_rn(qz, qz));
  const float nqxx = -qxx;

  unsigned long long pk[4] = {0ull, 0ull, 0ull, 0ull};

  for (int tile = 0; tile < 4; ++tile) {
    {
      const float4* gsrc = (const float4*)(xb + tile * 3072);
      float4 r0 = gsrc[tid * 3];
      float4 r1 = gsrc[tid * 3 + 1];
      float4 r2 = gsrc[tid * 3 + 2];
      const int base = tid * 4;
      tile4[base]     = make_float4(r0.x, r0.y, r0.z, 0.0f);
      tile4[base + 1] = make_float4(r0.w, r1.x, r1.y, 0.0f);
      tile4[base + 2] = make_float4(r1.z, r1.w, r2.x, 0.0f);
      tile4[base + 3] = make_float4(r2.y, r2.z, r2.w, 0.0f);
    }
    __syncthreads();

#pragma unroll 4
    for (int tloc = 0; tloc < 16; ++tloc) {
      const int j = tile * 1024 + tloc * 64 + lane;
      const float4 pt = tile4[tloc * 64 + lane];
      const unsigned long long key = knn_key(qx, qy, qz, nqxx, pt.x, pt.y, pt.z, j);
      const bool c0 = key > pk[0], c1 = key > pk[1], c2 = key > pk[2], c3 = key > pk[3];
      pk[3] = c3 ? (c2 ? pk[2] : key) : pk[3];
      pk[2] = c2 ? (c1 ? pk[1] : key) : pk[2];
      pk[1] = c1 ? (c0 ? pk[0] : key) : pk[1];
      pk[0] = c0 ? key : pk[0];
    }
    __syncthreads();
  }

  // merge: 16 pops; owner found by pk[0]==v (keys globally distinct)
  int nidx[K_];
  int stash = 0;
  int h = 0;
#pragma unroll
  for (int k = 0; k < K_; ++k) {
    unsigned long long v = pk[0];
#pragma unroll
    for (int off = 32; off >= 1; off >>= 1) {
      unsigned long long ov = __shfl_xor(v, off, 64);
      if (ov > v) v = ov;
    }
    const int jidx = (4095 - (int)(unsigned)(v & 0xFFFFFFFFull)) & (N_ - 1);
    nidx[k] = jidx;
    if (lane == k) stash = jidx;
    if (pk[0] == v) {
      pk[0] = pk[1]; pk[1] = pk[2]; pk[2] = pk[3]; pk[3] = 0ull;
      ++h;
    }
  }
  // exact fallback (rare, wave-uniform)
  if (__ballot(h >= 4) != 0ull) {
    unsigned long long q[K_];
#pragma unroll
    for (int k = 0; k < K_; ++k) q[k] = 0ull;
    for (int t = 0; t < 64; ++t) {
      const int j = t * 64 + lane;
      const unsigned long long key =
          knn_key(qx, qy, qz, nqxx, xb[3 * j], xb[3 * j + 1], xb[3 * j + 2], j);
      bool c[K_];
#pragma unroll
      for (int s = 0; s < K_; ++s) c[s] = key > q[s];
#pragma unroll
      for (int s = K_ - 1; s >= 1; --s)
        q[s] = c[s] ? (c[s - 1] ? q[s - 1] : key) : q[s];
      q[0] = c[0] ? key : q[0];
    }
#pragma unroll
    for (int k = 0; k < K_; ++k) {
      unsigned long long v = q[0];
#pragma unroll
      for (int off = 32; off >= 1; off >>= 1) {
        unsigned long long ov = __shfl_xor(v, off, 64);
        if (ov > v) v = ov;
      }
      const int jidx = (4095 - (int)(unsigned)(v & 0xFFFFFFFFull)) & (N_ - 1);
      nidx[k] = jidx;
      if (lane == k) stash = jidx;
      if (q[0] == v) {
#pragma unroll
        for (int s = 0; s < K_ - 1; ++s) q[s] = q[s + 1];
        q[K_ - 1] = 0ull;
      }
    }
  }

  // cov/eig/gfeat (byte-identical math)
  float c00 = 0, c01 = 0, c02 = 0, c11 = 0, c12 = 0, c22 = 0;
  float mrx = 0, mry = 0, mrz = 0, md = 0;
#pragma unroll
  for (int k = 0; k < K_; ++k) {
    const int j = nidx[k];
    const float rx = __fsub_rn(xb[3 * j], qx);
    const float ry = __fsub_rn(xb[3 * j + 1], qy);
    const float rz = __fsub_rn(xb[3 * j + 2], qz);
    c00 = __fadd_rn(c00, __fmul_rn(rx, rx));
    c01 = __fadd_rn(c01, __fmul_rn(rx, ry));
    c02 = __fadd_rn(c02, __fmul_rn(rx, rz));
    c11 = __fadd_rn(c11, __fmul_rn(ry, ry));
    c12 = __fadd_rn(c12, __fmul_rn(ry, rz));
    c22 = __fadd_rn(c22, __fmul_rn(rz, rz));
    mrx = __fadd_rn(mrx, rx);
    mry = __fadd_rn(mry, ry);
    mrz = __fadd_rn(mrz, rz);
    const float nn = __fadd_rn(__fadd_rn(__fmul_rn(rx, rx), __fmul_rn(ry, ry)),
                               __fmul_rn(rz, rz));
    md = __fadd_rn(md, sqrtf(nn));
  }
  const float s16 = 0.0625f;
  float Z[3][3];
  eig3_f(__fmul_rn(c00, s16), __fmul_rn(c01, s16), __fmul_rn(c02, s16),
         __fmul_rn(c11, s16), __fmul_rn(c12, s16), __fmul_rn(c22, s16), Z);
  float gf[10];
  gf[0] = Z[0][0]; gf[1] = Z[1][0]; gf[2] = Z[2][0];
  gf[3] = Z[0][2]; gf[4] = Z[1][2]; gf[5] = Z[2][2];
  gf[6] = __fmul_rn(mrx, s16); gf[7] = __fmul_rn(mry, s16);
  gf[8] = __fmul_rn(mrz, s16);
  gf[9] = __fmul_rn(md, s16);

  if (lane < K_) nidx_ws[(size_t)p * K_ + lane] = stash;
  if (lane == 0) {
    float* g = gf_ws + (size_t)p * 12;
#pragma unroll
    for (int ii = 0; ii < 10; ++ii) g[ii] = gf[ii];
  }
}

// ---------------- Kernel B: block-cooperative MLPs (16 pts/block) ----------------
__global__ __launch_bounds__(256) void mlp_kernel(
    const float* __restrict__ feats, const int* __restrict__ nidx_ws,
    const float* __restrict__ gf_ws,
    const float* __restrict__ geo_w1, const float* __restrict__ geo_b1,
    const float* __restrict__ geo_g1, const float* __restrict__ geo_be1,
    const float* __restrict__ geo_w2, const float* __restrict__ geo_b2,
    const float* __restrict__ diff_w1, const float* __restrict__ diff_b1,
    const float* __restrict__ diff_g1, const float* __restrict__ diff_be1,
    const float* __restrict__ diff_w2, const float* __restrict__ diff_b2,
    const float* __restrict__ ep_w1, const float* __restrict__ ep_b1,
    const float* __restrict__ ep_w2, const float* __restrict__ ep_b2,
    const float* __restrict__ ref_w1, const float* __restrict__ ref_b1,
    const float* __restrict__ ref_g1, const float* __restrict__ ref_be1,
    float* __restrict__ out, float* __restrict__ out_prob) {

  __shared__ float w[8192];        // 32 KB weight window
  __shared__ float fsh[16 * 128];  // 8 KB  features of the 16 points
  __shared__ float sdif[16 * 128]; // 8 KB  feat_diff
  __shared__ float ysh[16 * 64];   // 4 KB  hidden activations (reused)
  __shared__ float edsh[16 * 128]; // 8 KB  [ge||de] then [ge||de]*prob
  __shared__ float insh[16 * 12];  // gf inputs
  __shared__ int nsh[16 * 16];     // neighbor indices

  const int tid = threadIdx.x;
  const int lane = tid & 63;
  const int g = tid >> 6;
  const int P0 = blockIdx.x * 16;
  const int b = P0 >> 12;
  const int r0 = P0 & 4095;
  const float* fb = feats + (size_t)b * N_ * C_;

  // stage inputs + geo weights
  if (tid < 192) insh[tid] = gf_ws[(size_t)P0 * 12 + tid];
  nsh[tid] = nidx_ws[(size_t)P0 * K_ + tid];
#pragma unroll
  for (int m = 0; m < 8; ++m)
    fsh[m * 256 + tid] = fb[(size_t)r0 * C_ + m * 256 + tid];
  if (tid < 160) ((float4*)w)[tid] = ((const float4*)geo_w1)[tid];
#pragma unroll
  for (int m = 0; m < 4; ++m)
    ((float4*)(w + 640))[m * 256 + tid] = ((const float4*)geo_w2)[m * 256 + tid];
  __syncthreads();

  // geo layer 1 + LN (wave g owns points 4g..4g+3)
#pragma unroll
  for (int ptl = 0; ptl < 4; ++ptl) {
    const int pt = g * 4 + ptl;
    float acc = 0.0f;
#pragma unroll
    for (int c = 0; c < 10; ++c) acc += insh[pt * 12 + c] * w[c * 64 + lane];
    acc += geo_b1[lane];
    float m = wave_sum64(acc) * (1.0f / 64.0f);
    float xm = acc - m;
    float var = wave_sum64(xm * xm) * (1.0f / 64.0f);
    float yv = xm * (1.0f / sqrtf(var + 1e-5f)) * geo_g1[lane] + geo_be1[lane];
    ysh[pt * 64 + lane] = fmaxf(yv, 0.0f);
  }
  __syncthreads();

  // geo layer 2
  float ge[4], de[4], prob[4];
#pragma unroll
  for (int ptl = 0; ptl < 4; ++ptl) {
    const int pt = g * 4 + ptl;
    float acc = 0.0f;
#pragma unroll 8
    for (int c = 0; c < 64; ++c) acc += ysh[pt * 64 + c] * w[640 + c * 64 + lane];
    ge[ptl] = acc + geo_b2[lane];
  }

  // feat_diff: threads (h2, c), 8 pts each
  {
    const int h2 = tid >> 7, c = tid & 127;
    for (int ptp = 0; ptp < 8; ++ptp) {
      const int pt = h2 * 8 + ptp;
      const float fv = fsh[pt * 128 + c];
      float s = 0.0f;
#pragma unroll
      for (int k = 0; k < K_; ++k) {
        const int j = nsh[pt * 16 + k];
        s += fabsf(fv - fb[(size_t)j * C_ + c]);
      }
      sdif[pt * 128 + c] = s * (1.0f / 16.0f);
    }
  }
  __syncthreads();   // geo window reads done + sdif visible
#pragma unroll
  for (int m = 0; m < 8; ++m)
    ((float4*)w)[m * 256 + tid] = ((const float4*)diff_w1)[m * 256 + tid];
  __syncthreads();

  // diff layer 1 + LN
#pragma unroll
  for (int ptl = 0; ptl < 4; ++ptl) {
    const int pt = g * 4 + ptl;
    float acc = 0.0f;
#pragma unroll 8
    for (int c = 0; c < 128; ++c) acc += sdif[pt * 128 + c] * w[c * 64 + lane];
    acc += diff_b1[lane];
    float m = wave_sum64(acc) * (1.0f / 64.0f);
    float xm = acc - m;
    float var = wave_sum64(xm * xm) * (1.0f / 64.0f);
    float yv = xm * (1.0f / sqrtf(var + 1e-5f)) * diff_g1[lane] + diff_be1[lane];
    ysh[pt * 64 + lane] = fmaxf(yv, 0.0f);
  }
  __syncthreads();   // diff_w1 reads done + ysh visible
#pragma unroll
  for (int m = 0; m < 4; ++m)
    ((float4*)w)[m * 256 + tid] = ((const float4*)diff_w2)[m * 256 + tid];
#pragma unroll
  for (int m = 0; m < 4; ++m)
    ((float4*)w)[1024 + m * 256 + tid] = ((const float4*)ep_w1)[m * 256 + tid];
  __syncthreads();

  // diff layer 2, stash [ge||de] for ep
#pragma unroll
  for (int ptl = 0; ptl < 4; ++ptl) {
    const int pt = g * 4 + ptl;
    float acc = 0.0f;
#pragma unroll 8
    for (int c = 0; c < 64; ++c) acc += ysh[pt * 64 + c] * w[c * 64 + lane];
    de[ptl] = acc + diff_b2[lane];
    edsh[pt * 128 + lane] = ge[ptl];
    edsh[pt * 128 + 64 + lane] = de[ptl];
  }
  __syncthreads();

  // edge-prob MLP
  const int u = lane & 31;
#pragma unroll
  for (int ptl = 0; ptl < 4; ++ptl) {
    const int pt = g * 4 + ptl;
    float a = 0.0f;
#pragma unroll 8
    for (int c = 0; c < 128; ++c) a += edsh[pt * 128 + c] * w[4096 + c * 32 + u];
    a += ep_b1[u];
    float hh = (lane < 32) ? fmaxf(a, 0.0f) * ep_w2[u] : 0.0f;
    float tsum = wave_sum64(hh) + ep_b2[0];
    prob[ptl] = 1.0f / (1.0f + expf(-tsum));
  }
  __syncthreads();   // ep reads of edsh done
#pragma unroll
  for (int ptl = 0; ptl < 4; ++ptl) {
    const int pt = g * 4 + ptl;
    edsh[pt * 128 + lane] = ge[ptl] * prob[ptl];
    edsh[pt * 128 + 64 + lane] = de[ptl] * prob[ptl];
  }

  // ref matvec: 4 chunks of 64 input-channels (32 KB each)
  float a0[4] = {0, 0, 0, 0}, a1[4] = {0, 0, 0, 0};
  for (int ch = 0; ch < 4; ++ch) {
    __syncthreads();   // edsh visible (ch0) / prior chunk reads done
    {
      const float4* gsrc = (const float4*)(ref_w1 + ch * 8192);
#pragma unroll
      for (int m = 0; m < 8; ++m) ((float4*)w)[m * 256 + tid] = gsrc[m * 256 + tid];
    }
    __syncthreads();
#pragma unroll
    for (int ptl = 0; ptl < 4; ++ptl) {
      const int pt = g * 4 + ptl;
      const float* src = (ch < 2) ? &fsh[pt * 128 + ch * 64]
                                  : &edsh[pt * 128 + (ch - 2) * 64];
#pragma unroll 4
      for (int cl = 0; cl < 64; ++cl) {
        const float e = src[cl];
        a0[ptl] += e * w[cl * 128 + lane];
        a1[ptl] += e * w[cl * 128 + 64 + lane];
      }
    }
  }

  // epilogue
#pragma unroll
  for (int ptl = 0; ptl < 4; ++ptl) {
    const int pt = g * 4 + ptl;
    float A0 = a0[ptl] + ref_b1[lane];
    float A1 = a1[ptl] + ref_b1[64 + lane];
    float mm2 = wave_sum64(A0 + A1) * (1.0f / 128.0f);
    float d0 = A0 - mm2, d1 = A1 - mm2;
    float var2 = wave_sum64(d0 * d0 + d1 * d1) * (1.0f / 128.0f);
    float rs = 1.0f / sqrtf(var2 + 1e-5f);
    float y0 = d0 * rs * ref_g1[lane] + ref_be1[lane];
    float y1 = d1 * rs * ref_g1[64 + lane] + ref_be1[64 + lane];
    y0 = fmaxf(y0, 0.0f) + fsh[pt * 128 + lane];
    y1 = fmaxf(y1, 0.0f) + fsh[pt * 128 + 64 + lane];
    out[(size_t)(P0 + pt) * 128 + lane] = y0;
    out[(size_t)(P0 + pt) * 128 + 64 + lane] = y1;
    if (lane == 0) out_prob[P0 + pt] = prob[ptl];
  }
}

// ---------------- Fallback: R8 fused kernel (proven, 450us) ----------------
__global__ __launch_bounds__(256) void fused_kernel(
    const float* __restrict__ xyz, const float* __restrict__ feats,
    const float* __restrict__ geo_w1, const float* __restrict__ geo_b1,
    const float* __restrict__ geo_g1, const float* __restrict__ geo_be1,
    const float* __restrict__ geo_w2, const float* __restrict__ geo_b2,
    const float* __restrict__ diff_w1, const float* __restrict__ diff_b1,
    const float* __restrict__ diff_g1, const float* __restrict__ diff_be1,
    const float* __restrict__ diff_w2, const float* __restrict__ diff_b2,
    const float* __restrict__ ep_w1, const float* __restrict__ ep_b1,
    const float* __restrict__ ep_w2, const float* __restrict__ ep_b2,
    const float* __restrict__ ref_w1, const float* __restrict__ ref_b1,
    const float* __restrict__ ref_g1, const float* __restrict__ ref_be1,
    float* __restrict__ out, float* __restrict__ out_prob) {

  __shared__ float4 tile4[1024];

  const int wave = threadIdx.x >> 6;
  const int lane = threadIdx.x & 63;
  const int tid = threadIdx.x;
  const int p = blockIdx.x * 4 + wave;
  const int b = p >> 12;
  const int i = p & 4095;
  const float* xb = xyz + (size_t)b * (N_ * 3);

  const float qx = xb[3 * i];
  const float qy = xb[3 * i + 1];
  const float qz = xb[3 * i + 2];
  const float qxx =
      __fadd_rn(__fadd_rn(__fmul_rn(qx, qx), __fmul_rn(qy, qy)), __fmul_rn(qz, qz));
  const float nqxx = -qxx;

  unsigned long long pk[4] = {0ull, 0ull, 0ull, 0ull};
  for (int tile = 0; tile < 4; ++tile) {
    {
      const float4* gsrc = (const float4*)(xb + tile * 3072);
      float4 r0 = gsrc[tid * 3];
      float4 r1 = gsrc[tid * 3 + 1];
      float4 r2 = gsrc[tid * 3 + 2];
      const int base = tid * 4;
      tile4[base]     = make_float4(r0.x, r0.y, r0.z, 0.0f);
      tile4[base + 1] = make_float4(r0.w, r1.x, r1.y, 0.0f);
      tile4[base + 2] = make_float4(r1.z, r1.w, r2.x, 0.0f);
      tile4[base + 3] = make_float4(r2.y, r2.z, r2.w, 0.0f);
    }
    __syncthreads();
#pragma unroll 4
    for (int tloc = 0; tloc < 16; ++tloc) {
      const int j = tile * 1024 + tloc * 64 + lane;
      const float4 pt = tile4[tloc * 64 + lane];
      const unsigned long long key = knn_key(qx, qy, qz, nqxx, pt.x, pt.y, pt.z, j);
      const bool c0 = key > pk[0], c1 = key > pk[1], c2 = key > pk[2], c3 = key > pk[3];
      pk[3] = c3 ? (c2 ? pk[2] : key) : pk[3];
      pk[2] = c2 ? (c1 ? pk[1] : key) : pk[2];
      pk[1] = c1 ? (c0 ? pk[0] : key) : pk[1];
      pk[0] = c0 ? key : pk[0];
    }
    __syncthreads();
  }

  int nidx[K_];
  int h = 0;
#pragma unroll
  for (int k = 0; k < K_; ++k) {
    unsigned long long v = pk[0];
#pragma unroll
    for (int off = 32; off >= 1; off >>= 1) {
      unsigned long long ov = __shfl_xor(v, off, 64);
      if (ov > v) v = ov;
    }
    nidx[k] = (4095 - (int)(unsigned)(v & 0xFFFFFFFFull)) & (N_ - 1);
    if (pk[0] == v) {
      pk[0] = pk[1]; pk[1] = pk[2]; pk[2] = pk[3]; pk[3] = 0ull;
      ++h;
    }
  }
  if (__ballot(h >= 4) != 0ull) {
    unsigned long long q[K_];
#pragma unroll
    for (int k = 0; k < K_; ++k) q[k] = 0ull;
    for (int t = 0; t < 64; ++t) {
      const int j = t * 64 + lane;
      const unsigned long long key =
          knn_key(qx, qy, qz, nqxx, xb[3 * j], xb[3 * j + 1], xb[3 * j + 2], j);
      bool c[K_];
#pragma unroll
      for (int s = 0; s < K_; ++s) c[s] = key > q[s];
#pragma unroll
      for (int s = K_ - 1; s >= 1; --s)
        q[s] = c[s] ? (c[s - 1] ? q[s - 1] : key) : q[s];
      q[0] = c[0] ? key : q[0];
    }
#pragma unroll
    for (int k = 0; k < K_; ++k) {
      unsigned long long v = q[0];
#pragma unroll
      for (int off = 32; off >= 1; off >>= 1) {
        unsigned long long ov = __shfl_xor(v, off, 64);
        if (ov > v) v = ov;
      }
      nidx[k] = (4095 - (int)(unsigned)(v & 0xFFFFFFFFull)) & (N_ - 1);
      if (q[0] == v) {
#pragma unroll
        for (int s = 0; s < K_ - 1; ++s) q[s] = q[s + 1];
        q[K_ - 1] = 0ull;
      }
    }
  }

  float c00 = 0, c01 = 0, c02 = 0, c11 = 0, c12 = 0, c22 = 0;
  float mrx = 0, mry = 0, mrz = 0, md = 0;
#pragma unroll
  for (int k = 0; k < K_; ++k) {
    const int j = nidx[k];
    const float rx = __fsub_rn(xb[3 * j], qx);
    const float ry = __fsub_rn(xb[3 * j + 1], qy);
    const float rz = __fsub_rn(xb[3 * j + 2], qz);
    c00 = __fadd_rn(c00, __fmul_rn(rx, rx));
    c01 = __fadd_rn(c01, __fmul_rn(rx, ry));
    c02 = __fadd_rn(c02, __fmul_rn(rx, rz));
    c11 = __fadd_rn(c11, __fmul_rn(ry, ry));
    c12 = __fadd_rn(c12, __fmul_rn(ry, rz));
    c22 = __fadd_rn(c22, __fmul_rn(rz, rz));
    mrx = __fadd_rn(mrx, rx);
    mry = __fadd_rn(mry, ry);
    mrz = __fadd_rn(mrz, rz);
    const float nn = __fadd_rn(__fadd_rn(__fmul_rn(rx, rx), __fmul_rn(ry, ry)),
                               __fmul_rn(rz, rz));
    md = __fadd_rn(md, sqrtf(nn));
  }
  const float s16 = 0.0625f;
  float Z[3][3];
  eig3_f(__fmul_rn(c00, s16), __fmul_rn(c01, s16), __fmul_rn(c02, s16),
         __fmul_rn(c11, s16), __fmul_rn(c12, s16), __fmul_rn(c22, s16), Z);
  float gf[10];
  gf[0] = Z[0][0]; gf[1] = Z[1][0]; gf[2] = Z[2][0];
  gf[3] = Z[0][2]; gf[4] = Z[1][2]; gf[5] = Z[2][2];
  gf[6] = __fmul_rn(mrx, s16); gf[7] = __fmul_rn(mry, s16);
  gf[8] = __fmul_rn(mrz, s16);
  gf[9] = __fmul_rn(md, s16);

  float acc = 0.0f;
#pragma unroll
  for (int ii = 0; ii < 10; ++ii) acc += gf[ii] * geo_w1[ii * 64 + lane];
  acc += geo_b1[lane];
  float yr;
  {
    float m = wave_sum64(acc) * (1.0f / 64.0f);
    float xm = acc - m;
    float var = wave_sum64(xm * xm) * (1.0f / 64.0f);
    float yv = xm * (1.0f / sqrtf(var + 1e-5f)) * geo_g1[lane] + geo_be1[lane];
    yr = fmaxf(yv, 0.0f);
  }
  float ge = 0.0f;
#pragma unroll 8
  for (int jj = 0; jj < 64; ++jj) ge += __shfl(yr, jj, 64) * geo_w2[jj * 64 + lane];
  ge += geo_b2[lane];

  const float* fb = feats + (size_t)b * N_ * C_;
  const float* fi = fb + (size_t)i * C_;
  const float f0 = fi[lane];
  const float f1 = fi[64 + lane];
  float s0 = 0.0f, s1 = 0.0f;
#pragma unroll
  for (int k = 0; k < K_; ++k) {
    const float* fj = fb + (size_t)nidx[k] * C_;
    s0 += fabsf(f0 - fj[lane]);
    s1 += fabsf(f1 - fj[64 + lane]);
  }
  s0 *= (1.0f / 16.0f);
  s1 *= (1.0f / 16.0f);
  float acc2 = 0.0f;
#pragma unroll 8
  for (int c = 0; c < 64; ++c) acc2 += __shfl(s0, c, 64) * diff_w1[c * 64 + lane];
#pragma unroll 8
  for (int c = 64; c < 128; ++c) acc2 += __shfl(s1, c - 64, 64) * diff_w1[c * 64 + lane];
  acc2 += diff_b1[lane];
  float yr2;
  {
    float m = wave_sum64(acc2) * (1.0f / 64.0f);
    float xm = acc2 - m;
    float var = wave_sum64(xm * xm) * (1.0f / 64.0f);
    float yv = xm * (1.0f / sqrtf(var + 1e-5f)) * diff_g1[lane] + diff_be1[lane];
    yr2 = fmaxf(yv, 0.0f);
  }
  float de = 0.0f;
#pragma unroll 8
  for (int jj = 0; jj < 64; ++jj) de += __shfl(yr2, jj, 64) * diff_w2[jj * 64 + lane];
  de += diff_b2[lane];

  {
    const int u = lane & 31;
    float a = 0.0f;
#pragma unroll 8
    for (int c = 0; c < 64; ++c) a += __shfl(ge, c, 64) * ep_w1[c * 32 + u];
#pragma unroll 8
    for (int c = 64; c < 128; ++c) a += __shfl(de, c - 64, 64) * ep_w1[c * 32 + u];
    a += ep_b1[u];
    float hh = (lane < 32) ? fmaxf(a, 0.0f) * ep_w2[u] : 0.0f;
    float tsum = wave_sum64(hh) + ep_b2[0];
    float prob = 1.0f / (1.0f + expf(-tsum));

    const float gep = ge * prob;
    const float dep = de * prob;
    float a0 = 0.0f, a1 = 0.0f;
#pragma unroll 4
    for (int c = 0; c < 64; ++c) {
      float ec = __shfl(f0, c, 64);
      a0 += ec * ref_w1[c * 128 + lane];
      a1 += ec * ref_w1[c * 128 + 64 + lane];
    }
#pragma unroll 4
    for (int c = 64; c < 128; ++c) {
      float ec = __shfl(f1, c - 64, 64);
      a0 += ec * ref_w1[c * 128 + lane];
      a1 += ec * ref_w1[c * 128 + 64 + lane];
    }
#pragma unroll 4
    for (int c = 128; c < 192; ++c) {
      float ec = __shfl(gep, c - 128, 64);
      a0 += ec * ref_w1[c * 128 + lane];
      a1 += ec * ref_w1[c * 128 + 64 + lane];
    }
#pragma unroll 4
    for (int c = 192; c < 256; ++c) {
      float ec = __shfl(dep, c - 192, 64);
      a0 += ec * ref_w1[c * 128 + lane];
      a1 += ec * ref_w1[c * 128 + 64 + lane];
    }
    a0 += ref_b1[lane];
    a1 += ref_b1[64 + lane];
    float mm2 = wave_sum64(a0 + a1) * (1.0f / 128.0f);
    float d0 = a0 - mm2, d1 = a1 - mm2;
    float var2 = wave_sum64(d0 * d0 + d1 * d1) * (1.0f / 128.0f);
    float rs = 1.0f / sqrtf(var2 + 1e-5f);
    float y0 = d0 * rs * ref_g1[lane] + ref_be1[lane];
    float y1 = d1 * rs * ref_g1[64 + lane] + ref_be1[64 + lane];
    y0 = fmaxf(y0, 0.0f) + f0;
    y1 = fmaxf(y1, 0.0f) + f1;
    out[(size_t)p * 128 + lane] = y0;
    out[(size_t)p * 128 + 64 + lane] = y1;
    if (lane == 0) out_prob[p] = prob;
  }
}

extern "C" void kernel_launch(void* const* d_in, const int* in_sizes, int n_in,
                              void* d_out, int out_size, void* d_ws, size_t ws_size,
                              hipStream_t stream) {
  const float* xyz = (const float*)d_in[0];
  const float* features = (const float*)d_in[1];
  const float* geo_w1 = (const float*)d_in[2];
  const float* geo_b1 = (const float*)d_in[3];
  const float* geo_g1 = (const float*)d_in[4];
  const float* geo_be1 = (const float*)d_in[5];
  const float* geo_w2 = (const float*)d_in[6];
  const float* geo_b2 = (const float*)d_in[7];
  const float* diff_w1 = (const float*)d_in[8];
  const float* diff_b1 = (const float*)d_in[9];
  const float* diff_g1 = (const float*)d_in[10];
  const float* diff_be1 = (const float*)d_in[11];
  const float* diff_w2 = (const float*)d_in[12];
  const float* diff_b2 = (const float*)d_in[13];
  const float* ep_w1 = (const float*)d_in[14];
  const float* ep_b1 = (const float*)d_in[15];
  const float* ep_w2 = (const float*)d_in[16];
  const float* ep_b2 = (const float*)d_in[17];
  const float* ref_w1 = (const float*)d_in[18];
  const float* ref_b1 = (const float*)d_in[19];
  const float* ref_g1 = (const float*)d_in[20];
  const float* ref_be1 = (const float*)d_in[21];

  float* out = (float*)d_out;
  float* out_prob = out + (size_t)NPT * C_;

  if (ws_size >= (size_t)(2 * 1024 * 1024)) {
    int* nidx_ws = (int*)d_ws;                             // 16384*16*4 = 1 MB
    float* gf_ws = (float*)((char*)d_ws + (1u << 20));     // 16384*12*4 = 768 KB
    knn_geo_kernel<<<dim3(NPT / 4), dim3(256), 0, stream>>>(xyz, nidx_ws, gf_ws);
    mlp_kernel<<<dim3(NPT / 16), dim3(256), 0, stream>>>(
        features, nidx_ws, gf_ws, geo_w1, geo_b1, geo_g1, geo_be1, geo_w2,
        geo_b2, diff_w1, diff_b1, diff_g1, diff_be1, diff_w2, diff_b2, ep_w1,
        ep_b1, ep_w2, ep_b2, ref_w1, ref_b1, ref_g1, ref_be1, out, out_prob);
  } else {
    fused_kernel<<<dim3(NPT / 4), dim3(256), 0, stream>>>(
        xyz, features, geo_w1, geo_b1, geo_g1, geo_be1, geo_w2, geo_b2,
        diff_w1, diff_b1, diff_g1, diff_be1, diff_w2, diff_b2, ep_w1, ep_b1,
        ep_w2, ep_b2, ref_w1, ref_b1, ref_g1, ref_be1, out, out_prob);
  }
}

// Round 11
// 355.687 us; speedup vs baseline: 1.5195x; 1.2474x over previous
//
#include <hip/hip_runtime.h>
#include <hip/hip_bf16.h>

// B=4, N=4096, C=128, K=16. float32 in/out.
// R10 split: knn_geo 274us (VALUBusy 64%, latency-exposed serial chains),
// mlp ~160us, total 443us.
// R11: (1) knn_kernel: 4 query points per wave -- shared candidate read/xxj,
//      4 independent insertion chains (ILP), merge pops-outer/points-inner so
//      the 4 u64 butterflies interleave within shuffle latency. SoA tile
//      (0 conflicts). (2) cov+eig moved to per-thread eig_kernel (TLP hides
//      the serial branchy solver; own profiler line). (3) mlp_kernel as R10.
// All per-point arithmetic byte-identical (numpy-f32-faithful).
// Fallback to proven R8 fused kernel if ws_size < 2MB.
#define N_ 4096
#define C_ 128
#define K_ 16
#define NPT 16384

__device__ __forceinline__ float wave_sum64(float v) {
#pragma unroll
  for (int off = 32; off >= 1; off >>= 1) v += __shfl_xor(v, off, 64);
  return v;
}

// ---------------- LAPACK f32 helpers ----------------

__device__ __forceinline__ float sign_f(float a, float b) {
  return copysignf(fabsf(a), b);
}

__device__ float lapy2_f(float x, float y) {
#pragma clang fp contract(off)
  float xa = fabsf(x), ya = fabsf(y);
  float w = fmaxf(xa, ya), z = fminf(xa, ya);
  if (z == 0.0f) return w;
  float t = z / w;
  return w * sqrtf(1.0f + t * t);
}

__device__ void lartg_f(float f, float g, float& c, float& s, float& r) {
#pragma clang fp contract(off)
  if (g == 0.0f) {
    c = 1.0f; s = 0.0f; r = f;
  } else if (f == 0.0f) {
    c = 0.0f; s = copysignf(1.0f, g); r = fabsf(g);
  } else {
    float d = sqrtf(f * f + g * g);
    c = fabsf(f) / d;
    r = sign_f(d, f);
    s = g / r;
  }
}

__device__ void laev2_f(float a, float b, float cc, float& rt1, float& rt2,
                        float& cs1, float& sn1) {
#pragma clang fp contract(off)
  float sm = a + cc;
  float df = a - cc;
  float adf = fabsf(df);
  float tb = b + b;
  float ab = fabsf(tb);
  float acmx, acmn;
  if (fabsf(a) > fabsf(cc)) { acmx = a; acmn = cc; } else { acmx = cc; acmn = a; }
  float rt;
  if (adf > ab) {
    float t = ab / adf; rt = adf * sqrtf(1.0f + t * t);
  } else if (adf < ab) {
    float t = adf / ab; rt = ab * sqrtf(1.0f + t * t);
  } else {
    rt = ab * sqrtf(2.0f);
  }
  int sgn1;
  if (sm < 0.0f) {
    rt1 = 0.5f * (sm - rt); sgn1 = -1;
    rt2 = (acmx / rt1) * acmn - (b / rt1) * b;
  } else if (sm > 0.0f) {
    rt1 = 0.5f * (sm + rt); sgn1 = 1;
    rt2 = (acmx / rt1) * acmn - (b / rt1) * b;
  } else {
    rt1 = 0.5f * rt; rt2 = -0.5f * rt; sgn1 = 1;
  }
  float cs; int sgn2;
  if (df >= 0.0f) { cs = df + rt; sgn2 = 1; } else { cs = df - rt; sgn2 = -1; }
  float acs = fabsf(cs);
  if (acs > ab) {
    float ct = -tb / cs;
    sn1 = 1.0f / sqrtf(1.0f + ct * ct);
    cs1 = ct * sn1;
  } else {
    if (ab == 0.0f) { cs1 = 1.0f; sn1 = 0.0f; }
    else {
      float tn = -cs / tb;
      cs1 = 1.0f / sqrtf(1.0f + tn * tn);
      sn1 = tn * cs1;
    }
  }
  if (sgn1 == sgn2) { float tn = cs1; cs1 = -sn1; sn1 = tn; }
}

__device__ void steqr3_f(float d[3], float e[2], float Z[3][3]) {
#pragma clang fp contract(off)
  const int n = 3;
  const float eps = 5.9604644775390625e-08f;
  const float eps2 = eps * eps;
  const float safmin = 1.17549435e-38f;
  const int nmaxit = n * 30;
  int jtot = 0;
  int l1 = 1;

  for (int og = 0; og < 16; ++og) {
    if (l1 > n) break;
    if (l1 > 1) e[l1 - 2] = 0.0f;
    int m, l, lend;
    if (l1 <= n - 1) {
      bool found = false;
      for (m = l1; m <= n - 1; ++m) {
        float tst = fabsf(e[m - 1]);
        if (tst == 0.0f) { found = true; break; }
        if (tst <= (sqrtf(fabsf(d[m - 1])) * sqrtf(fabsf(d[m]))) * eps) {
          e[m - 1] = 0.0f; found = true; break;
        }
      }
      if (!found) m = n;
    } else {
      m = n;
    }
    l = l1; lend = m; l1 = m + 1;
    if (lend == l) continue;
    if (fabsf(d[lend - 1]) < fabsf(d[l - 1])) { int t = l; l = lend; lend = t; }

    if (lend > l) {
      for (int it = 0; it < 128; ++it) {
        int mm;
        if (l != lend) {
          bool f2 = false;
          for (mm = l; mm <= lend - 1; ++mm) {
            float tst = e[mm - 1] * e[mm - 1];
            if (tst <= (eps2 * fabsf(d[mm - 1])) * fabsf(d[mm]) + safmin) { f2 = true; break; }
          }
          if (!f2) mm = lend;
        } else mm = lend;
        if (mm < lend) e[mm - 1] = 0.0f;
        float p = d[l - 1];
        if (mm == l) {
          d[l - 1] = p; ++l;
          if (l <= lend) continue;
          break;
        }
        if (mm == l + 1) {
          float rt1, rt2, cc, ss;
          laev2_f(d[l - 1], e[l - 1], d[l], rt1, rt2, cc, ss);
          for (int r = 0; r < n; ++r) {
            float temp = Z[r][l];
            Z[r][l] = cc * temp - ss * Z[r][l - 1];
            Z[r][l - 1] = ss * temp + cc * Z[r][l - 1];
          }
          d[l - 1] = rt1; d[l] = rt2; e[l - 1] = 0.0f;
          l += 2;
          if (l <= lend) continue;
          break;
        }
        if (jtot == nmaxit) break;
        ++jtot;
        float g = (d[l] - p) / (2.0f * e[l - 1]);
        float r = lapy2_f(g, 1.0f);
        g = d[mm - 1] - p + e[l - 1] / (g + sign_f(r, g));
        float s = 1.0f, c = 1.0f;
        p = 0.0f;
        float csv[2], snv[2];
        for (int i = mm - 1; i >= l; --i) {
          float f = s * e[i - 1];
          float bb = c * e[i - 1];
          lartg_f(g, f, c, s, r);
          if (i != mm - 1) e[i] = r;
          g = d[i] - p;
          r = (d[i - 1] - g) * s + 2.0f * c * bb;
          p = s * r;
          d[i] = g + p;
          g = c * r - bb;
          csv[i - l] = c;
          snv[i - l] = -s;
        }
        int mml = mm - l;
        for (int j = mml; j >= 1; --j) {
          float cc = csv[j - 1], ss = snv[j - 1];
          for (int r2 = 0; r2 < n; ++r2) {
            float temp = Z[r2][l + j - 1];
            Z[r2][l + j - 1] = cc * temp - ss * Z[r2][l + j - 2];
            Z[r2][l + j - 2] = ss * temp + cc * Z[r2][l + j - 2];
          }
        }
        d[l - 1] -= p;
        e[l - 1] = g;
      }
    } else {
      for (int it = 0; it < 128; ++it) {
        int mm;
        if (l != lend) {
          bool f2 = false;
          for (mm = l; mm >= lend + 1; --mm) {
            float tst = e[mm - 2] * e[mm - 2];
            if (tst <= (eps2 * fabsf(d[mm - 1])) * fabsf(d[mm - 2]) + safmin) { f2 = true; break; }
          }
          if (!f2) mm = lend;
        } else mm = lend;
        if (mm > lend) e[mm - 2] = 0.0f;
        float p = d[l - 1];
        if (mm == l) {
          d[l - 1] = p; --l;
          if (l >= lend) continue;
          break;
        }
        if (mm == l - 1) {
          float rt1, rt2, cc, ss;
          laev2_f(d[l - 2], e[l - 2], d[l - 1], rt1, rt2, cc, ss);
          for (int r = 0; r < n; ++r) {
            float temp = Z[r][l - 1];
            Z[r][l - 1] = cc * temp - ss * Z[r][l - 2];
            Z[r][l - 2] = ss * temp + cc * Z[r][l - 2];
          }
          d[l - 2] = rt1; d[l - 1] = rt2; e[l - 2] = 0.0f;
          l -= 2;
          if (l >= lend) continue;
          break;
        }
        if (jtot == nmaxit) break;
        ++jtot;
        float g = (d[l - 2] - p) / (2.0f * e[l - 2]);
        float r = lapy2_f(g, 1.0f);
        g = d[mm - 1] - p + e[l - 2] / (g + sign_f(r, g));
        float s = 1.0f, c = 1.0f;
        p = 0.0f;
        float csv[2], snv[2];
        for (int i = mm; i <= l - 1; ++i) {
          float f = s * e[i - 1];
          float bb = c * e[i - 1];
          lartg_f(g, f, c, s, r);
          if (i != mm) e[i - 2] = r;
          g = d[i - 1] - p;
          r = (d[i] - g) * s + 2.0f * c * bb;
          p = s * r;
          d[i - 1] = g + p;
          g = c * r - bb;
          csv[i - mm] = c;
          snv[i - mm] = s;
        }
        int lm = l - mm;
        for (int j = 1; j <= lm; ++j) {
          float cc = csv[j - 1], ss = snv[j - 1];
          for (int r2 = 0; r2 < n; ++r2) {
            float temp = Z[r2][mm + j - 1];
            Z[r2][mm + j - 1] = cc * temp - ss * Z[r2][mm + j - 2];
            Z[r2][mm + j - 2] = ss * temp + cc * Z[r2][mm + j - 2];
          }
        }
        d[l - 1] -= p;
        e[l - 2] = g;
      }
    }
  }
  for (int ii = 2; ii <= n; ++ii) {
    int i = ii - 1, k = i;
    float p = d[i - 1];
    for (int j = ii; j <= n; ++j) {
      if (d[j - 1] < p) { k = j; p = d[j - 1]; }
    }
    if (k != i) {
      d[k - 1] = d[i - 1]; d[i - 1] = p;
      for (int r = 0; r < n; ++r) {
        float t = Z[r][i - 1]; Z[r][i - 1] = Z[r][k - 1]; Z[r][k - 1] = t;
      }
    }
  }
}

__device__ void eig3_f(float A00, float A10, float A20,
                       float A11, float A21, float A22, float Z[3][3]) {
#pragma clang fp contract(off)
  float d[3], e[2];
  float tau = 0.0f, v2 = 0.0f;
  d[0] = A00;
  float xnorm = fabsf(A20);
  if (xnorm == 0.0f) {
    tau = 0.0f; v2 = 0.0f;
    e[0] = A10; d[1] = A11; e[1] = A21; d[2] = A22;
  } else {
    float beta = -sign_f(lapy2_f(A10, xnorm), A10);
    tau = (beta - A10) / beta;
    float inv = 1.0f / (A10 - beta);
    v2 = A20 * inv;
    e[0] = beta;
    float x0 = tau * A11;
    float x1 = tau * A21;
    float tmp2 = A21 * v2;
    x0 = x0 + tau * tmp2;
    x1 = x1 + (tau * v2) * A22;
    float dotv = x0 + x1 * v2;
    float aw = (-0.5f * tau) * dotv;
    float w0 = x0 + aw;
    float w1 = x1 + aw * v2;
    d[1] = (A11 - w0) - w0;
    float pq = v2 * w0;
    e[1] = (A21 - pq) - w1;
    float pr = v2 * w1;
    d[2] = (A22 - pr) - pr;
  }
  Z[0][0] = 1.0f; Z[0][1] = 0.0f; Z[0][2] = 0.0f;
  Z[1][0] = 0.0f; Z[1][1] = 1.0f; Z[1][2] = 0.0f;
  Z[2][0] = 0.0f; Z[2][1] = 0.0f; Z[2][2] = 1.0f;
  steqr3_f(d, e, Z);
  if (tau != 0.0f) {
    for (int j = 0; j < 3; ++j) {
      float sum = Z[1][j] + v2 * Z[2][j];
      float tw = tau * sum;
      Z[1][j] = Z[1][j] - tw;
      Z[2][j] = Z[2][j] - v2 * tw;
    }
  }
}

// ---------------- KNN key (numpy-f32-faithful) ----------------
__device__ __forceinline__ unsigned long long knn_key(float qx, float qy, float qz,
                                                      float nqxx, float x, float y,
                                                      float z, int j) {
  const float dot = __fmaf_rn(qz, z, __fmaf_rn(qy, y, __fmul_rn(qx, x)));
  const float xxj =
      __fadd_rn(__fadd_rn(__fmul_rn(x, x), __fmul_rn(y, y)), __fmul_rn(z, z));
  const float inner = __fmul_rn(-2.0f, dot);
  const float pval = __fsub_rn(__fsub_rn(nqxx, inner), xxj);
  const unsigned bits = __float_as_uint(pval);
  const unsigned ordv = bits ^ (unsigned)(((int)bits >> 31) | 0x80000000);
  return ((unsigned long long)ordv << 32) | (unsigned)(4095 - j);
}

// ---------------- Kernel A1: KNN only, 4 query points per wave ----------------
__global__ __launch_bounds__(256) void knn_kernel(const float* __restrict__ xyz,
                                                  int* __restrict__ nidx_ws) {
  __shared__ struct { float xs[1024]; float ys[1024]; float zs[1024]; } soa;  // 12 KB

  const int wave = threadIdx.x >> 6;
  const int lane = threadIdx.x & 63;
  const int tid = threadIdx.x;
  const int P0 = blockIdx.x * 16;       // 16 points/block, same batch
  const int b = P0 >> 12;
  const int r0 = P0 & 4095;
  const int pbase = r0 + wave * 4;      // this wave's 4 query rows
  const float* xb = xyz + (size_t)b * (N_ * 3);

  float qx[4], qy[4], qz[4], nqxx[4];
#pragma unroll
  for (int q = 0; q < 4; ++q) {
    const int i = pbase + q;
    qx[q] = xb[3 * i]; qy[q] = xb[3 * i + 1]; qz[q] = xb[3 * i + 2];
    nqxx[q] = -__fadd_rn(__fadd_rn(__fmul_rn(qx[q], qx[q]), __fmul_rn(qy[q], qy[q])),
                         __fmul_rn(qz[q], qz[q]));
  }

  unsigned long long pk[4][4];
#pragma unroll
  for (int q = 0; q < 4; ++q)
#pragma unroll
    for (int s = 0; s < 4; ++s) pk[q][s] = 0ull;

  for (int tile = 0; tile < 4; ++tile) {
    {
      const float4* gsrc = (const float4*)(xb + tile * 3072);
      float4 a0 = gsrc[tid * 3];
      float4 a1 = gsrc[tid * 3 + 1];
      float4 a2 = gsrc[tid * 3 + 2];
      const int qq = tid * 4;
      soa.xs[qq] = a0.x; soa.xs[qq + 1] = a0.w; soa.xs[qq + 2] = a1.z; soa.xs[qq + 3] = a2.y;
      soa.ys[qq] = a0.y; soa.ys[qq + 1] = a1.x; soa.ys[qq + 2] = a1.w; soa.ys[qq + 3] = a2.z;
      soa.zs[qq] = a0.z; soa.zs[qq + 1] = a1.y; soa.zs[qq + 2] = a2.x; soa.zs[qq + 3] = a2.w;
    }
    __syncthreads();

#pragma unroll 2
    for (int tloc = 0; tloc < 16; ++tloc) {
      const int idx = tloc * 64 + lane;
      const int j = tile * 1024 + idx;
      const float x = soa.xs[idx];
      const float y = soa.ys[idx];
      const float z = soa.zs[idx];
      const float xxj =
          __fadd_rn(__fadd_rn(__fmul_rn(x, x), __fmul_rn(y, y)), __fmul_rn(z, z));
      const unsigned jenc = (unsigned)(4095 - j);
#pragma unroll
      for (int q = 0; q < 4; ++q) {
        const float dot =
            __fmaf_rn(qz[q], z, __fmaf_rn(qy[q], y, __fmul_rn(qx[q], x)));
        const float inner = __fmul_rn(-2.0f, dot);
        const float pval = __fsub_rn(__fsub_rn(nqxx[q], inner), xxj);
        const unsigned bits = __float_as_uint(pval);
        const unsigned ordv = bits ^ (unsigned)(((int)bits >> 31) | 0x80000000);
        const unsigned long long key = ((unsigned long long)ordv << 32) | jenc;
        const bool c0 = key > pk[q][0], c1 = key > pk[q][1],
                   c2 = key > pk[q][2], c3 = key > pk[q][3];
        pk[q][3] = c3 ? (c2 ? pk[q][2] : key) : pk[q][3];
        pk[q][2] = c2 ? (c1 ? pk[q][1] : key) : pk[q][2];
        pk[q][1] = c1 ? (c0 ? pk[q][0] : key) : pk[q][1];
        pk[q][0] = c0 ? key : pk[q][0];
      }
    }
    __syncthreads();
  }

  // merge: pops-outer, points-inner (4 independent butterflies interleave)
  int stash[4];
  int h[4] = {0, 0, 0, 0};
#pragma unroll
  for (int k = 0; k < K_; ++k) {
    unsigned long long v[4];
#pragma unroll
    for (int q = 0; q < 4; ++q) v[q] = pk[q][0];
#pragma unroll
    for (int off = 32; off >= 1; off >>= 1) {
#pragma unroll
      for (int q = 0; q < 4; ++q) {
        unsigned long long ov = __shfl_xor(v[q], off, 64);
        if (ov > v[q]) v[q] = ov;
      }
    }
#pragma unroll
    for (int q = 0; q < 4; ++q) {
      const int jidx = (4095 - (int)(unsigned)(v[q] & 0xFFFFFFFFull)) & (N_ - 1);
      if (lane == k) stash[q] = jidx;
      if (pk[q][0] == v[q]) {
        pk[q][0] = pk[q][1]; pk[q][1] = pk[q][2]; pk[q][2] = pk[q][3];
        pk[q][3] = 0ull;
        ++h[q];
      }
    }
  }
  // exact fallback per query (rare ~0.7%/pt, wave-uniform, global reads)
#pragma unroll
  for (int q = 0; q < 4; ++q) {
    if (__ballot(h[q] >= 4) != 0ull) {
      unsigned long long qq[K_];
#pragma unroll
      for (int k = 0; k < K_; ++k) qq[k] = 0ull;
      for (int t = 0; t < 64; ++t) {
        const int j = t * 64 + lane;
        const unsigned long long key = knn_key(qx[q], qy[q], qz[q], nqxx[q],
                                               xb[3 * j], xb[3 * j + 1],
                                               xb[3 * j + 2], j);
        bool c[K_];
#pragma unroll
        for (int s = 0; s < K_; ++s) c[s] = key > qq[s];
#pragma unroll
        for (int s = K_ - 1; s >= 1; --s)
          qq[s] = c[s] ? (c[s - 1] ? qq[s - 1] : key) : qq[s];
        qq[0] = c[0] ? key : qq[0];
      }
#pragma unroll
      for (int k = 0; k < K_; ++k) {
        unsigned long long v = qq[0];
#pragma unroll
        for (int off = 32; off >= 1; off >>= 1) {
          unsigned long long ov = __shfl_xor(v, off, 64);
          if (ov > v) v = ov;
        }
        const int jidx = (4095 - (int)(unsigned)(v & 0xFFFFFFFFull)) & (N_ - 1);
        if (lane == k) stash[q] = jidx;
        if (qq[0] == v) {
#pragma unroll
          for (int s = 0; s < K_ - 1; ++s) qq[s] = qq[s + 1];
          qq[K_ - 1] = 0ull;
        }
      }
    }
  }

  if (lane < K_) {
    const int pg = P0 + wave * 4;
#pragma unroll
    for (int q = 0; q < 4; ++q)
      nidx_ws[(size_t)(pg + q) * K_ + lane] = stash[q];
  }
}

// ---------------- Kernel A2: cov + eig, one point per thread ----------------
__global__ __launch_bounds__(64) void eig_kernel(const float* __restrict__ xyz,
                                                 const int* __restrict__ nidx_ws,
                                                 float* __restrict__ gf_ws) {
  const int p = blockIdx.x * 64 + threadIdx.x;
  const int b = p >> 12;
  const int i = p & 4095;
  const float* xb = xyz + (size_t)b * (N_ * 3);
  const float qx = xb[3 * i];
  const float qy = xb[3 * i + 1];
  const float qz = xb[3 * i + 2];

  int nidx[K_];
#pragma unroll
  for (int k = 0; k < K_; ++k) nidx[k] = nidx_ws[(size_t)p * K_ + k];

  float c00 = 0, c01 = 0, c02 = 0, c11 = 0, c12 = 0, c22 = 0;
  float mrx = 0, mry = 0, mrz = 0, md = 0;
#pragma unroll
  for (int k = 0; k < K_; ++k) {
    const int j = nidx[k];
    const float rx = __fsub_rn(xb[3 * j], qx);
    const float ry = __fsub_rn(xb[3 * j + 1], qy);
    const float rz = __fsub_rn(xb[3 * j + 2], qz);
    c00 = __fadd_rn(c00, __fmul_rn(rx, rx));
    c01 = __fadd_rn(c01, __fmul_rn(rx, ry));
    c02 = __fadd_rn(c02, __fmul_rn(rx, rz));
    c11 = __fadd_rn(c11, __fmul_rn(ry, ry));
    c12 = __fadd_rn(c12, __fmul_rn(ry, rz));
    c22 = __fadd_rn(c22, __fmul_rn(rz, rz));
    mrx = __fadd_rn(mrx, rx);
    mry = __fadd_rn(mry, ry);
    mrz = __fadd_rn(mrz, rz);
    const float nn = __fadd_rn(__fadd_rn(__fmul_rn(rx, rx), __fmul_rn(ry, ry)),
                               __fmul_rn(rz, rz));
    md = __fadd_rn(md, sqrtf(nn));
  }
  const float s16 = 0.0625f;
  float Z[3][3];
  eig3_f(__fmul_rn(c00, s16), __fmul_rn(c01, s16), __fmul_rn(c02, s16),
         __fmul_rn(c11, s16), __fmul_rn(c12, s16), __fmul_rn(c22, s16), Z);
  float* g = gf_ws + (size_t)p * 12;
  g[0] = Z[0][0]; g[1] = Z[1][0]; g[2] = Z[2][0];
  g[3] = Z[0][2]; g[4] = Z[1][2]; g[5] = Z[2][2];
  g[6] = __fmul_rn(mrx, s16); g[7] = __fmul_rn(mry, s16);
  g[8] = __fmul_rn(mrz, s16);
  g[9] = __fmul_rn(md, s16);
}

// ---------------- Kernel B: block-cooperative MLPs (16 pts/block) ----------------
__global__ __launch_bounds__(256) void mlp_kernel(
    const float* __restrict__ feats, const int* __restrict__ nidx_ws,
    const float* __restrict__ gf_ws,
    const float* __restrict__ geo_w1, const float* __restrict__ geo_b1,
    const float* __restrict__ geo_g1, const float* __restrict__ geo_be1,
    const float* __restrict__ geo_w2, const float* __restrict__ geo_b2,
    const float* __restrict__ diff_w1, const float* __restrict__ diff_b1,
    const float* __restrict__ diff_g1, const float* __restrict__ diff_be1,
    const float* __restrict__ diff_w2, const float* __restrict__ diff_b2,
    const float* __restrict__ ep_w1, const float* __restrict__ ep_b1,
    const float* __restrict__ ep_w2, const float* __restrict__ ep_b2,
    const float* __restrict__ ref_w1, const float* __restrict__ ref_b1,
    const float* __restrict__ ref_g1, const float* __restrict__ ref_be1,
    float* __restrict__ out, float* __restrict__ out_prob) {

  __shared__ float w[8192];
  __shared__ float fsh[16 * 128];
  __shared__ float sdif[16 * 128];
  __shared__ float ysh[16 * 64];
  __shared__ float edsh[16 * 128];
  __shared__ float insh[16 * 12];
  __shared__ int nsh[16 * 16];

  const int tid = threadIdx.x;
  const int lane = tid & 63;
  const int g = tid >> 6;
  const int P0 = blockIdx.x * 16;
  const int b = P0 >> 12;
  const int r0 = P0 & 4095;
  const float* fb = feats + (size_t)b * N_ * C_;

  if (tid < 192) insh[tid] = gf_ws[(size_t)P0 * 12 + tid];
  nsh[tid] = nidx_ws[(size_t)P0 * K_ + tid];
#pragma unroll
  for (int m = 0; m < 8; ++m)
    fsh[m * 256 + tid] = fb[(size_t)r0 * C_ + m * 256 + tid];
  if (tid < 160) ((float4*)w)[tid] = ((const float4*)geo_w1)[tid];
#pragma unroll
  for (int m = 0; m < 4; ++m)
    ((float4*)(w + 640))[m * 256 + tid] = ((const float4*)geo_w2)[m * 256 + tid];
  __syncthreads();

#pragma unroll
  for (int ptl = 0; ptl < 4; ++ptl) {
    const int pt = g * 4 + ptl;
    float acc = 0.0f;
#pragma unroll
    for (int c = 0; c < 10; ++c) acc += insh[pt * 12 + c] * w[c * 64 + lane];
    acc += geo_b1[lane];
    float m = wave_sum64(acc) * (1.0f / 64.0f);
    float xm = acc - m;
    float var = wave_sum64(xm * xm) * (1.0f / 64.0f);
    float yv = xm * (1.0f / sqrtf(var + 1e-5f)) * geo_g1[lane] + geo_be1[lane];
    ysh[pt * 64 + lane] = fmaxf(yv, 0.0f);
  }
  __syncthreads();

  float ge[4], de[4], prob[4];
#pragma unroll
  for (int ptl = 0; ptl < 4; ++ptl) {
    const int pt = g * 4 + ptl;
    float acc = 0.0f;
#pragma unroll 8
    for (int c = 0; c < 64; ++c) acc += ysh[pt * 64 + c] * w[640 + c * 64 + lane];
    ge[ptl] = acc + geo_b2[lane];
  }

  {
    const int h2 = tid >> 7, c = tid & 127;
    for (int ptp = 0; ptp < 8; ++ptp) {
      const int pt = h2 * 8 + ptp;
      const float fv = fsh[pt * 128 + c];
      float s = 0.0f;
#pragma unroll
      for (int k = 0; k < K_; ++k) {
        const int j = nsh[pt * 16 + k];
        s += fabsf(fv - fb[(size_t)j * C_ + c]);
      }
      sdif[pt * 128 + c] = s * (1.0f / 16.0f);
    }
  }
  __syncthreads();
#pragma unroll
  for (int m = 0; m < 8; ++m)
    ((float4*)w)[m * 256 + tid] = ((const float4*)diff_w1)[m * 256 + tid];
  __syncthreads();

#pragma unroll
  for (int ptl = 0; ptl < 4; ++ptl) {
    const int pt = g * 4 + ptl;
    float acc = 0.0f;
#pragma unroll 8
    for (int c = 0; c < 128; ++c) acc += sdif[pt * 128 + c] * w[c * 64 + lane];
    acc += diff_b1[lane];
    float m = wave_sum64(acc) * (1.0f / 64.0f);
    float xm = acc - m;
    float var = wave_sum64(xm * xm) * (1.0f / 64.0f);
    float yv = xm * (1.0f / sqrtf(var + 1e-5f)) * diff_g1[lane] + diff_be1[lane];
    ysh[pt * 64 + lane] = fmaxf(yv, 0.0f);
  }
  __syncthreads();
#pragma unroll
  for (int m = 0; m < 4; ++m)
    ((float4*)w)[m * 256 + tid] = ((const float4*)diff_w2)[m * 256 + tid];
#pragma unroll
  for (int m = 0; m < 4; ++m)
    ((float4*)w)[1024 + m * 256 + tid] = ((const float4*)ep_w1)[m * 256 + tid];
  __syncthreads();

#pragma unroll
  for (int ptl = 0; ptl < 4; ++ptl) {
    const int pt = g * 4 + ptl;
    float acc = 0.0f;
#pragma unroll 8
    for (int c = 0; c < 64; ++c) acc += ysh[pt * 64 + c] * w[c * 64 + lane];
    de[ptl] = acc + diff_b2[lane];
    edsh[pt * 128 + lane] = ge[ptl];
    edsh[pt * 128 + 64 + lane] = de[ptl];
  }
  __syncthreads();

  const int u = lane & 31;
#pragma unroll
  for (int ptl = 0; ptl < 4; ++ptl) {
    const int pt = g * 4 + ptl;
    float a = 0.0f;
#pragma unroll 8
    for (int c = 0; c < 128; ++c) a += edsh[pt * 128 + c] * w[4096 + c * 32 + u];
    a += ep_b1[u];
    float hh = (lane < 32) ? fmaxf(a, 0.0f) * ep_w2[u] : 0.0f;
    float tsum = wave_sum64(hh) + ep_b2[0];
    prob[ptl] = 1.0f / (1.0f + expf(-tsum));
  }
  __syncthreads();
#pragma unroll
  for (int ptl = 0; ptl < 4; ++ptl) {
    const int pt = g * 4 + ptl;
    edsh[pt * 128 + lane] = ge[ptl] * prob[ptl];
    edsh[pt * 128 + 64 + lane] = de[ptl] * prob[ptl];
  }

  float a0[4] = {0, 0, 0, 0}, a1[4] = {0, 0, 0, 0};
  for (int ch = 0; ch < 4; ++ch) {
    __syncthreads();
    {
      const float4* gsrc = (const float4*)(ref_w1 + ch * 8192);
#pragma unroll
      for (int m = 0; m < 8; ++m) ((float4*)w)[m * 256 + tid] = gsrc[m * 256 + tid];
    }
    __syncthreads();
#pragma unroll
    for (int ptl = 0; ptl < 4; ++ptl) {
      const int pt = g * 4 + ptl;
      const float* src = (ch < 2) ? &fsh[pt * 128 + ch * 64]
                                  : &edsh[pt * 128 + (ch - 2) * 64];
#pragma unroll 4
      for (int cl = 0; cl < 64; ++cl) {
        const float e = src[cl];
        a0[ptl] += e * w[cl * 128 + lane];
        a1[ptl] += e * w[cl * 128 + 64 + lane];
      }
    }
  }

#pragma unroll
  for (int ptl = 0; ptl < 4; ++ptl) {
    const int pt = g * 4 + ptl;
    float A0 = a0[ptl] + ref_b1[lane];
    float A1 = a1[ptl] + ref_b1[64 + lane];
    float mm2 = wave_sum64(A0 + A1) * (1.0f / 128.0f);
    float d0 = A0 - mm2, d1 = A1 - mm2;
    float var2 = wave_sum64(d0 * d0 + d1 * d1) * (1.0f / 128.0f);
    float rs = 1.0f / sqrtf(var2 + 1e-5f);
    float y0 = d0 * rs * ref_g1[lane] + ref_be1[lane];
    float y1 = d1 * rs * ref_g1[64 + lane] + ref_be1[64 + lane];
    y0 = fmaxf(y0, 0.0f) + fsh[pt * 128 + lane];
    y1 = fmaxf(y1, 0.0f) + fsh[pt * 128 + 64 + lane];
    out[(size_t)(P0 + pt) * 128 + lane] = y0;
    out[(size_t)(P0 + pt) * 128 + 64 + lane] = y1;
    if (lane == 0) out_prob[P0 + pt] = prob[ptl];
  }
}

// ---------------- Fallback: R8 fused kernel (proven) ----------------
__global__ __launch_bounds__(256) void fused_kernel(
    const float* __restrict__ xyz, const float* __restrict__ feats,
    const float* __restrict__ geo_w1, const float* __restrict__ geo_b1,
    const float* __restrict__ geo_g1, const float* __restrict__ geo_be1,
    const float* __restrict__ geo_w2, const float* __restrict__ geo_b2,
    const float* __restrict__ diff_w1, const float* __restrict__ diff_b1,
    const float* __restrict__ diff_g1, const float* __restrict__ diff_be1,
    const float* __restrict__ diff_w2, const float* __restrict__ diff_b2,
    const float* __restrict__ ep_w1, const float* __restrict__ ep_b1,
    const float* __restrict__ ep_w2, const float* __restrict__ ep_b2,
    const float* __restrict__ ref_w1, const float* __restrict__ ref_b1,
    const float* __restrict__ ref_g1, const float* __restrict__ ref_be1,
    float* __restrict__ out, float* __restrict__ out_prob) {

  __shared__ float4 tile4[1024];

  const int wave = threadIdx.x >> 6;
  const int lane = threadIdx.x & 63;
  const int tid = threadIdx.x;
  const int p = blockIdx.x * 4 + wave;
  const int b = p >> 12;
  const int i = p & 4095;
  const float* xb = xyz + (size_t)b * (N_ * 3);

  const float qx = xb[3 * i];
  const float qy = xb[3 * i + 1];
  const float qz = xb[3 * i + 2];
  const float qxx =
      __fadd_rn(__fadd_rn(__fmul_rn(qx, qx), __fmul_rn(qy, qy)), __fmul_rn(qz, qz));
  const float nqxx = -qxx;

  unsigned long long pk[4] = {0ull, 0ull, 0ull, 0ull};
  for (int tile = 0; tile < 4; ++tile) {
    {
      const float4* gsrc = (const float4*)(xb + tile * 3072);
      float4 r0 = gsrc[tid * 3];
      float4 r1 = gsrc[tid * 3 + 1];
      float4 r2 = gsrc[tid * 3 + 2];
      const int base = tid * 4;
      tile4[base]     = make_float4(r0.x, r0.y, r0.z, 0.0f);
      tile4[base + 1] = make_float4(r0.w, r1.x, r1.y, 0.0f);
      tile4[base + 2] = make_float4(r1.z, r1.w, r2.x, 0.0f);
      tile4[base + 3] = make_float4(r2.y, r2.z, r2.w, 0.0f);
    }
    __syncthreads();
#pragma unroll 4
    for (int tloc = 0; tloc < 16; ++tloc) {
      const int j = tile * 1024 + tloc * 64 + lane;
      const float4 pt = tile4[tloc * 64 + lane];
      const unsigned long long key = knn_key(qx, qy, qz, nqxx, pt.x, pt.y, pt.z, j);
      const bool c0 = key > pk[0], c1 = key > pk[1], c2 = key > pk[2], c3 = key > pk[3];
      pk[3] = c3 ? (c2 ? pk[2] : key) : pk[3];
      pk[2] = c2 ? (c1 ? pk[1] : key) : pk[2];
      pk[1] = c1 ? (c0 ? pk[0] : key) : pk[1];
      pk[0] = c0 ? key : pk[0];
    }
    __syncthreads();
  }

  int nidx[K_];
  int h = 0;
#pragma unroll
  for (int k = 0; k < K_; ++k) {
    unsigned long long v = pk[0];
#pragma unroll
    for (int off = 32; off >= 1; off >>= 1) {
      unsigned long long ov = __shfl_xor(v, off, 64);
      if (ov > v) v = ov;
    }
    nidx[k] = (4095 - (int)(unsigned)(v & 0xFFFFFFFFull)) & (N_ - 1);
    if (pk[0] == v) {
      pk[0] = pk[1]; pk[1] = pk[2]; pk[2] = pk[3]; pk[3] = 0ull;
      ++h;
    }
  }
  if (__ballot(h >= 4) != 0ull) {
    unsigned long long q[K_];
#pragma unroll
    for (int k = 0; k < K_; ++k) q[k] = 0ull;
    for (int t = 0; t < 64; ++t) {
      const int j = t * 64 + lane;
      const unsigned long long key =
          knn_key(qx, qy, qz, nqxx, xb[3 * j], xb[3 * j + 1], xb[3 * j + 2], j);
      bool c[K_];
#pragma unroll
      for (int s = 0; s < K_; ++s) c[s] = key > q[s];
#pragma unroll
      for (int s = K_ - 1; s >= 1; --s)
        q[s] = c[s] ? (c[s - 1] ? q[s - 1] : key) : q[s];
      q[0] = c[0] ? key : q[0];
    }
#pragma unroll
    for (int k = 0; k < K_; ++k) {
      unsigned long long v = q[0];
#pragma unroll
      for (int off = 32; off >= 1; off >>= 1) {
        unsigned long long ov = __shfl_xor(v, off, 64);
        if (ov > v) v = ov;
      }
      nidx[k] = (4095 - (int)(unsigned)(v & 0xFFFFFFFFull)) & (N_ - 1);
      if (q[0] == v) {
#pragma unroll
        for (int s = 0; s < K_ - 1; ++s) q[s] = q[s + 1];
        q[K_ - 1] = 0ull;
      }
    }
  }

  float c00 = 0, c01 = 0, c02 = 0, c11 = 0, c12 = 0, c22 = 0;
  float mrx = 0, mry = 0, mrz = 0, md = 0;
#pragma unroll
  for (int k = 0; k < K_; ++k) {
    const int j = nidx[k];
    const float rx = __fsub_rn(xb[3 * j], qx);
    const float ry = __fsub_rn(xb[3 * j + 1], qy);
    const float rz = __fsub_rn(xb[3 * j + 2], qz);
    c00 = __fadd_rn(c00, __fmul_rn(rx, rx));
    c01 = __fadd_rn(c01, __fmul_rn(rx, ry));
    c02 = __fadd_rn(c02, __fmul_rn(rx, rz));
    c11 = __fadd_rn(c11, __fmul_rn(ry, ry));
    c12 = __fadd_rn(c12, __fmul_rn(ry, rz));
    c22 = __fadd_rn(c22, __fmul_rn(rz, rz));
    mrx = __fadd_rn(mrx, rx);
    mry = __fadd_rn(mry, ry);
    mrz = __fadd_rn(mrz, rz);
    const float nn = __fadd_rn(__fadd_rn(__fmul_rn(rx, rx), __fmul_rn(ry, ry)),
                               __fmul_rn(rz, rz));
    md = __fadd_rn(md, sqrtf(nn));
  }
  const float s16 = 0.0625f;
  float Z[3][3];
  eig3_f(__fmul_rn(c00, s16), __fmul_rn(c01, s16), __fmul_rn(c02, s16),
         __fmul_rn(c11, s16), __fmul_rn(c12, s16), __fmul_rn(c22, s16), Z);
  float gf[10];
  gf[0] = Z[0][0]; gf[1] = Z[1][0]; gf[2] = Z[2][0];
  gf[3] = Z[0][2]; gf[4] = Z[1][2]; gf[5] = Z[2][2];
  gf[6] = __fmul_rn(mrx, s16); gf[7] = __fmul_rn(mry, s16);
  gf[8] = __fmul_rn(mrz, s16);
  gf[9] = __fmul_rn(md, s16);

  float acc = 0.0f;
#pragma unroll
  for (int ii = 0; ii < 10; ++ii) acc += gf[ii] * geo_w1[ii * 64 + lane];
  acc += geo_b1[lane];
  float yr;
  {
    float m = wave_sum64(acc) * (1.0f / 64.0f);
    float xm = acc - m;
    float var = wave_sum64(xm * xm) * (1.0f / 64.0f);
    float yv = xm * (1.0f / sqrtf(var + 1e-5f)) * geo_g1[lane] + geo_be1[lane];
    yr = fmaxf(yv, 0.0f);
  }
  float ge = 0.0f;
#pragma unroll 8
  for (int jj = 0; jj < 64; ++jj) ge += __shfl(yr, jj, 64) * geo_w2[jj * 64 + lane];
  ge += geo_b2[lane];

  const float* fb = feats + (size_t)b * N_ * C_;
  const float* fi = fb + (size_t)i * C_;
  const float f0 = fi[lane];
  const float f1 = fi[64 + lane];
  float s0 = 0.0f, s1 = 0.0f;
#pragma unroll
  for (int k = 0; k < K_; ++k) {
    const float* fj = fb + (size_t)nidx[k] * C_;
    s0 += fabsf(f0 - fj[lane]);
    s1 += fabsf(f1 - fj[64 + lane]);
  }
  s0 *= (1.0f / 16.0f);
  s1 *= (1.0f / 16.0f);
  float acc2 = 0.0f;
#pragma unroll 8
  for (int c = 0; c < 64; ++c) acc2 += __shfl(s0, c, 64) * diff_w1[c * 64 + lane];
#pragma unroll 8
  for (int c = 64; c < 128; ++c) acc2 += __shfl(s1, c - 64, 64) * diff_w1[c * 64 + lane];
  acc2 += diff_b1[lane];
  float yr2;
  {
    float m = wave_sum64(acc2) * (1.0f / 64.0f);
    float xm = acc2 - m;
    float var = wave_sum64(xm * xm) * (1.0f / 64.0f);
    float yv = xm * (1.0f / sqrtf(var + 1e-5f)) * diff_g1[lane] + diff_be1[lane];
    yr2 = fmaxf(yv, 0.0f);
  }
  float de = 0.0f;
#pragma unroll 8
  for (int jj = 0; jj < 64; ++jj) de += __shfl(yr2, jj, 64) * diff_w2[jj * 64 + lane];
  de += diff_b2[lane];

  {
    const int u = lane & 31;
    float a = 0.0f;
#pragma unroll 8
    for (int c = 0; c < 64; ++c) a += __shfl(ge, c, 64) * ep_w1[c * 32 + u];
#pragma unroll 8
    for (int c = 64; c < 128; ++c) a += __shfl(de, c - 64, 64) * ep_w1[c * 32 + u];
    a += ep_b1[u];
    float hh = (lane < 32) ? fmaxf(a, 0.0f) * ep_w2[u] : 0.0f;
    float tsum = wave_sum64(hh) + ep_b2[0];
    float prob = 1.0f / (1.0f + expf(-tsum));

    const float gep = ge * prob;
    const float dep = de * prob;
    float a0 = 0.0f, a1 = 0.0f;
#pragma unroll 4
    for (int c = 0; c < 64; ++c) {
      float ec = __shfl(f0, c, 64);
      a0 += ec * ref_w1[c * 128 + lane];
      a1 += ec * ref_w1[c * 128 + 64 + lane];
    }
#pragma unroll 4
    for (int c = 64; c < 128; ++c) {
      float ec = __shfl(f1, c - 64, 64);
      a0 += ec * ref_w1[c * 128 + lane];
      a1 += ec * ref_w1[c * 128 + 64 + lane];
    }
#pragma unroll 4
    for (int c = 128; c < 192; ++c) {
      float ec = __shfl(gep, c - 128, 64);
      a0 += ec * ref_w1[c * 128 + lane];
      a1 += ec * ref_w1[c * 128 + 64 + lane];
    }
#pragma unroll 4
    for (int c = 192; c < 256; ++c) {
      float ec = __shfl(dep, c - 192, 64);
      a0 += ec * ref_w1[c * 128 + lane];
      a1 += ec * ref_w1[c * 128 + 64 + lane];
    }
    a0 += ref_b1[lane];
    a1 += ref_b1[64 + lane];
    float mm2 = wave_sum64(a0 + a1) * (1.0f / 128.0f);
    float d0 = a0 - mm2, d1 = a1 - mm2;
    float var2 = wave_sum64(d0 * d0 + d1 * d1) * (1.0f / 128.0f);
    float rs = 1.0f / sqrtf(var2 + 1e-5f);
    float y0 = d0 * rs * ref_g1[lane] + ref_be1[lane];
    float y1 = d1 * rs * ref_g1[64 + lane] + ref_be1[64 + lane];
    y0 = fmaxf(y0, 0.0f) + f0;
    y1 = fmaxf(y1, 0.0f) + f1;
    out[(size_t)p * 128 + lane] = y0;
    out[(size_t)p * 128 + 64 + lane] = y1;
    if (lane == 0) out_prob[p] = prob;
  }
}

extern "C" void kernel_launch(void* const* d_in, const int* in_sizes, int n_in,
                              void* d_out, int out_size, void* d_ws, size_t ws_size,
                              hipStream_t stream) {
  const float* xyz = (const float*)d_in[0];
  const float* features = (const float*)d_in[1];
  const float* geo_w1 = (const float*)d_in[2];
  const float* geo_b1 = (const float*)d_in[3];
  const float* geo_g1 = (const float*)d_in[4];
  const float* geo_be1 = (const float*)d_in[5];
  const float* geo_w2 = (const float*)d_in[6];
  const float* geo_b2 = (const float*)d_in[7];
  const float* diff_w1 = (const float*)d_in[8];
  const float* diff_b1 = (const float*)d_in[9];
  const float* diff_g1 = (const float*)d_in[10];
  const float* diff_be1 = (const float*)d_in[11];
  const float* diff_w2 = (const float*)d_in[12];
  const float* diff_b2 = (const float*)d_in[13];
  const float* ep_w1 = (const float*)d_in[14];
  const float* ep_b1 = (const float*)d_in[15];
  const float* ep_w2 = (const float*)d_in[16];
  const float* ep_b2 = (const float*)d_in[17];
  const float* ref_w1 = (const float*)d_in[18];
  const float* ref_b1 = (const float*)d_in[19];
  const float* ref_g1 = (const float*)d_in[20];
  const float* ref_be1 = (const float*)d_in[21];

  float* out = (float*)d_out;
  float* out_prob = out + (size_t)NPT * C_;

  if (ws_size >= (size_t)(2 * 1024 * 1024)) {
    int* nidx_ws = (int*)d_ws;                             // 1 MB
    float* gf_ws = (float*)((char*)d_ws + (1u << 20));     // 768 KB
    knn_kernel<<<dim3(NPT / 16), dim3(256), 0, stream>>>(xyz, nidx_ws);
    eig_kernel<<<dim3(NPT / 64), dim3(64), 0, stream>>>(xyz, nidx_ws, gf_ws);
    mlp_kernel<<<dim3(NPT / 16), dim3(256), 0, stream>>>(
        features, nidx_ws, gf_ws, geo_w1, geo_b1, geo_g1, geo_be1, geo_w2,
        geo_b2, diff_w1, diff_b1, diff_g1, diff_be1, diff_w2, diff_b2, ep_w1,
        ep_b1, ep_w2, ep_b2, ref_w1, ref_b1, ref_g1, ref_be1, out, out_prob);
  } else {
    fused_kernel<<<dim3(NPT / 4), dim3(256), 0, stream>>>(
        xyz, features, geo_w1, geo_b1, geo_g1, geo_be1, geo_w2, geo_b2,
        diff_w1, diff_b1, diff_g1, diff_be1, diff_w2, diff_b2, ep_w1, ep_b1,
        ep_w2, ep_b2, ref_w1, ref_b1, ref_g1, ref_be1, out, out_prob);
  }
}

// Round 12
// 325.106 us; speedup vs baseline: 1.6624x; 1.0941x over previous
//
#include <hip/hip_runtime.h>
#include <hip/hip_bf16.h>

// B=4, N=4096, C=128, K=16. float32 in/out.
// R11: knn 129us + eig (small) + mlp (~120us) = 355us total.
// R12: mlp matvecs inverted to channel-outer/point-inner: each LDS weight
// read is reused across the wave's 4 points (LDS ops ~ -45%). Per-point
// channel accumulation order unchanged. knn/eig kernels unchanged.
// Fallback to proven R8 fused kernel if ws_size < 2MB.
#define N_ 4096
#define C_ 128
#define K_ 16
#define NPT 16384

__device__ __forceinline__ float wave_sum64(float v) {
#pragma unroll
  for (int off = 32; off >= 1; off >>= 1) v += __shfl_xor(v, off, 64);
  return v;
}

// ---------------- LAPACK f32 helpers ----------------

__device__ __forceinline__ float sign_f(float a, float b) {
  return copysignf(fabsf(a), b);
}

__device__ float lapy2_f(float x, float y) {
#pragma clang fp contract(off)
  float xa = fabsf(x), ya = fabsf(y);
  float w = fmaxf(xa, ya), z = fminf(xa, ya);
  if (z == 0.0f) return w;
  float t = z / w;
  return w * sqrtf(1.0f + t * t);
}

__device__ void lartg_f(float f, float g, float& c, float& s, float& r) {
#pragma clang fp contract(off)
  if (g == 0.0f) {
    c = 1.0f; s = 0.0f; r = f;
  } else if (f == 0.0f) {
    c = 0.0f; s = copysignf(1.0f, g); r = fabsf(g);
  } else {
    float d = sqrtf(f * f + g * g);
    c = fabsf(f) / d;
    r = sign_f(d, f);
    s = g / r;
  }
}

__device__ void laev2_f(float a, float b, float cc, float& rt1, float& rt2,
                        float& cs1, float& sn1) {
#pragma clang fp contract(off)
  float sm = a + cc;
  float df = a - cc;
  float adf = fabsf(df);
  float tb = b + b;
  float ab = fabsf(tb);
  float acmx, acmn;
  if (fabsf(a) > fabsf(cc)) { acmx = a; acmn = cc; } else { acmx = cc; acmn = a; }
  float rt;
  if (adf > ab) {
    float t = ab / adf; rt = adf * sqrtf(1.0f + t * t);
  } else if (adf < ab) {
    float t = adf / ab; rt = ab * sqrtf(1.0f + t * t);
  } else {
    rt = ab * sqrtf(2.0f);
  }
  int sgn1;
  if (sm < 0.0f) {
    rt1 = 0.5f * (sm - rt); sgn1 = -1;
    rt2 = (acmx / rt1) * acmn - (b / rt1) * b;
  } else if (sm > 0.0f) {
    rt1 = 0.5f * (sm + rt); sgn1 = 1;
    rt2 = (acmx / rt1) * acmn - (b / rt1) * b;
  } else {
    rt1 = 0.5f * rt; rt2 = -0.5f * rt; sgn1 = 1;
  }
  float cs; int sgn2;
  if (df >= 0.0f) { cs = df + rt; sgn2 = 1; } else { cs = df - rt; sgn2 = -1; }
  float acs = fabsf(cs);
  if (acs > ab) {
    float ct = -tb / cs;
    sn1 = 1.0f / sqrtf(1.0f + ct * ct);
    cs1 = ct * sn1;
  } else {
    if (ab == 0.0f) { cs1 = 1.0f; sn1 = 0.0f; }
    else {
      float tn = -cs / tb;
      cs1 = 1.0f / sqrtf(1.0f + tn * tn);
      sn1 = tn * cs1;
    }
  }
  if (sgn1 == sgn2) { float tn = cs1; cs1 = -sn1; sn1 = tn; }
}

__device__ void steqr3_f(float d[3], float e[2], float Z[3][3]) {
#pragma clang fp contract(off)
  const int n = 3;
  const float eps = 5.9604644775390625e-08f;
  const float eps2 = eps * eps;
  const float safmin = 1.17549435e-38f;
  const int nmaxit = n * 30;
  int jtot = 0;
  int l1 = 1;

  for (int og = 0; og < 16; ++og) {
    if (l1 > n) break;
    if (l1 > 1) e[l1 - 2] = 0.0f;
    int m, l, lend;
    if (l1 <= n - 1) {
      bool found = false;
      for (m = l1; m <= n - 1; ++m) {
        float tst = fabsf(e[m - 1]);
        if (tst == 0.0f) { found = true; break; }
        if (tst <= (sqrtf(fabsf(d[m - 1])) * sqrtf(fabsf(d[m]))) * eps) {
          e[m - 1] = 0.0f; found = true; break;
        }
      }
      if (!found) m = n;
    } else {
      m = n;
    }
    l = l1; lend = m; l1 = m + 1;
    if (lend == l) continue;
    if (fabsf(d[lend - 1]) < fabsf(d[l - 1])) { int t = l; l = lend; lend = t; }

    if (lend > l) {
      for (int it = 0; it < 128; ++it) {
        int mm;
        if (l != lend) {
          bool f2 = false;
          for (mm = l; mm <= lend - 1; ++mm) {
            float tst = e[mm - 1] * e[mm - 1];
            if (tst <= (eps2 * fabsf(d[mm - 1])) * fabsf(d[mm]) + safmin) { f2 = true; break; }
          }
          if (!f2) mm = lend;
        } else mm = lend;
        if (mm < lend) e[mm - 1] = 0.0f;
        float p = d[l - 1];
        if (mm == l) {
          d[l - 1] = p; ++l;
          if (l <= lend) continue;
          break;
        }
        if (mm == l + 1) {
          float rt1, rt2, cc, ss;
          laev2_f(d[l - 1], e[l - 1], d[l], rt1, rt2, cc, ss);
          for (int r = 0; r < n; ++r) {
            float temp = Z[r][l];
            Z[r][l] = cc * temp - ss * Z[r][l - 1];
            Z[r][l - 1] = ss * temp + cc * Z[r][l - 1];
          }
          d[l - 1] = rt1; d[l] = rt2; e[l - 1] = 0.0f;
          l += 2;
          if (l <= lend) continue;
          break;
        }
        if (jtot == nmaxit) break;
        ++jtot;
        float g = (d[l] - p) / (2.0f * e[l - 1]);
        float r = lapy2_f(g, 1.0f);
        g = d[mm - 1] - p + e[l - 1] / (g + sign_f(r, g));
        float s = 1.0f, c = 1.0f;
        p = 0.0f;
        float csv[2], snv[2];
        for (int i = mm - 1; i >= l; --i) {
          float f = s * e[i - 1];
          float bb = c * e[i - 1];
          lartg_f(g, f, c, s, r);
          if (i != mm - 1) e[i] = r;
          g = d[i] - p;
          r = (d[i - 1] - g) * s + 2.0f * c * bb;
          p = s * r;
          d[i] = g + p;
          g = c * r - bb;
          csv[i - l] = c;
          snv[i - l] = -s;
        }
        int mml = mm - l;
        for (int j = mml; j >= 1; --j) {
          float cc = csv[j - 1], ss = snv[j - 1];
          for (int r2 = 0; r2 < n; ++r2) {
            float temp = Z[r2][l + j - 1];
            Z[r2][l + j - 1] = cc * temp - ss * Z[r2][l + j - 2];
            Z[r2][l + j - 2] = ss * temp + cc * Z[r2][l + j - 2];
          }
        }
        d[l - 1] -= p;
        e[l - 1] = g;
      }
    } else {
      for (int it = 0; it < 128; ++it) {
        int mm;
        if (l != lend) {
          bool f2 = false;
          for (mm = l; mm >= lend + 1; --mm) {
            float tst = e[mm - 2] * e[mm - 2];
            if (tst <= (eps2 * fabsf(d[mm - 1])) * fabsf(d[mm - 2]) + safmin) { f2 = true; break; }
          }
          if (!f2) mm = lend;
        } else mm = lend;
        if (mm > lend) e[mm - 2] = 0.0f;
        float p = d[l - 1];
        if (mm == l) {
          d[l - 1] = p; --l;
          if (l >= lend) continue;
          break;
        }
        if (mm == l - 1) {
          float rt1, rt2, cc, ss;
          laev2_f(d[l - 2], e[l - 2], d[l - 1], rt1, rt2, cc, ss);
          for (int r = 0; r < n; ++r) {
            float temp = Z[r][l - 1];
            Z[r][l - 1] = cc * temp - ss * Z[r][l - 2];
            Z[r][l - 2] = ss * temp + cc * Z[r][l - 2];
          }
          d[l - 2] = rt1; d[l - 1] = rt2; e[l - 2] = 0.0f;
          l -= 2;
          if (l >= lend) continue;
          break;
        }
        if (jtot == nmaxit) break;
        ++jtot;
        float g = (d[l - 2] - p) / (2.0f * e[l - 2]);
        float r = lapy2_f(g, 1.0f);
        g = d[mm - 1] - p + e[l - 2] / (g + sign_f(r, g));
        float s = 1.0f, c = 1.0f;
        p = 0.0f;
        float csv[2], snv[2];
        for (int i = mm; i <= l - 1; ++i) {
          float f = s * e[i - 1];
          float bb = c * e[i - 1];
          lartg_f(g, f, c, s, r);
          if (i != mm) e[i - 2] = r;
          g = d[i - 1] - p;
          r = (d[i] - g) * s + 2.0f * c * bb;
          p = s * r;
          d[i - 1] = g + p;
          g = c * r - bb;
          csv[i - mm] = c;
          snv[i - mm] = s;
        }
        int lm = l - mm;
        for (int j = 1; j <= lm; ++j) {
          float cc = csv[j - 1], ss = snv[j - 1];
          for (int r2 = 0; r2 < n; ++r2) {
            float temp = Z[r2][mm + j - 1];
            Z[r2][mm + j - 1] = cc * temp - ss * Z[r2][mm + j - 2];
            Z[r2][mm + j - 2] = ss * temp + cc * Z[r2][mm + j - 2];
          }
        }
        d[l - 1] -= p;
        e[l - 2] = g;
      }
    }
  }
  for (int ii = 2; ii <= n; ++ii) {
    int i = ii - 1, k = i;
    float p = d[i - 1];
    for (int j = ii; j <= n; ++j) {
      if (d[j - 1] < p) { k = j; p = d[j - 1]; }
    }
    if (k != i) {
      d[k - 1] = d[i - 1]; d[i - 1] = p;
      for (int r = 0; r < n; ++r) {
        float t = Z[r][i - 1]; Z[r][i - 1] = Z[r][k - 1]; Z[r][k - 1] = t;
      }
    }
  }
}

__device__ void eig3_f(float A00, float A10, float A20,
                       float A11, float A21, float A22, float Z[3][3]) {
#pragma clang fp contract(off)
  float d[3], e[2];
  float tau = 0.0f, v2 = 0.0f;
  d[0] = A00;
  float xnorm = fabsf(A20);
  if (xnorm == 0.0f) {
    tau = 0.0f; v2 = 0.0f;
    e[0] = A10; d[1] = A11; e[1] = A21; d[2] = A22;
  } else {
    float beta = -sign_f(lapy2_f(A10, xnorm), A10);
    tau = (beta - A10) / beta;
    float inv = 1.0f / (A10 - beta);
    v2 = A20 * inv;
    e[0] = beta;
    float x0 = tau * A11;
    float x1 = tau * A21;
    float tmp2 = A21 * v2;
    x0 = x0 + tau * tmp2;
    x1 = x1 + (tau * v2) * A22;
    float dotv = x0 + x1 * v2;
    float aw = (-0.5f * tau) * dotv;
    float w0 = x0 + aw;
    float w1 = x1 + aw * v2;
    d[1] = (A11 - w0) - w0;
    float pq = v2 * w0;
    e[1] = (A21 - pq) - w1;
    float pr = v2 * w1;
    d[2] = (A22 - pr) - pr;
  }
  Z[0][0] = 1.0f; Z[0][1] = 0.0f; Z[0][2] = 0.0f;
  Z[1][0] = 0.0f; Z[1][1] = 1.0f; Z[1][2] = 0.0f;
  Z[2][0] = 0.0f; Z[2][1] = 0.0f; Z[2][2] = 1.0f;
  steqr3_f(d, e, Z);
  if (tau != 0.0f) {
    for (int j = 0; j < 3; ++j) {
      float sum = Z[1][j] + v2 * Z[2][j];
      float tw = tau * sum;
      Z[1][j] = Z[1][j] - tw;
      Z[2][j] = Z[2][j] - v2 * tw;
    }
  }
}

// ---------------- KNN key (numpy-f32-faithful) ----------------
__device__ __forceinline__ unsigned long long knn_key(float qx, float qy, float qz,
                                                      float nqxx, float x, float y,
                                                      float z, int j) {
  const float dot = __fmaf_rn(qz, z, __fmaf_rn(qy, y, __fmul_rn(qx, x)));
  const float xxj =
      __fadd_rn(__fadd_rn(__fmul_rn(x, x), __fmul_rn(y, y)), __fmul_rn(z, z));
  const float inner = __fmul_rn(-2.0f, dot);
  const float pval = __fsub_rn(__fsub_rn(nqxx, inner), xxj);
  const unsigned bits = __float_as_uint(pval);
  const unsigned ordv = bits ^ (unsigned)(((int)bits >> 31) | 0x80000000);
  return ((unsigned long long)ordv << 32) | (unsigned)(4095 - j);
}

// ---------------- Kernel A1: KNN, 4 query points per wave (R11, proven) ----------------
__global__ __launch_bounds__(256) void knn_kernel(const float* __restrict__ xyz,
                                                  int* __restrict__ nidx_ws) {
  __shared__ struct { float xs[1024]; float ys[1024]; float zs[1024]; } soa;

  const int wave = threadIdx.x >> 6;
  const int lane = threadIdx.x & 63;
  const int tid = threadIdx.x;
  const int P0 = blockIdx.x * 16;
  const int b = P0 >> 12;
  const int r0 = P0 & 4095;
  const int pbase = r0 + wave * 4;
  const float* xb = xyz + (size_t)b * (N_ * 3);

  float qx[4], qy[4], qz[4], nqxx[4];
#pragma unroll
  for (int q = 0; q < 4; ++q) {
    const int i = pbase + q;
    qx[q] = xb[3 * i]; qy[q] = xb[3 * i + 1]; qz[q] = xb[3 * i + 2];
    nqxx[q] = -__fadd_rn(__fadd_rn(__fmul_rn(qx[q], qx[q]), __fmul_rn(qy[q], qy[q])),
                         __fmul_rn(qz[q], qz[q]));
  }

  unsigned long long pk[4][4];
#pragma unroll
  for (int q = 0; q < 4; ++q)
#pragma unroll
    for (int s = 0; s < 4; ++s) pk[q][s] = 0ull;

  for (int tile = 0; tile < 4; ++tile) {
    {
      const float4* gsrc = (const float4*)(xb + tile * 3072);
      float4 a0 = gsrc[tid * 3];
      float4 a1 = gsrc[tid * 3 + 1];
      float4 a2 = gsrc[tid * 3 + 2];
      const int qq = tid * 4;
      soa.xs[qq] = a0.x; soa.xs[qq + 1] = a0.w; soa.xs[qq + 2] = a1.z; soa.xs[qq + 3] = a2.y;
      soa.ys[qq] = a0.y; soa.ys[qq + 1] = a1.x; soa.ys[qq + 2] = a1.w; soa.ys[qq + 3] = a2.z;
      soa.zs[qq] = a0.z; soa.zs[qq + 1] = a1.y; soa.zs[qq + 2] = a2.x; soa.zs[qq + 3] = a2.w;
    }
    __syncthreads();

#pragma unroll 2
    for (int tloc = 0; tloc < 16; ++tloc) {
      const int idx = tloc * 64 + lane;
      const int j = tile * 1024 + idx;
      const float x = soa.xs[idx];
      const float y = soa.ys[idx];
      const float z = soa.zs[idx];
      const float xxj =
          __fadd_rn(__fadd_rn(__fmul_rn(x, x), __fmul_rn(y, y)), __fmul_rn(z, z));
      const unsigned jenc = (unsigned)(4095 - j);
#pragma unroll
      for (int q = 0; q < 4; ++q) {
        const float dot =
            __fmaf_rn(qz[q], z, __fmaf_rn(qy[q], y, __fmul_rn(qx[q], x)));
        const float inner = __fmul_rn(-2.0f, dot);
        const float pval = __fsub_rn(__fsub_rn(nqxx[q], inner), xxj);
        const unsigned bits = __float_as_uint(pval);
        const unsigned ordv = bits ^ (unsigned)(((int)bits >> 31) | 0x80000000);
        const unsigned long long key = ((unsigned long long)ordv << 32) | jenc;
        const bool c0 = key > pk[q][0], c1 = key > pk[q][1],
                   c2 = key > pk[q][2], c3 = key > pk[q][3];
        pk[q][3] = c3 ? (c2 ? pk[q][2] : key) : pk[q][3];
        pk[q][2] = c2 ? (c1 ? pk[q][1] : key) : pk[q][2];
        pk[q][1] = c1 ? (c0 ? pk[q][0] : key) : pk[q][1];
        pk[q][0] = c0 ? key : pk[q][0];
      }
    }
    __syncthreads();
  }

  int stash[4];
  int h[4] = {0, 0, 0, 0};
#pragma unroll
  for (int k = 0; k < K_; ++k) {
    unsigned long long v[4];
#pragma unroll
    for (int q = 0; q < 4; ++q) v[q] = pk[q][0];
#pragma unroll
    for (int off = 32; off >= 1; off >>= 1) {
#pragma unroll
      for (int q = 0; q < 4; ++q) {
        unsigned long long ov = __shfl_xor(v[q], off, 64);
        if (ov > v[q]) v[q] = ov;
      }
    }
#pragma unroll
    for (int q = 0; q < 4; ++q) {
      const int jidx = (4095 - (int)(unsigned)(v[q] & 0xFFFFFFFFull)) & (N_ - 1);
      if (lane == k) stash[q] = jidx;
      if (pk[q][0] == v[q]) {
        pk[q][0] = pk[q][1]; pk[q][1] = pk[q][2]; pk[q][2] = pk[q][3];
        pk[q][3] = 0ull;
        ++h[q];
      }
    }
  }
#pragma unroll
  for (int q = 0; q < 4; ++q) {
    if (__ballot(h[q] >= 4) != 0ull) {
      unsigned long long qq[K_];
#pragma unroll
      for (int k = 0; k < K_; ++k) qq[k] = 0ull;
      for (int t = 0; t < 64; ++t) {
        const int j = t * 64 + lane;
        const unsigned long long key = knn_key(qx[q], qy[q], qz[q], nqxx[q],
                                               xb[3 * j], xb[3 * j + 1],
                                               xb[3 * j + 2], j);
        bool c[K_];
#pragma unroll
        for (int s = 0; s < K_; ++s) c[s] = key > qq[s];
#pragma unroll
        for (int s = K_ - 1; s >= 1; --s)
          qq[s] = c[s] ? (c[s - 1] ? qq[s - 1] : key) : qq[s];
        qq[0] = c[0] ? key : qq[0];
      }
#pragma unroll
      for (int k = 0; k < K_; ++k) {
        unsigned long long v = qq[0];
#pragma unroll
        for (int off = 32; off >= 1; off >>= 1) {
          unsigned long long ov = __shfl_xor(v, off, 64);
          if (ov > v) v = ov;
        }
        const int jidx = (4095 - (int)(unsigned)(v & 0xFFFFFFFFull)) & (N_ - 1);
        if (lane == k) stash[q] = jidx;
        if (qq[0] == v) {
#pragma unroll
          for (int s = 0; s < K_ - 1; ++s) qq[s] = qq[s + 1];
          qq[K_ - 1] = 0ull;
        }
      }
    }
  }

  if (lane < K_) {
    const int pg = P0 + wave * 4;
#pragma unroll
    for (int q = 0; q < 4; ++q)
      nidx_ws[(size_t)(pg + q) * K_ + lane] = stash[q];
  }
}

// ---------------- Kernel A2: cov + eig, one point per thread ----------------
__global__ __launch_bounds__(64) void eig_kernel(const float* __restrict__ xyz,
                                                 const int* __restrict__ nidx_ws,
                                                 float* __restrict__ gf_ws) {
  const int p = blockIdx.x * 64 + threadIdx.x;
  const int b = p >> 12;
  const int i = p & 4095;
  const float* xb = xyz + (size_t)b * (N_ * 3);
  const float qx = xb[3 * i];
  const float qy = xb[3 * i + 1];
  const float qz = xb[3 * i + 2];

  int nidx[K_];
#pragma unroll
  for (int k = 0; k < K_; ++k) nidx[k] = nidx_ws[(size_t)p * K_ + k];

  float c00 = 0, c01 = 0, c02 = 0, c11 = 0, c12 = 0, c22 = 0;
  float mrx = 0, mry = 0, mrz = 0, md = 0;
#pragma unroll
  for (int k = 0; k < K_; ++k) {
    const int j = nidx[k];
    const float rx = __fsub_rn(xb[3 * j], qx);
    const float ry = __fsub_rn(xb[3 * j + 1], qy);
    const float rz = __fsub_rn(xb[3 * j + 2], qz);
    c00 = __fadd_rn(c00, __fmul_rn(rx, rx));
    c01 = __fadd_rn(c01, __fmul_rn(rx, ry));
    c02 = __fadd_rn(c02, __fmul_rn(rx, rz));
    c11 = __fadd_rn(c11, __fmul_rn(ry, ry));
    c12 = __fadd_rn(c12, __fmul_rn(ry, rz));
    c22 = __fadd_rn(c22, __fmul_rn(rz, rz));
    mrx = __fadd_rn(mrx, rx);
    mry = __fadd_rn(mry, ry);
    mrz = __fadd_rn(mrz, rz);
    const float nn = __fadd_rn(__fadd_rn(__fmul_rn(rx, rx), __fmul_rn(ry, ry)),
                               __fmul_rn(rz, rz));
    md = __fadd_rn(md, sqrtf(nn));
  }
  const float s16 = 0.0625f;
  float Z[3][3];
  eig3_f(__fmul_rn(c00, s16), __fmul_rn(c01, s16), __fmul_rn(c02, s16),
         __fmul_rn(c11, s16), __fmul_rn(c12, s16), __fmul_rn(c22, s16), Z);
  float* g = gf_ws + (size_t)p * 12;
  g[0] = Z[0][0]; g[1] = Z[1][0]; g[2] = Z[2][0];
  g[3] = Z[0][2]; g[4] = Z[1][2]; g[5] = Z[2][2];
  g[6] = __fmul_rn(mrx, s16); g[7] = __fmul_rn(mry, s16);
  g[8] = __fmul_rn(mrz, s16);
  g[9] = __fmul_rn(md, s16);
}

// ---------------- Kernel B: block-cooperative MLPs, channel-outer matvecs ----------------
__global__ __launch_bounds__(256) void mlp_kernel(
    const float* __restrict__ feats, const int* __restrict__ nidx_ws,
    const float* __restrict__ gf_ws,
    const float* __restrict__ geo_w1, const float* __restrict__ geo_b1,
    const float* __restrict__ geo_g1, const float* __restrict__ geo_be1,
    const float* __restrict__ geo_w2, const float* __restrict__ geo_b2,
    const float* __restrict__ diff_w1, const float* __restrict__ diff_b1,
    const float* __restrict__ diff_g1, const float* __restrict__ diff_be1,
    const float* __restrict__ diff_w2, const float* __restrict__ diff_b2,
    const float* __restrict__ ep_w1, const float* __restrict__ ep_b1,
    const float* __restrict__ ep_w2, const float* __restrict__ ep_b2,
    const float* __restrict__ ref_w1, const float* __restrict__ ref_b1,
    const float* __restrict__ ref_g1, const float* __restrict__ ref_be1,
    float* __restrict__ out, float* __restrict__ out_prob) {

  __shared__ float w[8192];
  __shared__ float fsh[16 * 128];
  __shared__ float sdif[16 * 128];
  __shared__ float ysh[16 * 64];
  __shared__ float edsh[16 * 128];
  __shared__ float insh[16 * 12];
  __shared__ int nsh[16 * 16];

  const int tid = threadIdx.x;
  const int lane = tid & 63;
  const int g = tid >> 6;
  const int P0 = blockIdx.x * 16;
  const int b = P0 >> 12;
  const int r0 = P0 & 4095;
  const float* fb = feats + (size_t)b * N_ * C_;

  if (tid < 192) insh[tid] = gf_ws[(size_t)P0 * 12 + tid];
  nsh[tid] = nidx_ws[(size_t)P0 * K_ + tid];
#pragma unroll
  for (int m = 0; m < 8; ++m)
    fsh[m * 256 + tid] = fb[(size_t)r0 * C_ + m * 256 + tid];
  if (tid < 160) ((float4*)w)[tid] = ((const float4*)geo_w1)[tid];
#pragma unroll
  for (int m = 0; m < 4; ++m)
    ((float4*)(w + 640))[m * 256 + tid] = ((const float4*)geo_w2)[m * 256 + tid];
  __syncthreads();

  // geo layer 1 (channel-outer) + LN
  {
    float acc[4] = {0, 0, 0, 0};
#pragma unroll
    for (int c = 0; c < 10; ++c) {
      const float wv = w[c * 64 + lane];
#pragma unroll
      for (int ptl = 0; ptl < 4; ++ptl)
        acc[ptl] += insh[(g * 4 + ptl) * 12 + c] * wv;
    }
#pragma unroll
    for (int ptl = 0; ptl < 4; ++ptl) {
      const int pt = g * 4 + ptl;
      float a = acc[ptl] + geo_b1[lane];
      float m = wave_sum64(a) * (1.0f / 64.0f);
      float xm = a - m;
      float var = wave_sum64(xm * xm) * (1.0f / 64.0f);
      float yv = xm * (1.0f / sqrtf(var + 1e-5f)) * geo_g1[lane] + geo_be1[lane];
      ysh[pt * 64 + lane] = fmaxf(yv, 0.0f);
    }
  }
  __syncthreads();

  // geo layer 2 (channel-outer)
  float ge[4] = {0, 0, 0, 0}, de[4], prob[4];
#pragma unroll 4
  for (int c = 0; c < 64; ++c) {
    const float wv = w[640 + c * 64 + lane];
#pragma unroll
    for (int ptl = 0; ptl < 4; ++ptl)
      ge[ptl] += ysh[(g * 4 + ptl) * 64 + c] * wv;
  }
#pragma unroll
  for (int ptl = 0; ptl < 4; ++ptl) ge[ptl] += geo_b2[lane];

  // feat_diff
  {
    const int h2 = tid >> 7, c = tid & 127;
    for (int ptp = 0; ptp < 8; ++ptp) {
      const int pt = h2 * 8 + ptp;
      const float fv = fsh[pt * 128 + c];
      float s = 0.0f;
#pragma unroll
      for (int k = 0; k < K_; ++k) {
        const int j = nsh[pt * 16 + k];
        s += fabsf(fv - fb[(size_t)j * C_ + c]);
      }
      sdif[pt * 128 + c] = s * (1.0f / 16.0f);
    }
  }
  __syncthreads();
#pragma unroll
  for (int m = 0; m < 8; ++m)
    ((float4*)w)[m * 256 + tid] = ((const float4*)diff_w1)[m * 256 + tid];
  __syncthreads();

  // diff layer 1 (channel-outer) + LN
  {
    float acc[4] = {0, 0, 0, 0};
#pragma unroll 4
    for (int c = 0; c < 128; ++c) {
      const float wv = w[c * 64 + lane];
#pragma unroll
      for (int ptl = 0; ptl < 4; ++ptl)
        acc[ptl] += sdif[(g * 4 + ptl) * 128 + c] * wv;
    }
#pragma unroll
    for (int ptl = 0; ptl < 4; ++ptl) {
      const int pt = g * 4 + ptl;
      float a = acc[ptl] + diff_b1[lane];
      float m = wave_sum64(a) * (1.0f / 64.0f);
      float xm = a - m;
      float var = wave_sum64(xm * xm) * (1.0f / 64.0f);
      float yv = xm * (1.0f / sqrtf(var + 1e-5f)) * diff_g1[lane] + diff_be1[lane];
      ysh[pt * 64 + lane] = fmaxf(yv, 0.0f);
    }
  }
  __syncthreads();
#pragma unroll
  for (int m = 0; m < 4; ++m)
    ((float4*)w)[m * 256 + tid] = ((const float4*)diff_w2)[m * 256 + tid];
#pragma unroll
  for (int m = 0; m < 4; ++m)
    ((float4*)w)[1024 + m * 256 + tid] = ((const float4*)ep_w1)[m * 256 + tid];
  __syncthreads();

  // diff layer 2 (channel-outer), stash [ge||de]
  {
    float acc[4] = {0, 0, 0, 0};
#pragma unroll 4
    for (int c = 0; c < 64; ++c) {
      const float wv = w[c * 64 + lane];
#pragma unroll
      for (int ptl = 0; ptl < 4; ++ptl)
        acc[ptl] += ysh[(g * 4 + ptl) * 64 + c] * wv;
    }
#pragma unroll
    for (int ptl = 0; ptl < 4; ++ptl) {
      const int pt = g * 4 + ptl;
      de[ptl] = acc[ptl] + diff_b2[lane];
      edsh[pt * 128 + lane] = ge[ptl];
      edsh[pt * 128 + 64 + lane] = de[ptl];
    }
  }
  __syncthreads();

  // edge-prob MLP (channel-outer)
  const int u = lane & 31;
  {
    float ea[4] = {0, 0, 0, 0};
#pragma unroll 4
    for (int c = 0; c < 128; ++c) {
      const float wv = w[4096 + c * 32 + u];
#pragma unroll
      for (int ptl = 0; ptl < 4; ++ptl)
        ea[ptl] += edsh[(g * 4 + ptl) * 128 + c] * wv;
    }
#pragma unroll
    for (int ptl = 0; ptl < 4; ++ptl) {
      float a = ea[ptl] + ep_b1[u];
      float hh = (lane < 32) ? fmaxf(a, 0.0f) * ep_w2[u] : 0.0f;
      float tsum = wave_sum64(hh) + ep_b2[0];
      prob[ptl] = 1.0f / (1.0f + expf(-tsum));
    }
  }
  __syncthreads();
#pragma unroll
  for (int ptl = 0; ptl < 4; ++ptl) {
    const int pt = g * 4 + ptl;
    edsh[pt * 128 + lane] = ge[ptl] * prob[ptl];
    edsh[pt * 128 + 64 + lane] = de[ptl] * prob[ptl];
  }

  // ref matvec: 4 chunks of 64 input-channels, channel-outer
  float a0[4] = {0, 0, 0, 0}, a1[4] = {0, 0, 0, 0};
  for (int ch = 0; ch < 4; ++ch) {
    __syncthreads();
    {
      const float4* gsrc = (const float4*)(ref_w1 + ch * 8192);
#pragma unroll
      for (int m = 0; m < 8; ++m) ((float4*)w)[m * 256 + tid] = gsrc[m * 256 + tid];
    }
    __syncthreads();
#pragma unroll 4
    for (int cl = 0; cl < 64; ++cl) {
      const float w0 = w[cl * 128 + lane];
      const float w1v = w[cl * 128 + 64 + lane];
#pragma unroll
      for (int ptl = 0; ptl < 4; ++ptl) {
        const int pt = g * 4 + ptl;
        const float e = (ch < 2) ? fsh[pt * 128 + ch * 64 + cl]
                                 : edsh[pt * 128 + (ch - 2) * 64 + cl];
        a0[ptl] += e * w0;
        a1[ptl] += e * w1v;
      }
    }
  }

  // epilogue
#pragma unroll
  for (int ptl = 0; ptl < 4; ++ptl) {
    const int pt = g * 4 + ptl;
    float A0 = a0[ptl] + ref_b1[lane];
    float A1 = a1[ptl] + ref_b1[64 + lane];
    float mm2 = wave_sum64(A0 + A1) * (1.0f / 128.0f);
    float d0 = A0 - mm2, d1 = A1 - mm2;
    float var2 = wave_sum64(d0 * d0 + d1 * d1) * (1.0f / 128.0f);
    float rs = 1.0f / sqrtf(var2 + 1e-5f);
    float y0 = d0 * rs * ref_g1[lane] + ref_be1[lane];
    float y1 = d1 * rs * ref_g1[64 + lane] + ref_be1[64 + lane];
    y0 = fmaxf(y0, 0.0f) + fsh[pt * 128 + lane];
    y1 = fmaxf(y1, 0.0f) + fsh[pt * 128 + 64 + lane];
    out[(size_t)(P0 + pt) * 128 + lane] = y0;
    out[(size_t)(P0 + pt) * 128 + 64 + lane] = y1;
    if (lane == 0) out_prob[P0 + pt] = prob[ptl];
  }
}

// ---------------- Fallback: R8 fused kernel (proven) ----------------
__global__ __launch_bounds__(256) void fused_kernel(
    const float* __restrict__ xyz, const float* __restrict__ feats,
    const float* __restrict__ geo_w1, const float* __restrict__ geo_b1,
    const float* __restrict__ geo_g1, const float* __restrict__ geo_be1,
    const float* __restrict__ geo_w2, const float* __restrict__ geo_b2,
    const float* __restrict__ diff_w1, const float* __restrict__ diff_b1,
    const float* __restrict__ diff_g1, const float* __restrict__ diff_be1,
    const float* __restrict__ diff_w2, const float* __restrict__ diff_b2,
    const float* __restrict__ ep_w1, const float* __restrict__ ep_b1,
    const float* __restrict__ ep_w2, const float* __restrict__ ep_b2,
    const float* __restrict__ ref_w1, const float* __restrict__ ref_b1,
    const float* __restrict__ ref_g1, const float* __restrict__ ref_be1,
    float* __restrict__ out, float* __restrict__ out_prob) {

  __shared__ float4 tile4[1024];

  const int wave = threadIdx.x >> 6;
  const int lane = threadIdx.x & 63;
  const int tid = threadIdx.x;
  const int p = blockIdx.x * 4 + wave;
  const int b = p >> 12;
  const int i = p & 4095;
  const float* xb = xyz + (size_t)b * (N_ * 3);

  const float qx = xb[3 * i];
  const float qy = xb[3 * i + 1];
  const float qz = xb[3 * i + 2];
  const float qxx =
      __fadd_rn(__fadd_rn(__fmul_rn(qx, qx), __fmul_rn(qy, qy)), __fmul_rn(qz, qz));
  const float nqxx = -qxx;

  unsigned long long pk[4] = {0ull, 0ull, 0ull, 0ull};
  for (int tile = 0; tile < 4; ++tile) {
    {
      const float4* gsrc = (const float4*)(xb + tile * 3072);
      float4 r0v = gsrc[tid * 3];
      float4 r1 = gsrc[tid * 3 + 1];
      float4 r2 = gsrc[tid * 3 + 2];
      const int base = tid * 4;
      tile4[base]     = make_float4(r0v.x, r0v.y, r0v.z, 0.0f);
      tile4[base + 1] = make_float4(r0v.w, r1.x, r1.y, 0.0f);
      tile4[base + 2] = make_float4(r1.z, r1.w, r2.x, 0.0f);
      tile4[base + 3] = make_float4(r2.y, r2.z, r2.w, 0.0f);
    }
    __syncthreads();
#pragma unroll 4
    for (int tloc = 0; tloc < 16; ++tloc) {
      const int j = tile * 1024 + tloc * 64 + lane;
      const float4 pt = tile4[tloc * 64 + lane];
      const unsigned long long key = knn_key(qx, qy, qz, nqxx, pt.x, pt.y, pt.z, j);
      const bool c0 = key > pk[0], c1 = key > pk[1], c2 = key > pk[2], c3 = key > pk[3];
      pk[3] = c3 ? (c2 ? pk[2] : key) : pk[3];
      pk[2] = c2 ? (c1 ? pk[1] : key) : pk[2];
      pk[1] = c1 ? (c0 ? pk[0] : key) : pk[1];
      pk[0] = c0 ? key : pk[0];
    }
    __syncthreads();
  }

  int nidx[K_];
  int h = 0;
#pragma unroll
  for (int k = 0; k < K_; ++k) {
    unsigned long long v = pk[0];
#pragma unroll
    for (int off = 32; off >= 1; off >>= 1) {
      unsigned long long ov = __shfl_xor(v, off, 64);
      if (ov > v) v = ov;
    }
    nidx[k] = (4095 - (int)(unsigned)(v & 0xFFFFFFFFull)) & (N_ - 1);
    if (pk[0] == v) {
      pk[0] = pk[1]; pk[1] = pk[2]; pk[2] = pk[3]; pk[3] = 0ull;
      ++h;
    }
  }
  if (__ballot(h >= 4) != 0ull) {
    unsigned long long q[K_];
#pragma unroll
    for (int k = 0; k < K_; ++k) q[k] = 0ull;
    for (int t = 0; t < 64; ++t) {
      const int j = t * 64 + lane;
      const unsigned long long key =
          knn_key(qx, qy, qz, nqxx, xb[3 * j], xb[3 * j + 1], xb[3 * j + 2], j);
      bool c[K_];
#pragma unroll
      for (int s = 0; s < K_; ++s) c[s] = key > q[s];
#pragma unroll
      for (int s = K_ - 1; s >= 1; --s)
        q[s] = c[s] ? (c[s - 1] ? q[s - 1] : key) : q[s];
      q[0] = c[0] ? key : q[0];
    }
#pragma unroll
    for (int k = 0; k < K_; ++k) {
      unsigned long long v = q[0];
#pragma unroll
      for (int off = 32; off >= 1; off >>= 1) {
        unsigned long long ov = __shfl_xor(v, off, 64);
        if (ov > v) v = ov;
      }
      nidx[k] = (4095 - (int)(unsigned)(v & 0xFFFFFFFFull)) & (N_ - 1);
      if (q[0] == v) {
#pragma unroll
        for (int s = 0; s < K_ - 1; ++s) q[s] = q[s + 1];
        q[K_ - 1] = 0ull;
      }
    }
  }

  float c00 = 0, c01 = 0, c02 = 0, c11 = 0, c12 = 0, c22 = 0;
  float mrx = 0, mry = 0, mrz = 0, md = 0;
#pragma unroll
  for (int k = 0; k < K_; ++k) {
    const int j = nidx[k];
    const float rx = __fsub_rn(xb[3 * j], qx);
    const float ry = __fsub_rn(xb[3 * j + 1], qy);
    const float rz = __fsub_rn(xb[3 * j + 2], qz);
    c00 = __fadd_rn(c00, __fmul_rn(rx, rx));
    c01 = __fadd_rn(c01, __fmul_rn(rx, ry));
    c02 = __fadd_rn(c02, __fmul_rn(rx, rz));
    c11 = __fadd_rn(c11, __fmul_rn(ry, ry));
    c12 = __fadd_rn(c12, __fmul_rn(ry, rz));
    c22 = __fadd_rn(c22, __fmul_rn(rz, rz));
    mrx = __fadd_rn(mrx, rx);
    mry = __fadd_rn(mry, ry);
    mrz = __fadd_rn(mrz, rz);
    const float nn = __fadd_rn(__fadd_rn(__fmul_rn(rx, rx), __fmul_rn(ry, ry)),
                               __fmul_rn(rz, rz));
    md = __fadd_rn(md, sqrtf(nn));
  }
  const float s16 = 0.0625f;
  float Z[3][3];
  eig3_f(__fmul_rn(c00, s16), __fmul_rn(c01, s16), __fmul_rn(c02, s16),
         __fmul_rn(c11, s16), __fmul_rn(c12, s16), __fmul_rn(c22, s16), Z);
  float gf[10];
  gf[0] = Z[0][0]; gf[1] = Z[1][0]; gf[2] = Z[2][0];
  gf[3] = Z[0][2]; gf[4] = Z[1][2]; gf[5] = Z[2][2];
  gf[6] = __fmul_rn(mrx, s16); gf[7] = __fmul_rn(mry, s16);
  gf[8] = __fmul_rn(mrz, s16);
  gf[9] = __fmul_rn(md, s16);

  float acc = 0.0f;
#pragma unroll
  for (int ii = 0; ii < 10; ++ii) acc += gf[ii] * geo_w1[ii * 64 + lane];
  acc += geo_b1[lane];
  float yr;
  {
    float m = wave_sum64(acc) * (1.0f / 64.0f);
    float xm = acc - m;
    float var = wave_sum64(xm * xm) * (1.0f / 64.0f);
    float yv = xm * (1.0f / sqrtf(var + 1e-5f)) * geo_g1[lane] + geo_be1[lane];
    yr = fmaxf(yv, 0.0f);
  }
  float ge = 0.0f;
#pragma unroll 8
  for (int jj = 0; jj < 64; ++jj) ge += __shfl(yr, jj, 64) * geo_w2[jj * 64 + lane];
  ge += geo_b2[lane];

  const float* fb = feats + (size_t)b * N_ * C_;
  const float* fi = fb + (size_t)i * C_;
  const float f0 = fi[lane];
  const float f1 = fi[64 + lane];
  float s0 = 0.0f, s1 = 0.0f;
#pragma unroll
  for (int k = 0; k < K_; ++k) {
    const float* fj = fb + (size_t)nidx[k] * C_;
    s0 += fabsf(f0 - fj[lane]);
    s1 += fabsf(f1 - fj[64 + lane]);
  }
  s0 *= (1.0f / 16.0f);
  s1 *= (1.0f / 16.0f);
  float acc2 = 0.0f;
#pragma unroll 8
  for (int c = 0; c < 64; ++c) acc2 += __shfl(s0, c, 64) * diff_w1[c * 64 + lane];
#pragma unroll 8
  for (int c = 64; c < 128; ++c) acc2 += __shfl(s1, c - 64, 64) * diff_w1[c * 64 + lane];
  acc2 += diff_b1[lane];
  float yr2;
  {
    float m = wave_sum64(acc2) * (1.0f / 64.0f);
    float xm = acc2 - m;
    float var = wave_sum64(xm * xm) * (1.0f / 64.0f);
    float yv = xm * (1.0f / sqrtf(var + 1e-5f)) * diff_g1[lane] + diff_be1[lane];
    yr2 = fmaxf(yv, 0.0f);
  }
  float de = 0.0f;
#pragma unroll 8
  for (int jj = 0; jj < 64; ++jj) de += __shfl(yr2, jj, 64) * diff_w2[jj * 64 + lane];
  de += diff_b2[lane];

  {
    const int u = lane & 31;
    float a = 0.0f;
#pragma unroll 8
    for (int c = 0; c < 64; ++c) a += __shfl(ge, c, 64) * ep_w1[c * 32 + u];
#pragma unroll 8
    for (int c = 64; c < 128; ++c) a += __shfl(de, c - 64, 64) * ep_w1[c * 32 + u];
    a += ep_b1[u];
    float hh = (lane < 32) ? fmaxf(a, 0.0f) * ep_w2[u] : 0.0f;
    float tsum = wave_sum64(hh) + ep_b2[0];
    float prob = 1.0f / (1.0f + expf(-tsum));

    const float gep = ge * prob;
    const float dep = de * prob;
    float a0 = 0.0f, a1 = 0.0f;
#pragma unroll 4
    for (int c = 0; c < 64; ++c) {
      float ec = __shfl(f0, c, 64);
      a0 += ec * ref_w1[c * 128 + lane];
      a1 += ec * ref_w1[c * 128 + 64 + lane];
    }
#pragma unroll 4
    for (int c = 64; c < 128; ++c) {
      float ec = __shfl(f1, c - 64, 64);
      a0 += ec * ref_w1[c * 128 + lane];
      a1 += ec * ref_w1[c * 128 + 64 + lane];
    }
#pragma unroll 4
    for (int c = 128; c < 192; ++c) {
      float ec = __shfl(gep, c - 128, 64);
      a0 += ec * ref_w1[c * 128 + lane];
      a1 += ec * ref_w1[c * 128 + 64 + lane];
    }
#pragma unroll 4
    for (int c = 192; c < 256; ++c) {
      float ec = __shfl(dep, c - 192, 64);
      a0 += ec * ref_w1[c * 128 + lane];
      a1 += ec * ref_w1[c * 128 + 64 + lane];
    }
    a0 += ref_b1[lane];
    a1 += ref_b1[64 + lane];
    float mm2 = wave_sum64(a0 + a1) * (1.0f / 128.0f);
    float d0 = a0 - mm2, d1 = a1 - mm2;
    float var2 = wave_sum64(d0 * d0 + d1 * d1) * (1.0f / 128.0f);
    float rs = 1.0f / sqrtf(var2 + 1e-5f);
    float y0 = d0 * rs * ref_g1[lane] + ref_be1[lane];
    float y1 = d1 * rs * ref_g1[64 + lane] + ref_be1[64 + lane];
    y0 = fmaxf(y0, 0.0f) + f0;
    y1 = fmaxf(y1, 0.0f) + f1;
    out[(size_t)p * 128 + lane] = y0;
    out[(size_t)p * 128 + 64 + lane] = y1;
    if (lane == 0) out_prob[p] = prob;
  }
}

extern "C" void kernel_launch(void* const* d_in, const int* in_sizes, int n_in,
                              void* d_out, int out_size, void* d_ws, size_t ws_size,
                              hipStream_t stream) {
  const float* xyz = (const float*)d_in[0];
  const float* features = (const float*)d_in[1];
  const float* geo_w1 = (const float*)d_in[2];
  const float* geo_b1 = (const float*)d_in[3];
  const float* geo_g1 = (const float*)d_in[4];
  const float* geo_be1 = (const float*)d_in[5];
  const float* geo_w2 = (const float*)d_in[6];
  const float* geo_b2 = (const float*)d_in[7];
  const float* diff_w1 = (const float*)d_in[8];
  const float* diff_b1 = (const float*)d_in[9];
  const float* diff_g1 = (const float*)d_in[10];
  const float* diff_be1 = (const float*)d_in[11];
  const float* diff_w2 = (const float*)d_in[12];
  const float* diff_b2 = (const float*)d_in[13];
  const float* ep_w1 = (const float*)d_in[14];
  const float* ep_b1 = (const float*)d_in[15];
  const float* ep_w2 = (const float*)d_in[16];
  const float* ep_b2 = (const float*)d_in[17];
  const float* ref_w1 = (const float*)d_in[18];
  const float* ref_b1 = (const float*)d_in[19];
  const float* ref_g1 = (const float*)d_in[20];
  const float* ref_be1 = (const float*)d_in[21];

  float* out = (float*)d_out;
  float* out_prob = out + (size_t)NPT * C_;

  if (ws_size >= (size_t)(2 * 1024 * 1024)) {
    int* nidx_ws = (int*)d_ws;                             // 1 MB
    float* gf_ws = (float*)((char*)d_ws + (1u << 20));     // 768 KB
    knn_kernel<<<dim3(NPT / 16), dim3(256), 0, stream>>>(xyz, nidx_ws);
    eig_kernel<<<dim3(NPT / 64), dim3(64), 0, stream>>>(xyz, nidx_ws, gf_ws);
    mlp_kernel<<<dim3(NPT / 16), dim3(256), 0, stream>>>(
        features, nidx_ws, gf_ws, geo_w1, geo_b1, geo_g1, geo_be1, geo_w2,
        geo_b2, diff_w1, diff_b1, diff_g1, diff_be1, diff_w2, diff_b2, ep_w1,
        ep_b1, ep_w2, ep_b2, ref_w1, ref_b1, ref_g1, ref_be1, out, out_prob);
  } else {
    fused_kernel<<<dim3(NPT / 4), dim3(256), 0, stream>>>(
        xyz, features, geo_w1, geo_b1, geo_g1, geo_be1, geo_w2, geo_b2,
        diff_w1, diff_b1, diff_g1, diff_be1, diff_w2, diff_b2, ep_w1, ep_b1,
        ep_w2, ep_b2, ref_w1, ref_b1, ref_g1, ref_be1, out, out_prob);
  }
}

// Round 13
// 324.591 us; speedup vs baseline: 1.6651x; 1.0016x over previous
//
#include <hip/hip_runtime.h>
#include <hip/hip_bf16.h>

// B=4, N=4096, C=128, K=16. float32 in/out.
// R12: knn 128us (VALUBusy 52%, 4 waves/SIMD) + eig + mlp = 325us.
// R13: knn TLP x2 -- 2 queries per wave (grid NPT/8, 8192 waves -> 8/SIMD),
// __launch_bounds__(256,6) to keep VGPR under the 6-waves/SIMD cliff.
// Scan/merge/fallback logic and all arithmetic unchanged (numpy-f32-faithful).
// eig/mlp kernels unchanged from R12 (proven).
// Fallback to proven R8 fused kernel if ws_size < 2MB.
#define N_ 4096
#define C_ 128
#define K_ 16
#define NPT 16384

__device__ __forceinline__ float wave_sum64(float v) {
#pragma unroll
  for (int off = 32; off >= 1; off >>= 1) v += __shfl_xor(v, off, 64);
  return v;
}

// ---------------- LAPACK f32 helpers ----------------

__device__ __forceinline__ float sign_f(float a, float b) {
  return copysignf(fabsf(a), b);
}

__device__ float lapy2_f(float x, float y) {
#pragma clang fp contract(off)
  float xa = fabsf(x), ya = fabsf(y);
  float w = fmaxf(xa, ya), z = fminf(xa, ya);
  if (z == 0.0f) return w;
  float t = z / w;
  return w * sqrtf(1.0f + t * t);
}

__device__ void lartg_f(float f, float g, float& c, float& s, float& r) {
#pragma clang fp contract(off)
  if (g == 0.0f) {
    c = 1.0f; s = 0.0f; r = f;
  } else if (f == 0.0f) {
    c = 0.0f; s = copysignf(1.0f, g); r = fabsf(g);
  } else {
    float d = sqrtf(f * f + g * g);
    c = fabsf(f) / d;
    r = sign_f(d, f);
    s = g / r;
  }
}

__device__ void laev2_f(float a, float b, float cc, float& rt1, float& rt2,
                        float& cs1, float& sn1) {
#pragma clang fp contract(off)
  float sm = a + cc;
  float df = a - cc;
  float adf = fabsf(df);
  float tb = b + b;
  float ab = fabsf(tb);
  float acmx, acmn;
  if (fabsf(a) > fabsf(cc)) { acmx = a; acmn = cc; } else { acmx = cc; acmn = a; }
  float rt;
  if (adf > ab) {
    float t = ab / adf; rt = adf * sqrtf(1.0f + t * t);
  } else if (adf < ab) {
    float t = adf / ab; rt = ab * sqrtf(1.0f + t * t);
  } else {
    rt = ab * sqrtf(2.0f);
  }
  int sgn1;
  if (sm < 0.0f) {
    rt1 = 0.5f * (sm - rt); sgn1 = -1;
    rt2 = (acmx / rt1) * acmn - (b / rt1) * b;
  } else if (sm > 0.0f) {
    rt1 = 0.5f * (sm + rt); sgn1 = 1;
    rt2 = (acmx / rt1) * acmn - (b / rt1) * b;
  } else {
    rt1 = 0.5f * rt; rt2 = -0.5f * rt; sgn1 = 1;
  }
  float cs; int sgn2;
  if (df >= 0.0f) { cs = df + rt; sgn2 = 1; } else { cs = df - rt; sgn2 = -1; }
  float acs = fabsf(cs);
  if (acs > ab) {
    float ct = -tb / cs;
    sn1 = 1.0f / sqrtf(1.0f + ct * ct);
    cs1 = ct * sn1;
  } else {
    if (ab == 0.0f) { cs1 = 1.0f; sn1 = 0.0f; }
    else {
      float tn = -cs / tb;
      cs1 = 1.0f / sqrtf(1.0f + tn * tn);
      sn1 = tn * cs1;
    }
  }
  if (sgn1 == sgn2) { float tn = cs1; cs1 = -sn1; sn1 = tn; }
}

__device__ void steqr3_f(float d[3], float e[2], float Z[3][3]) {
#pragma clang fp contract(off)
  const int n = 3;
  const float eps = 5.9604644775390625e-08f;
  const float eps2 = eps * eps;
  const float safmin = 1.17549435e-38f;
  const int nmaxit = n * 30;
  int jtot = 0;
  int l1 = 1;

  for (int og = 0; og < 16; ++og) {
    if (l1 > n) break;
    if (l1 > 1) e[l1 - 2] = 0.0f;
    int m, l, lend;
    if (l1 <= n - 1) {
      bool found = false;
      for (m = l1; m <= n - 1; ++m) {
        float tst = fabsf(e[m - 1]);
        if (tst == 0.0f) { found = true; break; }
        if (tst <= (sqrtf(fabsf(d[m - 1])) * sqrtf(fabsf(d[m]))) * eps) {
          e[m - 1] = 0.0f; found = true; break;
        }
      }
      if (!found) m = n;
    } else {
      m = n;
    }
    l = l1; lend = m; l1 = m + 1;
    if (lend == l) continue;
    if (fabsf(d[lend - 1]) < fabsf(d[l - 1])) { int t = l; l = lend; lend = t; }

    if (lend > l) {
      for (int it = 0; it < 128; ++it) {
        int mm;
        if (l != lend) {
          bool f2 = false;
          for (mm = l; mm <= lend - 1; ++mm) {
            float tst = e[mm - 1] * e[mm - 1];
            if (tst <= (eps2 * fabsf(d[mm - 1])) * fabsf(d[mm]) + safmin) { f2 = true; break; }
          }
          if (!f2) mm = lend;
        } else mm = lend;
        if (mm < lend) e[mm - 1] = 0.0f;
        float p = d[l - 1];
        if (mm == l) {
          d[l - 1] = p; ++l;
          if (l <= lend) continue;
          break;
        }
        if (mm == l + 1) {
          float rt1, rt2, cc, ss;
          laev2_f(d[l - 1], e[l - 1], d[l], rt1, rt2, cc, ss);
          for (int r = 0; r < n; ++r) {
            float temp = Z[r][l];
            Z[r][l] = cc * temp - ss * Z[r][l - 1];
            Z[r][l - 1] = ss * temp + cc * Z[r][l - 1];
          }
          d[l - 1] = rt1; d[l] = rt2; e[l - 1] = 0.0f;
          l += 2;
          if (l <= lend) continue;
          break;
        }
        if (jtot == nmaxit) break;
        ++jtot;
        float g = (d[l] - p) / (2.0f * e[l - 1]);
        float r = lapy2_f(g, 1.0f);
        g = d[mm - 1] - p + e[l - 1] / (g + sign_f(r, g));
        float s = 1.0f, c = 1.0f;
        p = 0.0f;
        float csv[2], snv[2];
        for (int i = mm - 1; i >= l; --i) {
          float f = s * e[i - 1];
          float bb = c * e[i - 1];
          lartg_f(g, f, c, s, r);
          if (i != mm - 1) e[i] = r;
          g = d[i] - p;
          r = (d[i - 1] - g) * s + 2.0f * c * bb;
          p = s * r;
          d[i] = g + p;
          g = c * r - bb;
          csv[i - l] = c;
          snv[i - l] = -s;
        }
        int mml = mm - l;
        for (int j = mml; j >= 1; --j) {
          float cc = csv[j - 1], ss = snv[j - 1];
          for (int r2 = 0; r2 < n; ++r2) {
            float temp = Z[r2][l + j - 1];
            Z[r2][l + j - 1] = cc * temp - ss * Z[r2][l + j - 2];
            Z[r2][l + j - 2] = ss * temp + cc * Z[r2][l + j - 2];
          }
        }
        d[l - 1] -= p;
        e[l - 1] = g;
      }
    } else {
      for (int it = 0; it < 128; ++it) {
        int mm;
        if (l != lend) {
          bool f2 = false;
          for (mm = l; mm >= lend + 1; --mm) {
            float tst = e[mm - 2] * e[mm - 2];
            if (tst <= (eps2 * fabsf(d[mm - 1])) * fabsf(d[mm - 2]) + safmin) { f2 = true; break; }
          }
          if (!f2) mm = lend;
        } else mm = lend;
        if (mm > lend) e[mm - 2] = 0.0f;
        float p = d[l - 1];
        if (mm == l) {
          d[l - 1] = p; --l;
          if (l >= lend) continue;
          break;
        }
        if (mm == l - 1) {
          float rt1, rt2, cc, ss;
          laev2_f(d[l - 2], e[l - 2], d[l - 1], rt1, rt2, cc, ss);
          for (int r = 0; r < n; ++r) {
            float temp = Z[r][l - 1];
            Z[r][l - 1] = cc * temp - ss * Z[r][l - 2];
            Z[r][l - 2] = ss * temp + cc * Z[r][l - 2];
          }
          d[l - 2] = rt1; d[l - 1] = rt2; e[l - 2] = 0.0f;
          l -= 2;
          if (l >= lend) continue;
          break;
        }
        if (jtot == nmaxit) break;
        ++jtot;
        float g = (d[l - 2] - p) / (2.0f * e[l - 2]);
        float r = lapy2_f(g, 1.0f);
        g = d[mm - 1] - p + e[l - 2] / (g + sign_f(r, g));
        float s = 1.0f, c = 1.0f;
        p = 0.0f;
        float csv[2], snv[2];
        for (int i = mm; i <= l - 1; ++i) {
          float f = s * e[i - 1];
          float bb = c * e[i - 1];
          lartg_f(g, f, c, s, r);
          if (i != mm) e[i - 2] = r;
          g = d[i - 1] - p;
          r = (d[i] - g) * s + 2.0f * c * bb;
          p = s * r;
          d[i - 1] = g + p;
          g = c * r - bb;
          csv[i - mm] = c;
          snv[i - mm] = s;
        }
        int lm = l - mm;
        for (int j = 1; j <= lm; ++j) {
          float cc = csv[j - 1], ss = snv[j - 1];
          for (int r2 = 0; r2 < n; ++r2) {
            float temp = Z[r2][mm + j - 1];
            Z[r2][mm + j - 1] = cc * temp - ss * Z[r2][mm + j - 2];
            Z[r2][mm + j - 2] = ss * temp + cc * Z[r2][mm + j - 2];
          }
        }
        d[l - 1] -= p;
        e[l - 2] = g;
      }
    }
  }
  for (int ii = 2; ii <= n; ++ii) {
    int i = ii - 1, k = i;
    float p = d[i - 1];
    for (int j = ii; j <= n; ++j) {
      if (d[j - 1] < p) { k = j; p = d[j - 1]; }
    }
    if (k != i) {
      d[k - 1] = d[i - 1]; d[i - 1] = p;
      for (int r = 0; r < n; ++r) {
        float t = Z[r][i - 1]; Z[r][i - 1] = Z[r][k - 1]; Z[r][k - 1] = t;
      }
    }
  }
}

__device__ void eig3_f(float A00, float A10, float A20,
                       float A11, float A21, float A22, float Z[3][3]) {
#pragma clang fp contract(off)
  float d[3], e[2];
  float tau = 0.0f, v2 = 0.0f;
  d[0] = A00;
  float xnorm = fabsf(A20);
  if (xnorm == 0.0f) {
    tau = 0.0f; v2 = 0.0f;
    e[0] = A10; d[1] = A11; e[1] = A21; d[2] = A22;
  } else {
    float beta = -sign_f(lapy2_f(A10, xnorm), A10);
    tau = (beta - A10) / beta;
    float inv = 1.0f / (A10 - beta);
    v2 = A20 * inv;
    e[0] = beta;
    float x0 = tau * A11;
    float x1 = tau * A21;
    float tmp2 = A21 * v2;
    x0 = x0 + tau * tmp2;
    x1 = x1 + (tau * v2) * A22;
    float dotv = x0 + x1 * v2;
    float aw = (-0.5f * tau) * dotv;
    float w0 = x0 + aw;
    float w1 = x1 + aw * v2;
    d[1] = (A11 - w0) - w0;
    float pq = v2 * w0;
    e[1] = (A21 - pq) - w1;
    float pr = v2 * w1;
    d[2] = (A22 - pr) - pr;
  }
  Z[0][0] = 1.0f; Z[0][1] = 0.0f; Z[0][2] = 0.0f;
  Z[1][0] = 0.0f; Z[1][1] = 1.0f; Z[1][2] = 0.0f;
  Z[2][0] = 0.0f; Z[2][1] = 0.0f; Z[2][2] = 1.0f;
  steqr3_f(d, e, Z);
  if (tau != 0.0f) {
    for (int j = 0; j < 3; ++j) {
      float sum = Z[1][j] + v2 * Z[2][j];
      float tw = tau * sum;
      Z[1][j] = Z[1][j] - tw;
      Z[2][j] = Z[2][j] - v2 * tw;
    }
  }
}

// ---------------- KNN key (numpy-f32-faithful) ----------------
__device__ __forceinline__ unsigned long long knn_key(float qx, float qy, float qz,
                                                      float nqxx, float x, float y,
                                                      float z, int j) {
  const float dot = __fmaf_rn(qz, z, __fmaf_rn(qy, y, __fmul_rn(qx, x)));
  const float xxj =
      __fadd_rn(__fadd_rn(__fmul_rn(x, x), __fmul_rn(y, y)), __fmul_rn(z, z));
  const float inner = __fmul_rn(-2.0f, dot);
  const float pval = __fsub_rn(__fsub_rn(nqxx, inner), xxj);
  const unsigned bits = __float_as_uint(pval);
  const unsigned ordv = bits ^ (unsigned)(((int)bits >> 31) | 0x80000000);
  return ((unsigned long long)ordv << 32) | (unsigned)(4095 - j);
}

// ---------------- Kernel A1: KNN, 2 query points per wave, 8 pts/block ----------------
__global__ __launch_bounds__(256, 6) void knn_kernel(const float* __restrict__ xyz,
                                                     int* __restrict__ nidx_ws) {
  __shared__ struct { float xs[1024]; float ys[1024]; float zs[1024]; } soa;

  const int wave = threadIdx.x >> 6;
  const int lane = threadIdx.x & 63;
  const int tid = threadIdx.x;
  const int P0 = blockIdx.x * 8;        // 8 points/block (2 per wave)
  const int b = P0 >> 12;
  const int r0 = P0 & 4095;
  const int pbase = r0 + wave * 2;
  const float* xb = xyz + (size_t)b * (N_ * 3);

  float qx[2], qy[2], qz[2], nqxx[2];
#pragma unroll
  for (int q = 0; q < 2; ++q) {
    const int i = pbase + q;
    qx[q] = xb[3 * i]; qy[q] = xb[3 * i + 1]; qz[q] = xb[3 * i + 2];
    nqxx[q] = -__fadd_rn(__fadd_rn(__fmul_rn(qx[q], qx[q]), __fmul_rn(qy[q], qy[q])),
                         __fmul_rn(qz[q], qz[q]));
  }

  unsigned long long pk[2][4];
#pragma unroll
  for (int q = 0; q < 2; ++q)
#pragma unroll
    for (int s = 0; s < 4; ++s) pk[q][s] = 0ull;

  for (int tile = 0; tile < 4; ++tile) {
    {
      const float4* gsrc = (const float4*)(xb + tile * 3072);
      float4 a0 = gsrc[tid * 3];
      float4 a1 = gsrc[tid * 3 + 1];
      float4 a2 = gsrc[tid * 3 + 2];
      const int qq = tid * 4;
      soa.xs[qq] = a0.x; soa.xs[qq + 1] = a0.w; soa.xs[qq + 2] = a1.z; soa.xs[qq + 3] = a2.y;
      soa.ys[qq] = a0.y; soa.ys[qq + 1] = a1.x; soa.ys[qq + 2] = a1.w; soa.ys[qq + 3] = a2.z;
      soa.zs[qq] = a0.z; soa.zs[qq + 1] = a1.y; soa.zs[qq + 2] = a2.x; soa.zs[qq + 3] = a2.w;
    }
    __syncthreads();

#pragma unroll 2
    for (int tloc = 0; tloc < 16; ++tloc) {
      const int idx = tloc * 64 + lane;
      const int j = tile * 1024 + idx;
      const float x = soa.xs[idx];
      const float y = soa.ys[idx];
      const float z = soa.zs[idx];
      const float xxj =
          __fadd_rn(__fadd_rn(__fmul_rn(x, x), __fmul_rn(y, y)), __fmul_rn(z, z));
      const unsigned jenc = (unsigned)(4095 - j);
#pragma unroll
      for (int q = 0; q < 2; ++q) {
        const float dot =
            __fmaf_rn(qz[q], z, __fmaf_rn(qy[q], y, __fmul_rn(qx[q], x)));
        const float inner = __fmul_rn(-2.0f, dot);
        const float pval = __fsub_rn(__fsub_rn(nqxx[q], inner), xxj);
        const unsigned bits = __float_as_uint(pval);
        const unsigned ordv = bits ^ (unsigned)(((int)bits >> 31) | 0x80000000);
        const unsigned long long key = ((unsigned long long)ordv << 32) | jenc;
        const bool c0 = key > pk[q][0], c1 = key > pk[q][1],
                   c2 = key > pk[q][2], c3 = key > pk[q][3];
        pk[q][3] = c3 ? (c2 ? pk[q][2] : key) : pk[q][3];
        pk[q][2] = c2 ? (c1 ? pk[q][1] : key) : pk[q][2];
        pk[q][1] = c1 ? (c0 ? pk[q][0] : key) : pk[q][1];
        pk[q][0] = c0 ? key : pk[q][0];
      }
    }
    __syncthreads();
  }

  int stash[2];
  int h[2] = {0, 0};
#pragma unroll
  for (int k = 0; k < K_; ++k) {
    unsigned long long v[2];
#pragma unroll
    for (int q = 0; q < 2; ++q) v[q] = pk[q][0];
#pragma unroll
    for (int off = 32; off >= 1; off >>= 1) {
#pragma unroll
      for (int q = 0; q < 2; ++q) {
        unsigned long long ov = __shfl_xor(v[q], off, 64);
        if (ov > v[q]) v[q] = ov;
      }
    }
#pragma unroll
    for (int q = 0; q < 2; ++q) {
      const int jidx = (4095 - (int)(unsigned)(v[q] & 0xFFFFFFFFull)) & (N_ - 1);
      if (lane == k) stash[q] = jidx;
      if (pk[q][0] == v[q]) {
        pk[q][0] = pk[q][1]; pk[q][1] = pk[q][2]; pk[q][2] = pk[q][3];
        pk[q][3] = 0ull;
        ++h[q];
      }
    }
  }
#pragma unroll
  for (int q = 0; q < 2; ++q) {
    if (__ballot(h[q] >= 4) != 0ull) {
      unsigned long long qq[K_];
#pragma unroll
      for (int k = 0; k < K_; ++k) qq[k] = 0ull;
      for (int t = 0; t < 64; ++t) {
        const int j = t * 64 + lane;
        const unsigned long long key = knn_key(qx[q], qy[q], qz[q], nqxx[q],
                                               xb[3 * j], xb[3 * j + 1],
                                               xb[3 * j + 2], j);
        bool c[K_];
#pragma unroll
        for (int s = 0; s < K_; ++s) c[s] = key > qq[s];
#pragma unroll
        for (int s = K_ - 1; s >= 1; --s)
          qq[s] = c[s] ? (c[s - 1] ? qq[s - 1] : key) : qq[s];
        qq[0] = c[0] ? key : qq[0];
      }
#pragma unroll
      for (int k = 0; k < K_; ++k) {
        unsigned long long v = qq[0];
#pragma unroll
        for (int off = 32; off >= 1; off >>= 1) {
          unsigned long long ov = __shfl_xor(v, off, 64);
          if (ov > v) v = ov;
        }
        const int jidx = (4095 - (int)(unsigned)(v & 0xFFFFFFFFull)) & (N_ - 1);
        if (lane == k) stash[q] = jidx;
        if (qq[0] == v) {
#pragma unroll
          for (int s = 0; s < K_ - 1; ++s) qq[s] = qq[s + 1];
          qq[K_ - 1] = 0ull;
        }
      }
    }
  }

  if (lane < K_) {
    const int pg = P0 + wave * 2;
#pragma unroll
    for (int q = 0; q < 2; ++q)
      nidx_ws[(size_t)(pg + q) * K_ + lane] = stash[q];
  }
}

// ---------------- Kernel A2: cov + eig, one point per thread ----------------
__global__ __launch_bounds__(64) void eig_kernel(const float* __restrict__ xyz,
                                                 const int* __restrict__ nidx_ws,
                                                 float* __restrict__ gf_ws) {
  const int p = blockIdx.x * 64 + threadIdx.x;
  const int b = p >> 12;
  const int i = p & 4095;
  const float* xb = xyz + (size_t)b * (N_ * 3);
  const float qx = xb[3 * i];
  const float qy = xb[3 * i + 1];
  const float qz = xb[3 * i + 2];

  int nidx[K_];
#pragma unroll
  for (int k = 0; k < K_; ++k) nidx[k] = nidx_ws[(size_t)p * K_ + k];

  float c00 = 0, c01 = 0, c02 = 0, c11 = 0, c12 = 0, c22 = 0;
  float mrx = 0, mry = 0, mrz = 0, md = 0;
#pragma unroll
  for (int k = 0; k < K_; ++k) {
    const int j = nidx[k];
    const float rx = __fsub_rn(xb[3 * j], qx);
    const float ry = __fsub_rn(xb[3 * j + 1], qy);
    const float rz = __fsub_rn(xb[3 * j + 2], qz);
    c00 = __fadd_rn(c00, __fmul_rn(rx, rx));
    c01 = __fadd_rn(c01, __fmul_rn(rx, ry));
    c02 = __fadd_rn(c02, __fmul_rn(rx, rz));
    c11 = __fadd_rn(c11, __fmul_rn(ry, ry));
    c12 = __fadd_rn(c12, __fmul_rn(ry, rz));
    c22 = __fadd_rn(c22, __fmul_rn(rz, rz));
    mrx = __fadd_rn(mrx, rx);
    mry = __fadd_rn(mry, ry);
    mrz = __fadd_rn(mrz, rz);
    const float nn = __fadd_rn(__fadd_rn(__fmul_rn(rx, rx), __fmul_rn(ry, ry)),
                               __fmul_rn(rz, rz));
    md = __fadd_rn(md, sqrtf(nn));
  }
  const float s16 = 0.0625f;
  float Z[3][3];
  eig3_f(__fmul_rn(c00, s16), __fmul_rn(c01, s16), __fmul_rn(c02, s16),
         __fmul_rn(c11, s16), __fmul_rn(c12, s16), __fmul_rn(c22, s16), Z);
  float* g = gf_ws + (size_t)p * 12;
  g[0] = Z[0][0]; g[1] = Z[1][0]; g[2] = Z[2][0];
  g[3] = Z[0][2]; g[4] = Z[1][2]; g[5] = Z[2][2];
  g[6] = __fmul_rn(mrx, s16); g[7] = __fmul_rn(mry, s16);
  g[8] = __fmul_rn(mrz, s16);
  g[9] = __fmul_rn(md, s16);
}

// ---------------- Kernel B: block-cooperative MLPs, channel-outer (R12, proven) ----------------
__global__ __launch_bounds__(256) void mlp_kernel(
    const float* __restrict__ feats, const int* __restrict__ nidx_ws,
    const float* __restrict__ gf_ws,
    const float* __restrict__ geo_w1, const float* __restrict__ geo_b1,
    const float* __restrict__ geo_g1, const float* __restrict__ geo_be1,
    const float* __restrict__ geo_w2, const float* __restrict__ geo_b2,
    const float* __restrict__ diff_w1, const float* __restrict__ diff_b1,
    const float* __restrict__ diff_g1, const float* __restrict__ diff_be1,
    const float* __restrict__ diff_w2, const float* __restrict__ diff_b2,
    const float* __restrict__ ep_w1, const float* __restrict__ ep_b1,
    const float* __restrict__ ep_w2, const float* __restrict__ ep_b2,
    const float* __restrict__ ref_w1, const float* __restrict__ ref_b1,
    const float* __restrict__ ref_g1, const float* __restrict__ ref_be1,
    float* __restrict__ out, float* __restrict__ out_prob) {

  __shared__ float w[8192];
  __shared__ float fsh[16 * 128];
  __shared__ float sdif[16 * 128];
  __shared__ float ysh[16 * 64];
  __shared__ float edsh[16 * 128];
  __shared__ float insh[16 * 12];
  __shared__ int nsh[16 * 16];

  const int tid = threadIdx.x;
  const int lane = tid & 63;
  const int g = tid >> 6;
  const int P0 = blockIdx.x * 16;
  const int b = P0 >> 12;
  const int r0 = P0 & 4095;
  const float* fb = feats + (size_t)b * N_ * C_;

  if (tid < 192) insh[tid] = gf_ws[(size_t)P0 * 12 + tid];
  nsh[tid] = nidx_ws[(size_t)P0 * K_ + tid];
#pragma unroll
  for (int m = 0; m < 8; ++m)
    fsh[m * 256 + tid] = fb[(size_t)r0 * C_ + m * 256 + tid];
  if (tid < 160) ((float4*)w)[tid] = ((const float4*)geo_w1)[tid];
#pragma unroll
  for (int m = 0; m < 4; ++m)
    ((float4*)(w + 640))[m * 256 + tid] = ((const float4*)geo_w2)[m * 256 + tid];
  __syncthreads();

  // geo layer 1 (channel-outer) + LN
  {
    float acc[4] = {0, 0, 0, 0};
#pragma unroll
    for (int c = 0; c < 10; ++c) {
      const float wv = w[c * 64 + lane];
#pragma unroll
      for (int ptl = 0; ptl < 4; ++ptl)
        acc[ptl] += insh[(g * 4 + ptl) * 12 + c] * wv;
    }
#pragma unroll
    for (int ptl = 0; ptl < 4; ++ptl) {
      const int pt = g * 4 + ptl;
      float a = acc[ptl] + geo_b1[lane];
      float m = wave_sum64(a) * (1.0f / 64.0f);
      float xm = a - m;
      float var = wave_sum64(xm * xm) * (1.0f / 64.0f);
      float yv = xm * (1.0f / sqrtf(var + 1e-5f)) * geo_g1[lane] + geo_be1[lane];
      ysh[pt * 64 + lane] = fmaxf(yv, 0.0f);
    }
  }
  __syncthreads();

  // geo layer 2 (channel-outer)
  float ge[4] = {0, 0, 0, 0}, de[4], prob[4];
#pragma unroll 4
  for (int c = 0; c < 64; ++c) {
    const float wv = w[640 + c * 64 + lane];
#pragma unroll
    for (int ptl = 0; ptl < 4; ++ptl)
      ge[ptl] += ysh[(g * 4 + ptl) * 64 + c] * wv;
  }
#pragma unroll
  for (int ptl = 0; ptl < 4; ++ptl) ge[ptl] += geo_b2[lane];

  // feat_diff
  {
    const int h2 = tid >> 7, c = tid & 127;
    for (int ptp = 0; ptp < 8; ++ptp) {
      const int pt = h2 * 8 + ptp;
      const float fv = fsh[pt * 128 + c];
      float s = 0.0f;
#pragma unroll
      for (int k = 0; k < K_; ++k) {
        const int j = nsh[pt * 16 + k];
        s += fabsf(fv - fb[(size_t)j * C_ + c]);
      }
      sdif[pt * 128 + c] = s * (1.0f / 16.0f);
    }
  }
  __syncthreads();
#pragma unroll
  for (int m = 0; m < 8; ++m)
    ((float4*)w)[m * 256 + tid] = ((const float4*)diff_w1)[m * 256 + tid];
  __syncthreads();

  // diff layer 1 (channel-outer) + LN
  {
    float acc[4] = {0, 0, 0, 0};
#pragma unroll 4
    for (int c = 0; c < 128; ++c) {
      const float wv = w[c * 64 + lane];
#pragma unroll
      for (int ptl = 0; ptl < 4; ++ptl)
        acc[ptl] += sdif[(g * 4 + ptl) * 128 + c] * wv;
    }
#pragma unroll
    for (int ptl = 0; ptl < 4; ++ptl) {
      const int pt = g * 4 + ptl;
      float a = acc[ptl] + diff_b1[lane];
      float m = wave_sum64(a) * (1.0f / 64.0f);
      float xm = a - m;
      float var = wave_sum64(xm * xm) * (1.0f / 64.0f);
      float yv = xm * (1.0f / sqrtf(var + 1e-5f)) * diff_g1[lane] + diff_be1[lane];
      ysh[pt * 64 + lane] = fmaxf(yv, 0.0f);
    }
  }
  __syncthreads();
#pragma unroll
  for (int m = 0; m < 4; ++m)
    ((float4*)w)[m * 256 + tid] = ((const float4*)diff_w2)[m * 256 + tid];
#pragma unroll
  for (int m = 0; m < 4; ++m)
    ((float4*)w)[1024 + m * 256 + tid] = ((const float4*)ep_w1)[m * 256 + tid];
  __syncthreads();

  // diff layer 2 (channel-outer), stash [ge||de]
  {
    float acc[4] = {0, 0, 0, 0};
#pragma unroll 4
    for (int c = 0; c < 64; ++c) {
      const float wv = w[c * 64 + lane];
#pragma unroll
      for (int ptl = 0; ptl < 4; ++ptl)
        acc[ptl] += ysh[(g * 4 + ptl) * 64 + c] * wv;
    }
#pragma unroll
    for (int ptl = 0; ptl < 4; ++ptl) {
      const int pt = g * 4 + ptl;
      de[ptl] = acc[ptl] + diff_b2[lane];
      edsh[pt * 128 + lane] = ge[ptl];
      edsh[pt * 128 + 64 + lane] = de[ptl];
    }
  }
  __syncthreads();

  // edge-prob MLP (channel-outer)
  const int u = lane & 31;
  {
    float ea[4] = {0, 0, 0, 0};
#pragma unroll 4
    for (int c = 0; c < 128; ++c) {
      const float wv = w[4096 + c * 32 + u];
#pragma unroll
      for (int ptl = 0; ptl < 4; ++ptl)
        ea[ptl] += edsh[(g * 4 + ptl) * 128 + c] * wv;
    }
#pragma unroll
    for (int ptl = 0; ptl < 4; ++ptl) {
      float a = ea[ptl] + ep_b1[u];
      float hh = (lane < 32) ? fmaxf(a, 0.0f) * ep_w2[u] : 0.0f;
      float tsum = wave_sum64(hh) + ep_b2[0];
      prob[ptl] = 1.0f / (1.0f + expf(-tsum));
    }
  }
  __syncthreads();
#pragma unroll
  for (int ptl = 0; ptl < 4; ++ptl) {
    const int pt = g * 4 + ptl;
    edsh[pt * 128 + lane] = ge[ptl] * prob[ptl];
    edsh[pt * 128 + 64 + lane] = de[ptl] * prob[ptl];
  }

  // ref matvec: 4 chunks of 64 input-channels, channel-outer
  float a0[4] = {0, 0, 0, 0}, a1[4] = {0, 0, 0, 0};
  for (int ch = 0; ch < 4; ++ch) {
    __syncthreads();
    {
      const float4* gsrc = (const float4*)(ref_w1 + ch * 8192);
#pragma unroll
      for (int m = 0; m < 8; ++m) ((float4*)w)[m * 256 + tid] = gsrc[m * 256 + tid];
    }
    __syncthreads();
#pragma unroll 4
    for (int cl = 0; cl < 64; ++cl) {
      const float w0 = w[cl * 128 + lane];
      const float w1v = w[cl * 128 + 64 + lane];
#pragma unroll
      for (int ptl = 0; ptl < 4; ++ptl) {
        const int pt = g * 4 + ptl;
        const float e = (ch < 2) ? fsh[pt * 128 + ch * 64 + cl]
                                 : edsh[pt * 128 + (ch - 2) * 64 + cl];
        a0[ptl] += e * w0;
        a1[ptl] += e * w1v;
      }
    }
  }

  // epilogue
#pragma unroll
  for (int ptl = 0; ptl < 4; ++ptl) {
    const int pt = g * 4 + ptl;
    float A0 = a0[ptl] + ref_b1[lane];
    float A1 = a1[ptl] + ref_b1[64 + lane];
    float mm2 = wave_sum64(A0 + A1) * (1.0f / 128.0f);
    float d0 = A0 - mm2, d1 = A1 - mm2;
    float var2 = wave_sum64(d0 * d0 + d1 * d1) * (1.0f / 128.0f);
    float rs = 1.0f / sqrtf(var2 + 1e-5f);
    float y0 = d0 * rs * ref_g1[lane] + ref_be1[lane];
    float y1 = d1 * rs * ref_g1[64 + lane] + ref_be1[64 + lane];
    y0 = fmaxf(y0, 0.0f) + fsh[pt * 128 + lane];
    y1 = fmaxf(y1, 0.0f) + fsh[pt * 128 + 64 + lane];
    out[(size_t)(P0 + pt) * 128 + lane] = y0;
    out[(size_t)(P0 + pt) * 128 + 64 + lane] = y1;
    if (lane == 0) out_prob[P0 + pt] = prob[ptl];
  }
}

// ---------------- Fallback: R8 fused kernel (proven) ----------------
__global__ __launch_bounds__(256) void fused_kernel(
    const float* __restrict__ xyz, const float* __restrict__ feats,
    const float* __restrict__ geo_w1, const float* __restrict__ geo_b1,
    const float* __restrict__ geo_g1, const float* __restrict__ geo_be1,
    const float* __restrict__ geo_w2, const float* __restrict__ geo_b2,
    const float* __restrict__ diff_w1, const float* __restrict__ diff_b1,
    const float* __restrict__ diff_g1, const float* __restrict__ diff_be1,
    const float* __restrict__ diff_w2, const float* __restrict__ diff_b2,
    const float* __restrict__ ep_w1, const float* __restrict__ ep_b1,
    const float* __restrict__ ep_w2, const float* __restrict__ ep_b2,
    const float* __restrict__ ref_w1, const float* __restrict__ ref_b1,
    const float* __restrict__ ref_g1, const float* __restrict__ ref_be1,
    float* __restrict__ out, float* __restrict__ out_prob) {

  __shared__ float4 tile4[1024];

  const int wave = threadIdx.x >> 6;
  const int lane = threadIdx.x & 63;
  const int tid = threadIdx.x;
  const int p = blockIdx.x * 4 + wave;
  const int b = p >> 12;
  const int i = p & 4095;
  const float* xb = xyz + (size_t)b * (N_ * 3);

  const float qx = xb[3 * i];
  const float qy = xb[3 * i + 1];
  const float qz = xb[3 * i + 2];
  const float qxx =
      __fadd_rn(__fadd_rn(__fmul_rn(qx, qx), __fmul_rn(qy, qy)), __fmul_rn(qz, qz));
  const float nqxx = -qxx;

  unsigned long long pk[4] = {0ull, 0ull, 0ull, 0ull};
  for (int tile = 0; tile < 4; ++tile) {
    {
      const float4* gsrc = (const float4*)(xb + tile * 3072);
      float4 r0v = gsrc[tid * 3];
      float4 r1 = gsrc[tid * 3 + 1];
      float4 r2 = gsrc[tid * 3 + 2];
      const int base = tid * 4;
      tile4[base]     = make_float4(r0v.x, r0v.y, r0v.z, 0.0f);
      tile4[base + 1] = make_float4(r0v.w, r1.x, r1.y, 0.0f);
      tile4[base + 2] = make_float4(r1.z, r1.w, r2.x, 0.0f);
      tile4[base + 3] = make_float4(r2.y, r2.z, r2.w, 0.0f);
    }
    __syncthreads();
#pragma unroll 4
    for (int tloc = 0; tloc < 16; ++tloc) {
      const int j = tile * 1024 + tloc * 64 + lane;
      const float4 pt = tile4[tloc * 64 + lane];
      const unsigned long long key = knn_key(qx, qy, qz, nqxx, pt.x, pt.y, pt.z, j);
      const bool c0 = key > pk[0], c1 = key > pk[1], c2 = key > pk[2], c3 = key > pk[3];
      pk[3] = c3 ? (c2 ? pk[2] : key) : pk[3];
      pk[2] = c2 ? (c1 ? pk[1] : key) : pk[2];
      pk[1] = c1 ? (c0 ? pk[0] : key) : pk[1];
      pk[0] = c0 ? key : pk[0];
    }
    __syncthreads();
  }

  int nidx[K_];
  int h = 0;
#pragma unroll
  for (int k = 0; k < K_; ++k) {
    unsigned long long v = pk[0];
#pragma unroll
    for (int off = 32; off >= 1; off >>= 1) {
      unsigned long long ov = __shfl_xor(v, off, 64);
      if (ov > v) v = ov;
    }
    nidx[k] = (4095 - (int)(unsigned)(v & 0xFFFFFFFFull)) & (N_ - 1);
    if (pk[0] == v) {
      pk[0] = pk[1]; pk[1] = pk[2]; pk[2] = pk[3]; pk[3] = 0ull;
      ++h;
    }
  }
  if (__ballot(h >= 4) != 0ull) {
    unsigned long long q[K_];
#pragma unroll
    for (int k = 0; k < K_; ++k) q[k] = 0ull;
    for (int t = 0; t < 64; ++t) {
      const int j = t * 64 + lane;
      const unsigned long long key =
          knn_key(qx, qy, qz, nqxx, xb[3 * j], xb[3 * j + 1], xb[3 * j + 2], j);
      bool c[K_];
#pragma unroll
      for (int s = 0; s < K_; ++s) c[s] = key > q[s];
#pragma unroll
      for (int s = K_ - 1; s >= 1; --s)
        q[s] = c[s] ? (c[s - 1] ? q[s - 1] : key) : q[s];
      q[0] = c[0] ? key : q[0];
    }
#pragma unroll
    for (int k = 0; k < K_; ++k) {
      unsigned long long v = q[0];
#pragma unroll
      for (int off = 32; off >= 1; off >>= 1) {
        unsigned long long ov = __shfl_xor(v, off, 64);
        if (ov > v) v = ov;
      }
      nidx[k] = (4095 - (int)(unsigned)(v & 0xFFFFFFFFull)) & (N_ - 1);
      if (q[0] == v) {
#pragma unroll
        for (int s = 0; s < K_ - 1; ++s) q[s] = q[s + 1];
        q[K_ - 1] = 0ull;
      }
    }
  }

  float c00 = 0, c01 = 0, c02 = 0, c11 = 0, c12 = 0, c22 = 0;
  float mrx = 0, mry = 0, mrz = 0, md = 0;
#pragma unroll
  for (int k = 0; k < K_; ++k) {
    const int j = nidx[k];
    const float rx = __fsub_rn(xb[3 * j], qx);
    const float ry = __fsub_rn(xb[3 * j + 1], qy);
    const float rz = __fsub_rn(xb[3 * j + 2], qz);
    c00 = __fadd_rn(c00, __fmul_rn(rx, rx));
    c01 = __fadd_rn(c01, __fmul_rn(rx, ry));
    c02 = __fadd_rn(c02, __fmul_rn(rx, rz));
    c11 = __fadd_rn(c11, __fmul_rn(ry, ry));
    c12 = __fadd_rn(c12, __fmul_rn(ry, rz));
    c22 = __fadd_rn(c22, __fmul_rn(rz, rz));
    mrx = __fadd_rn(mrx, rx);
    mry = __fadd_rn(mry, ry);
    mrz = __fadd_rn(mrz, rz);
    const float nn = __fadd_rn(__fadd_rn(__fmul_rn(rx, rx), __fmul_rn(ry, ry)),
                               __fmul_rn(rz, rz));
    md = __fadd_rn(md, sqrtf(nn));
  }
  const float s16 = 0.0625f;
  float Z[3][3];
  eig3_f(__fmul_rn(c00, s16), __fmul_rn(c01, s16), __fmul_rn(c02, s16),
         __fmul_rn(c11, s16), __fmul_rn(c12, s16), __fmul_rn(c22, s16), Z);
  float gf[10];
  gf[0] = Z[0][0]; gf[1] = Z[1][0]; gf[2] = Z[2][0];
  gf[3] = Z[0][2]; gf[4] = Z[1][2]; gf[5] = Z[2][2];
  gf[6] = __fmul_rn(mrx, s16); gf[7] = __fmul_rn(mry, s16);
  gf[8] = __fmul_rn(mrz, s16);
  gf[9] = __fmul_rn(md, s16);

  float acc = 0.0f;
#pragma unroll
  for (int ii = 0; ii < 10; ++ii) acc += gf[ii] * geo_w1[ii * 64 + lane];
  acc += geo_b1[lane];
  float yr;
  {
    float m = wave_sum64(acc) * (1.0f / 64.0f);
    float xm = acc - m;
    float var = wave_sum64(xm * xm) * (1.0f / 64.0f);
    float yv = xm * (1.0f / sqrtf(var + 1e-5f)) * geo_g1[lane] + geo_be1[lane];
    yr = fmaxf(yv, 0.0f);
  }
  float ge = 0.0f;
#pragma unroll 8
  for (int jj = 0; jj < 64; ++jj) ge += __shfl(yr, jj, 64) * geo_w2[jj * 64 + lane];
  ge += geo_b2[lane];

  const float* fb = feats + (size_t)b * N_ * C_;
  const float* fi = fb + (size_t)i * C_;
  const float f0 = fi[lane];
  const float f1 = fi[64 + lane];
  float s0 = 0.0f, s1 = 0.0f;
#pragma unroll
  for (int k = 0; k < K_; ++k) {
    const float* fj = fb + (size_t)nidx[k] * C_;
    s0 += fabsf(f0 - fj[lane]);
    s1 += fabsf(f1 - fj[64 + lane]);
  }
  s0 *= (1.0f / 16.0f);
  s1 *= (1.0f / 16.0f);
  float acc2 = 0.0f;
#pragma unroll 8
  for (int c = 0; c < 64; ++c) acc2 += __shfl(s0, c, 64) * diff_w1[c * 64 + lane];
#pragma unroll 8
  for (int c = 64; c < 128; ++c) acc2 += __shfl(s1, c - 64, 64) * diff_w1[c * 64 + lane];
  acc2 += diff_b1[lane];
  float yr2;
  {
    float m = wave_sum64(acc2) * (1.0f / 64.0f);
    float xm = acc2 - m;
    float var = wave_sum64(xm * xm) * (1.0f / 64.0f);
    float yv = xm * (1.0f / sqrtf(var + 1e-5f)) * diff_g1[lane] + diff_be1[lane];
    yr2 = fmaxf(yv, 0.0f);
  }
  float de = 0.0f;
#pragma unroll 8
  for (int jj = 0; jj < 64; ++jj) de += __shfl(yr2, jj, 64) * diff_w2[jj * 64 + lane];
  de += diff_b2[lane];

  {
    const int u = lane & 31;
    float a = 0.0f;
#pragma unroll 8
    for (int c = 0; c < 64; ++c) a += __shfl(ge, c, 64) * ep_w1[c * 32 + u];
#pragma unroll 8
    for (int c = 64; c < 128; ++c) a += __shfl(de, c - 64, 64) * ep_w1[c * 32 + u];
    a += ep_b1[u];
    float hh = (lane < 32) ? fmaxf(a, 0.0f) * ep_w2[u] : 0.0f;
    float tsum = wave_sum64(hh) + ep_b2[0];
    float prob = 1.0f / (1.0f + expf(-tsum));

    const float gep = ge * prob;
    const float dep = de * prob;
    float a0 = 0.0f, a1 = 0.0f;
#pragma unroll 4
    for (int c = 0; c < 64; ++c) {
      float ec = __shfl(f0, c, 64);
      a0 += ec * ref_w1[c * 128 + lane];
      a1 += ec * ref_w1[c * 128 + 64 + lane];
    }
#pragma unroll 4
    for (int c = 64; c < 128; ++c) {
      float ec = __shfl(f1, c - 64, 64);
      a0 += ec * ref_w1[c * 128 + lane];
      a1 += ec * ref_w1[c * 128 + 64 + lane];
    }
#pragma unroll 4
    for (int c = 128; c < 192; ++c) {
      float ec = __shfl(gep, c - 128, 64);
      a0 += ec * ref_w1[c * 128 + lane];
      a1 += ec * ref_w1[c * 128 + 64 + lane];
    }
#pragma unroll 4
    for (int c = 192; c < 256; ++c) {
      float ec = __shfl(dep, c - 192, 64);
      a0 += ec * ref_w1[c * 128 + lane];
      a1 += ec * ref_w1[c * 128 + 64 + lane];
    }
    a0 += ref_b1[lane];
    a1 += ref_b1[64 + lane];
    float mm2 = wave_sum64(a0 + a1) * (1.0f / 128.0f);
    float d0 = a0 - mm2, d1 = a1 - mm2;
    float var2 = wave_sum64(d0 * d0 + d1 * d1) * (1.0f / 128.0f);
    float rs = 1.0f / sqrtf(var2 + 1e-5f);
    float y0 = d0 * rs * ref_g1[lane] + ref_be1[lane];
    float y1 = d1 * rs * ref_g1[64 + lane] + ref_be1[64 + lane];
    y0 = fmaxf(y0, 0.0f) + f0;
    y1 = fmaxf(y1, 0.0f) + f1;
    out[(size_t)p * 128 + lane] = y0;
    out[(size_t)p * 128 + 64 + lane] = y1;
    if (lane == 0) out_prob[p] = prob;
  }
}

extern "C" void kernel_launch(void* const* d_in, const int* in_sizes, int n_in,
                              void* d_out, int out_size, void* d_ws, size_t ws_size,
                              hipStream_t stream) {
  const float* xyz = (const float*)d_in[0];
  const float* features = (const float*)d_in[1];
  const float* geo_w1 = (const float*)d_in[2];
  const float* geo_b1 = (const float*)d_in[3];
  const float* geo_g1 = (const float*)d_in[4];
  const float* geo_be1 = (const float*)d_in[5];
  const float* geo_w2 = (const float*)d_in[6];
  const float* geo_b2 = (const float*)d_in[7];
  const float* diff_w1 = (const float*)d_in[8];
  const float* diff_b1 = (const float*)d_in[9];
  const float* diff_g1 = (const float*)d_in[10];
  const float* diff_be1 = (const float*)d_in[11];
  const float* diff_w2 = (const float*)d_in[12];
  const float* diff_b2 = (const float*)d_in[13];
  const float* ep_w1 = (const float*)d_in[14];
  const float* ep_b1 = (const float*)d_in[15];
  const float* ep_w2 = (const float*)d_in[16];
  const float* ep_b2 = (const float*)d_in[17];
  const float* ref_w1 = (const float*)d_in[18];
  const float* ref_b1 = (const float*)d_in[19];
  const float* ref_g1 = (const float*)d_in[20];
  const float* ref_be1 = (const float*)d_in[21];

  float* out = (float*)d_out;
  float* out_prob = out + (size_t)NPT * C_;

  if (ws_size >= (size_t)(2 * 1024 * 1024)) {
    int* nidx_ws = (int*)d_ws;                             // 1 MB
    float* gf_ws = (float*)((char*)d_ws + (1u << 20));     // 768 KB
    knn_kernel<<<dim3(NPT / 8), dim3(256), 0, stream>>>(xyz, nidx_ws);
    eig_kernel<<<dim3(NPT / 64), dim3(64), 0, stream>>>(xyz, nidx_ws, gf_ws);
    mlp_kernel<<<dim3(NPT / 16), dim3(256), 0, stream>>>(
        features, nidx_ws, gf_ws, geo_w1, geo_b1, geo_g1, geo_be1, geo_w2,
        geo_b2, diff_w1, diff_b1, diff_g1, diff_be1, diff_w2, diff_b2, ep_w1,
        ep_b1, ep_w2, ep_b2, ref_w1, ref_b1, ref_g1, ref_be1, out, out_prob);
  } else {
    fused_kernel<<<dim3(NPT / 4), dim3(256), 0, stream>>>(
        xyz, features, geo_w1, geo_b1, geo_g1, geo_be1, geo_w2, geo_b2,
        diff_w1, diff_b1, diff_g1, diff_be1, diff_w2, diff_b2, ep_w1, ep_b1,
        ep_w2, ep_b2, ref_w1, ref_b1, ref_g1, ref_be1, out, out_prob);
  }
}